// Round 2
// baseline (6672.639 us; speedup 1.0000x reference)
//
#include <hip/hip_runtime.h>
#include <hip/hip_bf16.h>

// Problem constants (match reference)
#define DD 128
#define CC 100000
#define BB 32
#define N_ITER 4
// INIT_NORM = sqrt(128)/sqrt(2) = 8.0 exactly
#define INV_INIT_NORM 0.125f

// ---------------- init / degree kernels ----------------

__global__ void bcast_init_kernel(const float* __restrict__ init, float* __restrict__ emb, int n) {
    int i = blockIdx.x * 256 + threadIdx.x;
    if (i < n) emb[i] = init[i & (DD - 1)] * INV_INIT_NORM;
}

__global__ void deg_kernel(const int* __restrict__ li, const int* __restrict__ ci,
                           float* __restrict__ ldeg, float* __restrict__ cdeg, int E) {
    int e = blockIdx.x * 256 + threadIdx.x;
    if (e < E) {
        atomicAdd(&ldeg[li[e]], 1.0f);
        atomicAdd(&cdeg[ci[e]], 1.0f);
    }
}

// ---------------- GEMM: Y[N,M] = act(A[N,K] @ W[M,K]^T + bias), optional row scale 1/max(deg,1) on A ----------------
// 128x128 tile, 8x8 per thread, 256 threads, BK=32, transposed LDS for float4 reads.

template<bool RELU, bool ROWSCALE>
__global__ __launch_bounds__(256)
void gemm_kernel(const float* __restrict__ A, const float* __restrict__ W,
                 const float* __restrict__ bias, float* __restrict__ Y,
                 int N, int K, int M, const float* __restrict__ deg) {
    __shared__ float As[32][132];  // [k][row]
    __shared__ float Ws[32][132];  // [k][col]

    const int tid = threadIdx.x;
    const int bn = blockIdx.x * 128;
    const int bm = blockIdx.y * 128;
    const int tx = tid & 15;      // col group
    const int ty = tid >> 4;      // row group
    const int lrow = tid >> 3;    // 0..31
    const int lk = (tid & 7) * 4; // 0..28

    float acc[8][8];
#pragma unroll
    for (int i = 0; i < 8; ++i)
#pragma unroll
        for (int j = 0; j < 8; ++j) acc[i][j] = 0.0f;

    for (int k0 = 0; k0 < K; k0 += 32) {
#pragma unroll
        for (int i = 0; i < 4; ++i) {
            int gr = bn + lrow + 32 * i;
            float4 v = make_float4(0.f, 0.f, 0.f, 0.f);
            if (gr < N) {
                v = *(const float4*)(A + (size_t)gr * K + k0 + lk);
                if (ROWSCALE) {
                    float s = 1.0f / fmaxf(deg[gr], 1.0f);
                    v.x *= s; v.y *= s; v.z *= s; v.w *= s;
                }
            }
            As[lk + 0][lrow + 32 * i] = v.x;
            As[lk + 1][lrow + 32 * i] = v.y;
            As[lk + 2][lrow + 32 * i] = v.z;
            As[lk + 3][lrow + 32 * i] = v.w;
        }
#pragma unroll
        for (int i = 0; i < 4; ++i) {
            int gm = bm + lrow + 32 * i;   // M is always a multiple of 128
            float4 v = *(const float4*)(W + (size_t)gm * K + k0 + lk);
            Ws[lk + 0][lrow + 32 * i] = v.x;
            Ws[lk + 1][lrow + 32 * i] = v.y;
            Ws[lk + 2][lrow + 32 * i] = v.z;
            Ws[lk + 3][lrow + 32 * i] = v.w;
        }
        __syncthreads();
#pragma unroll
        for (int k = 0; k < 32; ++k) {
            float a[8], w[8];
            *(float4*)&a[0] = *(const float4*)&As[k][ty * 8];
            *(float4*)&a[4] = *(const float4*)&As[k][ty * 8 + 4];
            *(float4*)&w[0] = *(const float4*)&Ws[k][tx * 8];
            *(float4*)&w[4] = *(const float4*)&Ws[k][tx * 8 + 4];
#pragma unroll
            for (int i = 0; i < 8; ++i)
#pragma unroll
                for (int j = 0; j < 8; ++j) acc[i][j] = fmaf(a[i], w[j], acc[i][j]);
        }
        __syncthreads();
    }

#pragma unroll
    for (int i = 0; i < 8; ++i) {
        int gr = bn + ty * 8 + i;
        if (gr >= N) break;
#pragma unroll
        for (int j = 0; j < 8; j += 4) {
            int gm = bm + tx * 8 + j;
            float4 o;
            o.x = acc[i][j + 0] + bias[gm + 0];
            o.y = acc[i][j + 1] + bias[gm + 1];
            o.z = acc[i][j + 2] + bias[gm + 2];
            o.w = acc[i][j + 3] + bias[gm + 3];
            if (RELU) {
                o.x = fmaxf(o.x, 0.f); o.y = fmaxf(o.y, 0.f);
                o.z = fmaxf(o.z, 0.f); o.w = fmaxf(o.w, 0.f);
            }
            *(float4*)(Y + (size_t)gr * M + gm) = o;
        }
    }
}

// ---------------- edge scatter: aggr[dst[e]] += msg[src[e]] ----------------

__global__ void scatter_kernel(const float* __restrict__ msg, const int* __restrict__ src,
                               const int* __restrict__ dst, float* __restrict__ aggr, int E) {
    int e = blockIdx.x * 4 + (threadIdx.x >> 6);
    if (e >= E) return;
    int lane = threadIdx.x & 63;
    const float2 m = ((const float2*)(msg + (size_t)src[e] * DD))[lane];
    float* d = aggr + (size_t)dst[e] * DD;
    atomicAdd(d + 2 * lane + 0, m.x);
    atomicAdd(d + 2 * lane + 1, m.y);
}

// ---------------- GRU elementwise ----------------

__device__ __forceinline__ float sigmoidf_(float x) { return 1.0f / (1.0f + expf(-x)); }

__global__ void gru_kernel(const float* __restrict__ gi, const float* __restrict__ gh,
                           float* __restrict__ h, int n) {
    int i = blockIdx.x * 256 + threadIdx.x;
    if (i >= n) return;
    int r = i >> 7, c = i & 127;
    size_t b = (size_t)r * 384 + c;
    float ir = gi[b], iz = gi[b + 128], in_ = gi[b + 256];
    float hr = gh[b], hz = gh[b + 128], hn = gh[b + 256];
    float rg = sigmoidf_(ir + hr);
    float zg = sigmoidf_(iz + hz);
    float ng = tanhf(in_ + rg * hn);
    float hv = h[i];
    h[i] = (1.0f - zg) * ng + zg * hv;
}

// ---------------- xcat: [aggr/l_deg , l_emb[l^1]] ----------------

__global__ void xcat_kernel(const float* __restrict__ aggr, const float* __restrict__ ldeg,
                            const float* __restrict__ lemb, float* __restrict__ xcat, int n) {
    int i = blockIdx.x * 256 + threadIdx.x;
    if (i >= n) return;
    int l = i >> 7, c = i & 127;
    float s = 1.0f / fmaxf(ldeg[l], 1.0f);
    xcat[(size_t)l * 256 + c] = aggr[i] * s;
    xcat[(size_t)l * 256 + 128 + c] = lemb[(size_t)(l ^ 1) * DD + c];
}

// ---------------- readout ----------------

__global__ void logit_kernel(const float* __restrict__ hidden, const float* __restrict__ w2,
                             const float* __restrict__ b2, const int* __restrict__ l_batch,
                             float* __restrict__ gsum, float* __restrict__ gcnt, int Lc) {
    int row = blockIdx.x * 4 + (threadIdx.x >> 6);
    if (row >= Lc) return;
    int lane = threadIdx.x & 63;
    float2 h = ((const float2*)(hidden + (size_t)row * DD))[lane];
    float2 w = ((const float2*)w2)[lane];
    float dp = h.x * w.x + h.y * w.y;
#pragma unroll
    for (int off = 32; off > 0; off >>= 1) dp += __shfl_down(dp, off);
    if (lane == 0) {
        int b = l_batch[row];
        atomicAdd(&gsum[b], dp + b2[0]);
        atomicAdd(&gcnt[b], 1.0f);
    }
}

__global__ void final_kernel(const float* __restrict__ gsum, const float* __restrict__ gcnt,
                             float* __restrict__ out) {
    int b = threadIdx.x;
    if (b < BB) {
        float m = gsum[b] / fmaxf(gcnt[b], 1.0f);
        out[b] = 1.0f / (1.0f + expf(-m));
    }
}

// ---------------- host side ----------------

static inline size_t align_up_(size_t x) { return (x + 255) & ~(size_t)255; }

static void launch_gemm(const float* A, const float* W, const float* bias, float* Y,
                        int N, int K, int M, const float* deg, bool relu, hipStream_t stream) {
    dim3 g((N + 127) / 128, M / 128);
    if (relu) {
        if (deg) gemm_kernel<true, true><<<g, 256, 0, stream>>>(A, W, bias, Y, N, K, M, deg);
        else     gemm_kernel<true, false><<<g, 256, 0, stream>>>(A, W, bias, Y, N, K, M, nullptr);
    } else {
        if (deg) gemm_kernel<false, true><<<g, 256, 0, stream>>>(A, W, bias, Y, N, K, M, deg);
        else     gemm_kernel<false, false><<<g, 256, 0, stream>>>(A, W, bias, Y, N, K, M, nullptr);
    }
}

extern "C" void kernel_launch(void* const* d_in, const int* in_sizes, int n_in,
                              void* d_out, int out_size, void* d_ws, size_t ws_size,
                              hipStream_t stream) {
    const int*   l_ei     = (const int*)d_in[0];
    const int*   c_ei     = (const int*)d_in[1];
    const int*   l_batch  = (const int*)d_in[2];
    const float* l_init   = (const float*)d_in[3];
    const float* c_init   = (const float*)d_in[4];
    const float* l2c_w1   = (const float*)d_in[5];
    const float* l2c_b1   = (const float*)d_in[6];
    const float* l2c_w2   = (const float*)d_in[7];
    const float* l2c_b2   = (const float*)d_in[8];
    const float* c2l_w1   = (const float*)d_in[9];
    const float* c2l_b1   = (const float*)d_in[10];
    const float* c2l_w2   = (const float*)d_in[11];
    const float* c2l_b2   = (const float*)d_in[12];
    const float* cgru_wih = (const float*)d_in[13];
    const float* cgru_whh = (const float*)d_in[14];
    const float* cgru_bih = (const float*)d_in[15];
    const float* cgru_bhh = (const float*)d_in[16];
    const float* lgru_wih = (const float*)d_in[17];
    const float* lgru_whh = (const float*)d_in[18];
    const float* lgru_bih = (const float*)d_in[19];
    const float* lgru_bhh = (const float*)d_in[20];
    const float* ro_w1    = (const float*)d_in[21];
    const float* ro_b1    = (const float*)d_in[22];
    const float* ro_w2    = (const float*)d_in[23];
    const float* ro_b2    = (const float*)d_in[24];

    const int E  = in_sizes[0];
    const int Lc = in_sizes[2];
    const int C  = CC;

    // ---- workspace carve (total ~195.5 MB; heavy aliasing) ----
    // pool_HA: max(C*D, 2*CHL*384) floats -> hidden | aggr | (gi_l,gh_l chunks)
    // pool_M : max(L*2D, C*D, 2*CHC*384) floats -> msg | xcat | (gi_c,gh_c chunks)
    const int CHC = 20000;   // clause GRU chunk rows: 2*20000*384*4 = 61.44 MB = L*2D*4
    const int CHL = 16384;   // literal GRU chunk rows: 2*16384*384*4 = 50.33 MB <= C*D*4
    char* p = (char*)d_ws;
    auto carve = [&](size_t bytes) { void* r = (void*)p; p += align_up_(bytes); return r; };
    float* l_emb   = (float*)carve((size_t)Lc * DD * 4);       // 30.72 MB
    float* c_emb   = (float*)carve((size_t)C * DD * 4);        // 51.2 MB
    float* l_deg   = (float*)carve((size_t)Lc * 4);
    float* c_deg   = (float*)carve((size_t)C * 4);
    float* pool_HA = (float*)carve((size_t)C * DD * 4);        // 51.2 MB
    float* pool_M  = (float*)carve((size_t)Lc * 2 * DD * 4);   // 61.44 MB
    float* g_sum   = (float*)carve((size_t)BB * 4);
    float* g_cnt   = (float*)carve((size_t)BB * 4);
    (void)ws_size; (void)n_in; (void)out_size;

    // degrees + init embeddings
    hipMemsetAsync(l_deg, 0, (size_t)Lc * 4, stream);
    hipMemsetAsync(c_deg, 0, (size_t)C * 4, stream);
    deg_kernel<<<(E + 255) / 256, 256, 0, stream>>>(l_ei, c_ei, l_deg, c_deg, E);
    bcast_init_kernel<<<((size_t)Lc * DD + 255) / 256, 256, 0, stream>>>(l_init, l_emb, Lc * DD);
    bcast_init_kernel<<<((size_t)C * DD + 255) / 256, 256, 0, stream>>>(c_init, c_emb, C * DD);

    for (int it = 0; it < N_ITER; ++it) {
        // ---- literal -> clause ----
        float* hidden = pool_HA;           // L*D
        float* msg    = pool_M;            // L*D
        launch_gemm(l_emb, l2c_w1, l2c_b1, hidden, Lc, 128, 128, nullptr, true, stream);
        launch_gemm(hidden, l2c_w2, l2c_b2, msg, Lc, 128, 128, nullptr, false, stream);
        float* aggr = pool_HA;             // C*D (hidden dead now)
        hipMemsetAsync(aggr, 0, (size_t)C * DD * 4, stream);
        scatter_kernel<<<(E + 3) / 4, 256, 0, stream>>>(msg, l_ei, c_ei, aggr, E);
        // chunked clause GRU: gi/gh chunks live in pool_M (msg dead now)
        {
            float* gi = pool_M;
            float* gh = pool_M + (size_t)CHC * 384;
            for (int r0 = 0; r0 < C; r0 += CHC) {
                int n = min(CHC, C - r0);
                launch_gemm(aggr + (size_t)r0 * DD, cgru_wih, cgru_bih, gi, n, 128, 384, c_deg + r0, false, stream);
                launch_gemm(c_emb + (size_t)r0 * DD, cgru_whh, cgru_bhh, gh, n, 128, 384, nullptr, false, stream);
                gru_kernel<<<((size_t)n * DD + 255) / 256, 256, 0, stream>>>(gi, gh, c_emb + (size_t)r0 * DD, n * DD);
            }
        }

        // ---- clause -> literal ----
        hidden = pool_HA;                  // C*D
        msg    = pool_M;                   // C*D
        launch_gemm(c_emb, c2l_w1, c2l_b1, hidden, C, 128, 128, nullptr, true, stream);
        launch_gemm(hidden, c2l_w2, c2l_b2, msg, C, 128, 128, nullptr, false, stream);
        aggr = pool_HA;                    // L*D (hidden dead)
        hipMemsetAsync(aggr, 0, (size_t)Lc * DD * 4, stream);
        scatter_kernel<<<(E + 3) / 4, 256, 0, stream>>>(msg, c_ei, l_ei, aggr, E);
        float* xcat = pool_M;              // L*2D (msg dead)
        xcat_kernel<<<((size_t)Lc * DD + 255) / 256, 256, 0, stream>>>(aggr, l_deg, l_emb, xcat, Lc * DD);
        // chunked literal GRU: gi/gh chunks live in pool_HA (aggr dead after xcat)
        {
            float* gi = pool_HA;
            float* gh = pool_HA + (size_t)CHL * 384;
            for (int r0 = 0; r0 < Lc; r0 += CHL) {
                int n = min(CHL, Lc - r0);
                launch_gemm(xcat + (size_t)r0 * 2 * DD, lgru_wih, lgru_bih, gi, n, 256, 384, nullptr, false, stream);
                launch_gemm(l_emb + (size_t)r0 * DD, lgru_whh, lgru_bhh, gh, n, 128, 384, nullptr, false, stream);
                gru_kernel<<<((size_t)n * DD + 255) / 256, 256, 0, stream>>>(gi, gh, l_emb + (size_t)r0 * DD, n * DD);
            }
        }
    }

    // ---- readout ----
    float* hidden = pool_HA;
    launch_gemm(l_emb, ro_w1, ro_b1, hidden, Lc, 128, 128, nullptr, true, stream);
    hipMemsetAsync(g_sum, 0, (size_t)BB * 4, stream);
    hipMemsetAsync(g_cnt, 0, (size_t)BB * 4, stream);
    logit_kernel<<<(Lc + 3) / 4, 256, 0, stream>>>(hidden, ro_w2, ro_b2, l_batch, g_sum, g_cnt, Lc);
    final_kernel<<<1, 64, 0, stream>>>(g_sum, g_cnt, (float*)d_out);
}

// Round 3
// 5006.981 us; speedup vs baseline: 1.3327x; 1.3327x over previous
//
#include <hip/hip_runtime.h>
#include <hip/hip_bf16.h>

#define DD 128
#define CC 100000
#define BB 32
#define N_ITER 4
#define INV_INIT_NORM 0.125f   // 1 / (sqrt(128)/sqrt(2)) = 1/8

typedef __attribute__((ext_vector_type(8))) short  frag_ab;   // 8 bf16 in 4 VGPRs
typedef __attribute__((ext_vector_type(4))) float  f32x4;
typedef __attribute__((ext_vector_type(4))) unsigned short us4;

__device__ __forceinline__ unsigned short f2bf(float f) {
    union { float f; unsigned u; } v; v.f = f;
    unsigned r = v.u + 0x7fff + ((v.u >> 16) & 1);   // RNE
    return (unsigned short)(r >> 16);
}
__device__ __forceinline__ float bf2f(unsigned short h) {
    union { unsigned u; float f; } v; v.u = ((unsigned)h) << 16;
    return v.f;
}

// ---------------- init / degree ----------------

__global__ void bcast_init_kernel(const float* __restrict__ init, float* __restrict__ emb, int n) {
    int i = blockIdx.x * 256 + threadIdx.x;
    if (i < n) emb[i] = init[i & (DD - 1)] * INV_INIT_NORM;
}

__global__ void deg_kernel(const int* __restrict__ li, const int* __restrict__ ci,
                           float* __restrict__ ldeg, float* __restrict__ cdeg, int E) {
    int e = blockIdx.x * 256 + threadIdx.x;
    if (e < E) {
        atomicAdd(&ldeg[li[e]], 1.0f);
        atomicAdd(&cdeg[ci[e]], 1.0f);
    }
}

// ---------------- split-bf16 MFMA GEMM ----------------
// Y[N,M] = act(A[N,K] @ W[M,K]^T + bias), optional row scale 1/max(deg,1) on A.
// fp32 inputs split to bf16 hi+lo during LDS staging; 3 MFMA passes
// (Ah*Bh + Ah*Bl + Al*Bh) give ~fp32 accuracy at matrix-core rate.
// 128x128 tile, 4 waves (2x2 of 64x64), BK=32, 16x16x32 bf16 MFMA.
// LDS layout [g][128][8] ushort with row ^= g<<1 swizzle: conflict-free writes,
// 2-way (free) frag reads.

template<bool RELU, bool ROWSCALE>
__global__ __launch_bounds__(256)
void mfma_gemm(const float* __restrict__ A, const float* __restrict__ W,
               const float* __restrict__ bias, float* __restrict__ Y,
               int N, int K, int M, const float* __restrict__ deg) {
    __shared__ unsigned short Ah[4][128][8], Al[4][128][8];
    __shared__ unsigned short Wh[4][128][8], Wl[4][128][8];

    const int tid = threadIdx.x;
    const int bn = blockIdx.x * 128;
    const int bm = blockIdx.y * 128;
    const int l  = tid & 63;
    const int w  = tid >> 6;
    const int wr = w >> 1, wc = w & 1;
    const int lr = l & 15, lg = l >> 4;

    f32x4 acc[4][4];
#pragma unroll
    for (int i = 0; i < 4; ++i)
#pragma unroll
        for (int j = 0; j < 4; ++j) acc[i][j] = (f32x4){0.f, 0.f, 0.f, 0.f};

    for (int k0 = 0; k0 < K; k0 += 32) {
        // ---- stage + split A and W tiles (128 rows x 32 k each) ----
#pragma unroll
        for (int t = 0; t < 4; ++t) {
            const int f   = t * 256 + tid;       // 0..1023 float4 slots
            const int row = f >> 3;              // 0..127
            const int kq  = f & 7;               // float4 within 32-k row
            const int g   = kq >> 1;             // k-octet 0..3
            const int hf  = (kq & 1) * 4;        // half within octet
            const int rs  = row ^ (g << 1);      // swizzled row

            // A
            float ax = 0.f, ay = 0.f, az = 0.f, aw = 0.f;
            const int gr = bn + row;
            if (gr < N) {
                const float4 va = *(const float4*)(A + (size_t)gr * K + k0 + kq * 4);
                float s = 1.0f;
                if (ROWSCALE) s = 1.0f / fmaxf(deg[gr], 1.0f);
                ax = va.x * s; ay = va.y * s; az = va.z * s; aw = va.w * s;
            }
            us4 h, lo;
            h[0] = f2bf(ax); h[1] = f2bf(ay); h[2] = f2bf(az); h[3] = f2bf(aw);
            lo[0] = f2bf(ax - bf2f(h[0])); lo[1] = f2bf(ay - bf2f(h[1]));
            lo[2] = f2bf(az - bf2f(h[2])); lo[3] = f2bf(aw - bf2f(h[3]));
            *(us4*)&Ah[g][rs][hf] = h;
            *(us4*)&Al[g][rs][hf] = lo;

            // W (M is a multiple of 128, no guard)
            const float4 vw = *(const float4*)(W + (size_t)(bm + row) * K + k0 + kq * 4);
            h[0] = f2bf(vw.x); h[1] = f2bf(vw.y); h[2] = f2bf(vw.z); h[3] = f2bf(vw.w);
            lo[0] = f2bf(vw.x - bf2f(h[0])); lo[1] = f2bf(vw.y - bf2f(h[1]));
            lo[2] = f2bf(vw.z - bf2f(h[2])); lo[3] = f2bf(vw.w - bf2f(h[3]));
            *(us4*)&Wh[g][rs][hf] = h;
            *(us4*)&Wl[g][rs][hf] = lo;
        }
        __syncthreads();

        // ---- fragment loads ----
        frag_ab a_h[4], a_l[4], b_h[4], b_l[4];
#pragma unroll
        for (int i = 0; i < 4; ++i) {
            const int ra = wr * 64 + i * 16 + lr, rsa = ra ^ (lg << 1);
            a_h[i] = *(const frag_ab*)&Ah[lg][rsa][0];
            a_l[i] = *(const frag_ab*)&Al[lg][rsa][0];
            const int rb = wc * 64 + i * 16 + lr, rsb = rb ^ (lg << 1);
            b_h[i] = *(const frag_ab*)&Wh[lg][rsb][0];
            b_l[i] = *(const frag_ab*)&Wl[lg][rsb][0];
        }

        // ---- 3-pass MFMA ----
#pragma unroll
        for (int i = 0; i < 4; ++i)
#pragma unroll
            for (int j = 0; j < 4; ++j) {
                acc[i][j] = __builtin_amdgcn_mfma_f32_16x16x32_bf16(a_h[i], b_h[j], acc[i][j], 0, 0, 0);
                acc[i][j] = __builtin_amdgcn_mfma_f32_16x16x32_bf16(a_h[i], b_l[j], acc[i][j], 0, 0, 0);
                acc[i][j] = __builtin_amdgcn_mfma_f32_16x16x32_bf16(a_l[i], b_h[j], acc[i][j], 0, 0, 0);
            }
        __syncthreads();
    }

    // ---- epilogue: C/D layout col = lane&15, row = (lane>>4)*4 + reg ----
#pragma unroll
    for (int j = 0; j < 4; ++j) {
        const int gc = bm + wc * 64 + j * 16 + lr;
        const float bj = bias[gc];
#pragma unroll
        for (int i = 0; i < 4; ++i) {
            const int grb = bn + wr * 64 + i * 16 + lg * 4;
#pragma unroll
            for (int r = 0; r < 4; ++r) {
                const int gr = grb + r;
                if (gr < N) {
                    float o = acc[i][j][r] + bj;
                    if (RELU) o = fmaxf(o, 0.f);
                    Y[(size_t)gr * M + gc] = o;
                }
            }
        }
    }
}

// ---------------- edge scatter: aggr[dst[e]] += msg[src[e]] ----------------

__global__ void scatter_kernel(const float* __restrict__ msg, const int* __restrict__ src,
                               const int* __restrict__ dst, float* __restrict__ aggr, int E) {
    int e = blockIdx.x * 4 + (threadIdx.x >> 6);
    if (e >= E) return;
    int lane = threadIdx.x & 63;
    const float2 m = ((const float2*)(msg + (size_t)src[e] * DD))[lane];
    float* d = aggr + (size_t)dst[e] * DD;
    atomicAdd(d + 2 * lane + 0, m.x);
    atomicAdd(d + 2 * lane + 1, m.y);
}

// ---------------- GRU elementwise (float4) ----------------

__device__ __forceinline__ float sigmoidf_(float x) { return 1.0f / (1.0f + expf(-x)); }

__global__ void gru4_kernel(const float* __restrict__ gi, const float* __restrict__ gh,
                            float* __restrict__ h, int n4) {
    int i = blockIdx.x * 256 + threadIdx.x;
    if (i >= n4) return;
    int r = i >> 5, c = i & 31;                 // 32 float4 per 128-row
    const float4* gi4 = (const float4*)gi;
    const float4* gh4 = (const float4*)gh;
    float4* h4 = (float4*)h;
    size_t b = (size_t)r * 96 + c;              // 96 float4 per 384-row
    float4 ir = gi4[b], iz = gi4[b + 32], in_ = gi4[b + 64];
    float4 hr = gh4[b], hz = gh4[b + 32], hn = gh4[b + 64];
    float4 hv = h4[(size_t)r * 32 + c];
    float4 o;
    {
        float rg = sigmoidf_(ir.x + hr.x), zg = sigmoidf_(iz.x + hz.x);
        float ng = tanhf(in_.x + rg * hn.x);
        o.x = (1.f - zg) * ng + zg * hv.x;
    }
    {
        float rg = sigmoidf_(ir.y + hr.y), zg = sigmoidf_(iz.y + hz.y);
        float ng = tanhf(in_.y + rg * hn.y);
        o.y = (1.f - zg) * ng + zg * hv.y;
    }
    {
        float rg = sigmoidf_(ir.z + hr.z), zg = sigmoidf_(iz.z + hz.z);
        float ng = tanhf(in_.z + rg * hn.z);
        o.z = (1.f - zg) * ng + zg * hv.z;
    }
    {
        float rg = sigmoidf_(ir.w + hr.w), zg = sigmoidf_(iz.w + hz.w);
        float ng = tanhf(in_.w + rg * hn.w);
        o.w = (1.f - zg) * ng + zg * hv.w;
    }
    h4[(size_t)r * 32 + c] = o;
}

// ---------------- xcat (float4): [aggr/l_deg , l_emb[l^1]] ----------------

__global__ void xcat4_kernel(const float* __restrict__ aggr, const float* __restrict__ ldeg,
                             const float* __restrict__ lemb, float* __restrict__ xcat, int n4) {
    int i = blockIdx.x * 256 + threadIdx.x;
    if (i >= n4) return;
    int lrow = i >> 5, c = i & 31;
    float s = 1.0f / fmaxf(ldeg[lrow], 1.0f);
    const float4* a4 = (const float4*)aggr;
    const float4* e4 = (const float4*)lemb;
    float4* x4 = (float4*)xcat;
    float4 a = a4[(size_t)lrow * 32 + c];
    a.x *= s; a.y *= s; a.z *= s; a.w *= s;
    x4[(size_t)lrow * 64 + c] = a;
    x4[(size_t)lrow * 64 + 32 + c] = e4[(size_t)(lrow ^ 1) * 32 + c];
}

// ---------------- readout: two-stage reduction, LDS bins ----------------

__global__ __launch_bounds__(256)
void logit2_kernel(const float* __restrict__ hidden, const float* __restrict__ w2,
                   const int* __restrict__ l_batch,
                   float* __restrict__ gsum, float* __restrict__ gcnt, int Lc) {
    __shared__ float s_sum[BB];
    __shared__ float s_cnt[BB];
    const int tid = threadIdx.x;
    if (tid < BB) { s_sum[tid] = 0.f; s_cnt[tid] = 0.f; }
    __syncthreads();
    const int lane = tid & 63;
    const int gw = blockIdx.x * 4 + (tid >> 6);
    const int nw = gridDim.x * 4;
    const float2 wv = ((const float2*)w2)[lane];
    for (int row = gw; row < Lc; row += nw) {
        float2 h = ((const float2*)(hidden + (size_t)row * DD))[lane];
        float dp = h.x * wv.x + h.y * wv.y;
#pragma unroll
        for (int off = 32; off > 0; off >>= 1) dp += __shfl_down(dp, off);
        if (lane == 0) {
            int b = l_batch[row];
            atomicAdd(&s_sum[b], dp);
            atomicAdd(&s_cnt[b], 1.0f);
        }
    }
    __syncthreads();
    if (tid < BB) {
        atomicAdd(&gsum[tid], s_sum[tid]);
        atomicAdd(&gcnt[tid], s_cnt[tid]);
    }
}

__global__ void final_kernel(const float* __restrict__ gsum, const float* __restrict__ gcnt,
                             const float* __restrict__ b2, float* __restrict__ out) {
    int b = threadIdx.x;
    if (b < BB) {
        float m = gsum[b] / fmaxf(gcnt[b], 1.0f) + b2[0];
        out[b] = 1.0f / (1.0f + expf(-m));
    }
}

// ---------------- host side ----------------

static inline size_t align_up_(size_t x) { return (x + 255) & ~(size_t)255; }
static inline int imin_(int a, int b) { return a < b ? a : b; }

static void launch_gemm(const float* A, const float* W, const float* bias, float* Y,
                        int N, int K, int M, const float* deg, bool relu, hipStream_t stream) {
    dim3 g((N + 127) / 128, M / 128);
    if (relu) {
        if (deg) mfma_gemm<true, true><<<g, 256, 0, stream>>>(A, W, bias, Y, N, K, M, deg);
        else     mfma_gemm<true, false><<<g, 256, 0, stream>>>(A, W, bias, Y, N, K, M, nullptr);
    } else {
        if (deg) mfma_gemm<false, true><<<g, 256, 0, stream>>>(A, W, bias, Y, N, K, M, deg);
        else     mfma_gemm<false, false><<<g, 256, 0, stream>>>(A, W, bias, Y, N, K, M, nullptr);
    }
}

extern "C" void kernel_launch(void* const* d_in, const int* in_sizes, int n_in,
                              void* d_out, int out_size, void* d_ws, size_t ws_size,
                              hipStream_t stream) {
    const int*   l_ei     = (const int*)d_in[0];
    const int*   c_ei     = (const int*)d_in[1];
    const int*   l_batch  = (const int*)d_in[2];
    const float* l_init   = (const float*)d_in[3];
    const float* c_init   = (const float*)d_in[4];
    const float* l2c_w1   = (const float*)d_in[5];
    const float* l2c_b1   = (const float*)d_in[6];
    const float* l2c_w2   = (const float*)d_in[7];
    const float* l2c_b2   = (const float*)d_in[8];
    const float* c2l_w1   = (const float*)d_in[9];
    const float* c2l_b1   = (const float*)d_in[10];
    const float* c2l_w2   = (const float*)d_in[11];
    const float* c2l_b2   = (const float*)d_in[12];
    const float* cgru_wih = (const float*)d_in[13];
    const float* cgru_whh = (const float*)d_in[14];
    const float* cgru_bih = (const float*)d_in[15];
    const float* cgru_bhh = (const float*)d_in[16];
    const float* lgru_wih = (const float*)d_in[17];
    const float* lgru_whh = (const float*)d_in[18];
    const float* lgru_bih = (const float*)d_in[19];
    const float* lgru_bhh = (const float*)d_in[20];
    const float* ro_w1    = (const float*)d_in[21];
    const float* ro_b1    = (const float*)d_in[22];
    const float* ro_w2    = (const float*)d_in[23];
    const float* ro_b2    = (const float*)d_in[24];

    const int E  = in_sizes[0];
    const int Lc = in_sizes[2];
    const int C  = CC;

    // workspace carve (~195.5 MB, heavy aliasing — proven safe in R2)
    const int CHC = 20000;   // clause GRU chunk rows (gates fit pool_M)
    const int CHL = 16384;   // literal GRU chunk rows (gates fit pool_HA)
    char* p = (char*)d_ws;
    auto carve = [&](size_t bytes) { void* r = (void*)p; p += align_up_(bytes); return r; };
    float* l_emb   = (float*)carve((size_t)Lc * DD * 4);
    float* c_emb   = (float*)carve((size_t)C * DD * 4);
    float* l_deg   = (float*)carve((size_t)Lc * 4);
    float* c_deg   = (float*)carve((size_t)C * 4);
    float* pool_HA = (float*)carve((size_t)C * DD * 4);
    float* pool_M  = (float*)carve((size_t)Lc * 2 * DD * 4);
    float* g_sum   = (float*)carve((size_t)BB * 4);
    float* g_cnt   = (float*)carve((size_t)BB * 4);
    (void)ws_size; (void)n_in; (void)out_size;

    hipMemsetAsync(l_deg, 0, (size_t)Lc * 4, stream);
    hipMemsetAsync(c_deg, 0, (size_t)C * 4, stream);
    deg_kernel<<<(E + 255) / 256, 256, 0, stream>>>(l_ei, c_ei, l_deg, c_deg, E);
    bcast_init_kernel<<<((size_t)Lc * DD + 255) / 256, 256, 0, stream>>>(l_init, l_emb, Lc * DD);
    bcast_init_kernel<<<((size_t)C * DD + 255) / 256, 256, 0, stream>>>(c_init, c_emb, C * DD);

    for (int it = 0; it < N_ITER; ++it) {
        // ---- literal -> clause ----
        float* hidden = pool_HA;
        float* msg    = pool_M;
        launch_gemm(l_emb, l2c_w1, l2c_b1, hidden, Lc, 128, 128, nullptr, true, stream);
        launch_gemm(hidden, l2c_w2, l2c_b2, msg, Lc, 128, 128, nullptr, false, stream);
        float* aggr = pool_HA;
        hipMemsetAsync(aggr, 0, (size_t)C * DD * 4, stream);
        scatter_kernel<<<(E + 3) / 4, 256, 0, stream>>>(msg, l_ei, c_ei, aggr, E);
        {
            float* gi = pool_M;
            float* gh = pool_M + (size_t)CHC * 384;
            for (int r0 = 0; r0 < C; r0 += CHC) {
                int n = imin_(CHC, C - r0);
                launch_gemm(aggr + (size_t)r0 * DD, cgru_wih, cgru_bih, gi, n, 128, 384, c_deg + r0, false, stream);
                launch_gemm(c_emb + (size_t)r0 * DD, cgru_whh, cgru_bhh, gh, n, 128, 384, nullptr, false, stream);
                gru4_kernel<<<((size_t)n * 32 + 255) / 256, 256, 0, stream>>>(gi, gh, c_emb + (size_t)r0 * DD, n * 32);
            }
        }

        // ---- clause -> literal ----
        hidden = pool_HA;
        msg    = pool_M;
        launch_gemm(c_emb, c2l_w1, c2l_b1, hidden, C, 128, 128, nullptr, true, stream);
        launch_gemm(hidden, c2l_w2, c2l_b2, msg, C, 128, 128, nullptr, false, stream);
        aggr = pool_HA;
        hipMemsetAsync(aggr, 0, (size_t)Lc * DD * 4, stream);
        scatter_kernel<<<(E + 3) / 4, 256, 0, stream>>>(msg, c_ei, l_ei, aggr, E);
        float* xcat = pool_M;
        xcat4_kernel<<<((size_t)Lc * 32 + 255) / 256, 256, 0, stream>>>(aggr, l_deg, l_emb, xcat, Lc * 32);
        {
            float* gi = pool_HA;
            float* gh = pool_HA + (size_t)CHL * 384;
            for (int r0 = 0; r0 < Lc; r0 += CHL) {
                int n = imin_(CHL, Lc - r0);
                launch_gemm(xcat + (size_t)r0 * 2 * DD, lgru_wih, lgru_bih, gi, n, 256, 384, nullptr, false, stream);
                launch_gemm(l_emb + (size_t)r0 * DD, lgru_whh, lgru_bhh, gh, n, 128, 384, nullptr, false, stream);
                gru4_kernel<<<((size_t)n * 32 + 255) / 256, 256, 0, stream>>>(gi, gh, l_emb + (size_t)r0 * DD, n * 32);
            }
        }
    }

    // ---- readout ----
    float* hidden = pool_HA;
    launch_gemm(l_emb, ro_w1, ro_b1, hidden, Lc, 128, 128, nullptr, true, stream);
    hipMemsetAsync(g_sum, 0, (size_t)BB * 4, stream);
    hipMemsetAsync(g_cnt, 0, (size_t)BB * 4, stream);
    logit2_kernel<<<256, 256, 0, stream>>>(hidden, ro_w2, l_batch, g_sum, g_cnt, Lc);
    final_kernel<<<1, 64, 0, stream>>>(g_sum, g_cnt, ro_b2, (float*)d_out);
}

// Round 4
// 3014.010 us; speedup vs baseline: 2.2139x; 1.6612x over previous
//
#include <hip/hip_runtime.h>
#include <hip/hip_bf16.h>

#define DD 128
#define CC 100000
#define BB 32
#define N_ITER 4
#define INV_INIT_NORM 0.125f   // 1/(sqrt(128)/sqrt(2)) = 1/8

typedef unsigned short u16;
typedef __attribute__((ext_vector_type(8))) short  frag_ab;   // 8 bf16 (4 VGPRs)
typedef __attribute__((ext_vector_type(4))) float  f32x4;
typedef __attribute__((ext_vector_type(8))) unsigned short us8;
typedef __attribute__((ext_vector_type(4))) unsigned short us4;

__device__ __forceinline__ u16 f2bf(float f) {
    union { float f; unsigned u; } v; v.f = f;
    unsigned r = v.u + 0x7fff + ((v.u >> 16) & 1);   // RNE
    return (u16)(r >> 16);
}
__device__ __forceinline__ float bf2f(u16 h) {
    union { unsigned u; float f; } v; v.u = ((unsigned)h) << 16;
    return v.f;
}

// ---------------- precompute: degrees / scan / CSR fill ----------------

__global__ void ideg_kernel(const int* __restrict__ li, const int* __restrict__ ci,
                            int* __restrict__ idl, int* __restrict__ idc, int E) {
    int e = blockIdx.x * 256 + threadIdx.x;
    if (e < E) {
        atomicAdd(&idl[li[e]], 1);
        atomicAdd(&idc[ci[e]], 1);
    }
}

// single-block exclusive scan (1024 threads, 4 elems/thread, shfl wave scans)
__global__ void scan_kernel(const int* __restrict__ deg, int* __restrict__ off, int n) {
    __shared__ int wsum[16];
    __shared__ int carry_s;
    const int tid = threadIdx.x, lane = tid & 63, wid = tid >> 6;
    if (tid == 0) carry_s = 0;
    __syncthreads();
    for (int base = 0; base < n; base += 4096) {
        int idx = base + tid * 4;
        int v0 = idx     < n ? deg[idx]     : 0;
        int v1 = idx + 1 < n ? deg[idx + 1] : 0;
        int v2 = idx + 2 < n ? deg[idx + 2] : 0;
        int v3 = idx + 3 < n ? deg[idx + 3] : 0;
        int t = v0 + v1 + v2 + v3;
        int s = t;
#pragma unroll
        for (int o = 1; o < 64; o <<= 1) { int u = __shfl_up(s, o); if (lane >= o) s += u; }
        if (lane == 63) wsum[wid] = s;
        __syncthreads();
        if (wid == 0 && lane < 16) {
            int x = wsum[lane];
#pragma unroll
            for (int o = 1; o < 16; o <<= 1) { int u = __shfl_up(x, o); if (lane >= o) x += u; }
            wsum[lane] = x;
        }
        __syncthreads();
        int woff = (wid > 0) ? wsum[wid - 1] : 0;
        int excl = carry_s + woff + s - t;
        if (idx     < n) off[idx]     = excl;
        if (idx + 1 < n) off[idx + 1] = excl + v0;
        if (idx + 2 < n) off[idx + 2] = excl + v0 + v1;
        if (idx + 3 < n) off[idx + 3] = excl + v0 + v1 + v2;
        __syncthreads();
        if (tid == 0) carry_s += wsum[15];
        __syncthreads();
    }
    if (threadIdx.x == 0) off[n] = carry_s;
}

__global__ void fill_kernel(const int* __restrict__ dst, const int* __restrict__ src,
                            const int* __restrict__ off, int* __restrict__ fill,
                            int* __restrict__ edges, int E) {
    int e = blockIdx.x * 256 + threadIdx.x;
    if (e < E) {
        int d = dst[e];
        int p = atomicAdd(&fill[d], 1);
        edges[off[d] + p] = src[e];
    }
}

// ---------------- precompute: weight folds / splits ----------------

// out[o*out_ld + k] = sum_m wih[o*ldw + m] * w2[m*128 + k]   (o < M, k < 128)
__global__ void foldw_kernel(const float* __restrict__ wih, int ldw,
                             const float* __restrict__ w2,
                             float* __restrict__ out, int out_ld, int M) {
    int idx = blockIdx.x * 256 + threadIdx.x;
    if (idx >= M * 128) return;
    int o = idx >> 7, k = idx & 127;
    float s = 0.f;
    for (int m = 0; m < 128; ++m) s += wih[(size_t)o * ldw + m] * w2[m * 128 + k];
    out[(size_t)o * out_ld + k] = s;
}

// out[o] = sum_m wih[o*ldw + m] * b2[m]
__global__ void foldb_kernel(const float* __restrict__ wih, int ldw,
                             const float* __restrict__ b2,
                             float* __restrict__ out, int M) {
    int o = blockIdx.x * 256 + threadIdx.x;
    if (o >= M) return;
    float s = 0.f;
    for (int m = 0; m < 128; ++m) s += wih[(size_t)o * ldw + m] * b2[m];
    out[o] = s;
}

__global__ void splitw_kernel(const float* __restrict__ w, u16* __restrict__ hi,
                              u16* __restrict__ lo, int n) {
    int i = blockIdx.x * 256 + threadIdx.x;
    if (i < n) {
        float f = w[i];
        u16 h = f2bf(f);
        hi[i] = h;
        lo[i] = f2bf(f - bf2f(h));
    }
}

__global__ void init_emb_kernel(const float* __restrict__ init, u16* __restrict__ hi,
                                u16* __restrict__ lo, int n) {
    int i = blockIdx.x * 256 + threadIdx.x;
    if (i < n) {
        float f = init[i & (DD - 1)] * INV_INIT_NORM;
        u16 h = f2bf(f);
        hi[i] = h;
        lo[i] = f2bf(f - bf2f(h));
    }
}

// ---------------- MFMA GEMM on pre-split bf16 hi/lo ----------------
// Y[N,M] = act(A[N,K] @ W[M,K]^T + bias (+ bias2 if deg>0))
// A given as hi/lo ushort planes (ld 128). XCAT: k<128 from A (h_agg, pre-scaled),
// k>=128 from A2 rows gr^1 (l_emb). W pre-split, ld K. 3-pass split-bf16 MFMA.

template<bool RELU, bool XCAT, bool BIAS2>
__global__ __launch_bounds__(256)
void mfma_gemm(const u16* __restrict__ Ahi, const u16* __restrict__ Alo,
               const u16* __restrict__ A2hi, const u16* __restrict__ A2lo,
               const u16* __restrict__ Whi, const u16* __restrict__ Wlo,
               const float* __restrict__ bias, const float* __restrict__ bias2,
               const int* __restrict__ ideg,
               float* __restrict__ Y, int N, int K, int M) {
    __shared__ u16 Ah[4][128][8], Al[4][128][8], Wh[4][128][8], Wl[4][128][8];

    const int tid = threadIdx.x;
    const int bn = blockIdx.x * 128, bm = blockIdx.y * 128;
    const int l = tid & 63, w = tid >> 6;
    const int wr = w >> 1, wc = w & 1;
    const int lr = l & 15, lg = l >> 4;

    f32x4 acc[4][4];
#pragma unroll
    for (int i = 0; i < 4; ++i)
#pragma unroll
        for (int j = 0; j < 4; ++j) acc[i][j] = (f32x4){0.f, 0.f, 0.f, 0.f};

    for (int k0 = 0; k0 < K; k0 += 32) {
#pragma unroll
        for (int t = 0; t < 2; ++t) {
            const int slot = t * 256 + tid;
            const int row = slot >> 2, g = slot & 3, rs = row ^ (g << 1);
            const int gr = bn + row;
            us8 vh = (us8)0, vl = (us8)0;
            if (gr < N) {
                if (XCAT && k0 >= 128) {
                    const size_t o = (size_t)(gr ^ 1) * 128 + (k0 - 128) + g * 8;
                    vh = *(const us8*)(A2hi + o);
                    vl = *(const us8*)(A2lo + o);
                } else {
                    const size_t o = (size_t)gr * 128 + k0 + g * 8;
                    vh = *(const us8*)(Ahi + o);
                    vl = *(const us8*)(Alo + o);
                }
            }
            *(us8*)&Ah[g][rs][0] = vh;
            *(us8*)&Al[g][rs][0] = vl;
            const size_t wo = (size_t)(bm + row) * K + k0 + g * 8;
            *(us8*)&Wh[g][rs][0] = *(const us8*)(Whi + wo);
            *(us8*)&Wl[g][rs][0] = *(const us8*)(Wlo + wo);
        }
        __syncthreads();

        frag_ab a_h[4], a_l[4], b_h[4], b_l[4];
#pragma unroll
        for (int i = 0; i < 4; ++i) {
            const int ra = wr * 64 + i * 16 + lr, rsa = ra ^ (lg << 1);
            a_h[i] = *(const frag_ab*)&Ah[lg][rsa][0];
            a_l[i] = *(const frag_ab*)&Al[lg][rsa][0];
            const int rb = wc * 64 + i * 16 + lr, rsb = rb ^ (lg << 1);
            b_h[i] = *(const frag_ab*)&Wh[lg][rsb][0];
            b_l[i] = *(const frag_ab*)&Wl[lg][rsb][0];
        }
#pragma unroll
        for (int i = 0; i < 4; ++i)
#pragma unroll
            for (int j = 0; j < 4; ++j) {
                acc[i][j] = __builtin_amdgcn_mfma_f32_16x16x32_bf16(a_h[i], b_h[j], acc[i][j], 0, 0, 0);
                acc[i][j] = __builtin_amdgcn_mfma_f32_16x16x32_bf16(a_h[i], b_l[j], acc[i][j], 0, 0, 0);
                acc[i][j] = __builtin_amdgcn_mfma_f32_16x16x32_bf16(a_l[i], b_h[j], acc[i][j], 0, 0, 0);
            }
        __syncthreads();
    }

    // epilogue: C/D layout col = lane&15, row = (lane>>4)*4 + reg
#pragma unroll
    for (int j = 0; j < 4; ++j) {
        const int gc = bm + wc * 64 + j * 16 + lr;
        const float bj = bias[gc];
        const float b2j = BIAS2 ? bias2[gc] : 0.f;
#pragma unroll
        for (int i = 0; i < 4; ++i) {
            const int grb = bn + wr * 64 + i * 16 + lg * 4;
#pragma unroll
            for (int r = 0; r < 4; ++r) {
                const int gr = grb + r;
                if (gr < N) {
                    float o = acc[i][j][r] + bj;
                    if (BIAS2) { if (ideg[gr] > 0) o += b2j; }
                    if (RELU) o = fmaxf(o, 0.f);
                    Y[(size_t)gr * M + gc] = o;
                }
            }
        }
    }
}

// ---------------- CSR gather: out[row] = (1/max(deg,1)) * sum over edges of h[src] ----------------
// writes split bf16 hi/lo planes

__global__ void gather_kernel(const float* __restrict__ h, const int* __restrict__ off,
                              const int* __restrict__ edges,
                              u16* __restrict__ ohi, u16* __restrict__ olo, int n) {
    int row = blockIdx.x * 4 + (threadIdx.x >> 6);
    if (row >= n) return;
    int lane = threadIdx.x & 63;
    int s = off[row], e = off[row + 1];
    float ax = 0.f, ay = 0.f;
    for (int i = s; i < e; ++i) {
        const float2 v = ((const float2*)(h + (size_t)edges[i] * DD))[lane];
        ax += v.x; ay += v.y;
    }
    float sc = 1.0f / (float)((e - s) > 0 ? (e - s) : 1);
    ax *= sc; ay *= sc;
    u16 h0 = f2bf(ax), h1 = f2bf(ay);
    u16 l0 = f2bf(ax - bf2f(h0)), l1 = f2bf(ay - bf2f(h1));
    *(ushort2*)(ohi + (size_t)row * DD + 2 * lane) = make_ushort2(h0, h1);
    *(ushort2*)(olo + (size_t)row * DD + 2 * lane) = make_ushort2(l0, l1);
}

// ---------------- GRU elementwise (4 elems/thread), h stored split ----------------

__device__ __forceinline__ float sigmoidf_(float x) { return 1.0f / (1.0f + expf(-x)); }

__global__ void gru4_kernel(const float* __restrict__ gi, const float* __restrict__ gh,
                            u16* __restrict__ hhi, u16* __restrict__ hlo, int n4) {
    int i = blockIdx.x * 256 + threadIdx.x;
    if (i >= n4) return;
    int r = i >> 5, c = i & 31;
    const float4* gi4 = (const float4*)gi;
    const float4* gh4 = (const float4*)gh;
    size_t b = (size_t)r * 96 + c;
    float4 ir = gi4[b], iz = gi4[b + 32], in_ = gi4[b + 64];
    float4 hr = gh4[b], hz = gh4[b + 32], hn = gh4[b + 64];
    us4 vh = *(const us4*)(hhi + (size_t)i * 4);
    us4 vl = *(const us4*)(hlo + (size_t)i * 4);
    float hv[4], o[4];
    float irr[4] = {ir.x, ir.y, ir.z, ir.w}, izz[4] = {iz.x, iz.y, iz.z, iz.w},
          inn[4] = {in_.x, in_.y, in_.z, in_.w};
    float hrr[4] = {hr.x, hr.y, hr.z, hr.w}, hzz[4] = {hz.x, hz.y, hz.z, hz.w},
          hnn[4] = {hn.x, hn.y, hn.z, hn.w};
#pragma unroll
    for (int k = 0; k < 4; ++k) {
        hv[k] = bf2f(vh[k]) + bf2f(vl[k]);
        float rg = sigmoidf_(irr[k] + hrr[k]);
        float zg = sigmoidf_(izz[k] + hzz[k]);
        float ng = tanhf(inn[k] + rg * hnn[k]);
        o[k] = (1.f - zg) * ng + zg * hv[k];
    }
    us4 oh, ol;
#pragma unroll
    for (int k = 0; k < 4; ++k) {
        oh[k] = f2bf(o[k]);
        ol[k] = f2bf(o[k] - bf2f(oh[k]));
    }
    *(us4*)(hhi + (size_t)i * 4) = oh;
    *(us4*)(hlo + (size_t)i * 4) = ol;
}

// ---------------- readout ----------------

__global__ __launch_bounds__(256)
void logit2_kernel(const float* __restrict__ hidden, const float* __restrict__ w2,
                   const int* __restrict__ l_batch,
                   float* __restrict__ gsum, float* __restrict__ gcnt, int Lc) {
    __shared__ float s_sum[BB];
    __shared__ float s_cnt[BB];
    const int tid = threadIdx.x;
    if (tid < BB) { s_sum[tid] = 0.f; s_cnt[tid] = 0.f; }
    __syncthreads();
    const int lane = tid & 63;
    const int gw = blockIdx.x * 4 + (tid >> 6);
    const int nw = gridDim.x * 4;
    const float2 wv = ((const float2*)w2)[lane];
    for (int row = gw; row < Lc; row += nw) {
        float2 h = ((const float2*)(hidden + (size_t)row * DD))[lane];
        float dp = h.x * wv.x + h.y * wv.y;
#pragma unroll
        for (int off = 32; off > 0; off >>= 1) dp += __shfl_down(dp, off);
        if (lane == 0) {
            int b = l_batch[row];
            atomicAdd(&s_sum[b], dp);
            atomicAdd(&s_cnt[b], 1.0f);
        }
    }
    __syncthreads();
    if (tid < BB) {
        atomicAdd(&gsum[tid], s_sum[tid]);
        atomicAdd(&gcnt[tid], s_cnt[tid]);
    }
}

__global__ void final_kernel(const float* __restrict__ gsum, const float* __restrict__ gcnt,
                             const float* __restrict__ b2, float* __restrict__ out) {
    int b = threadIdx.x;
    if (b < BB) {
        float m = gsum[b] / fmaxf(gcnt[b], 1.0f) + b2[0];
        out[b] = 1.0f / (1.0f + expf(-m));
    }
}

// ---------------- host side ----------------

static inline size_t align_up_(size_t x) { return (x + 255) & ~(size_t)255; }
static inline int imin_(int a, int b) { return a < b ? a : b; }

extern "C" void kernel_launch(void* const* d_in, const int* in_sizes, int n_in,
                              void* d_out, int out_size, void* d_ws, size_t ws_size,
                              hipStream_t stream) {
    const int*   l_ei     = (const int*)d_in[0];
    const int*   c_ei     = (const int*)d_in[1];
    const int*   l_batch  = (const int*)d_in[2];
    const float* l_init   = (const float*)d_in[3];
    const float* c_init   = (const float*)d_in[4];
    const float* l2c_w1   = (const float*)d_in[5];
    const float* l2c_b1   = (const float*)d_in[6];
    const float* l2c_w2   = (const float*)d_in[7];
    const float* l2c_b2   = (const float*)d_in[8];
    const float* c2l_w1   = (const float*)d_in[9];
    const float* c2l_b1   = (const float*)d_in[10];
    const float* c2l_w2   = (const float*)d_in[11];
    const float* c2l_b2   = (const float*)d_in[12];
    const float* cgru_wih = (const float*)d_in[13];
    const float* cgru_whh = (const float*)d_in[14];
    const float* cgru_bih = (const float*)d_in[15];
    const float* cgru_bhh = (const float*)d_in[16];
    const float* lgru_wih = (const float*)d_in[17];
    const float* lgru_whh = (const float*)d_in[18];
    const float* lgru_bih = (const float*)d_in[19];
    const float* lgru_bhh = (const float*)d_in[20];
    const float* ro_w1    = (const float*)d_in[21];
    const float* ro_b1    = (const float*)d_in[22];
    const float* ro_w2    = (const float*)d_in[23];
    const float* ro_b2    = (const float*)d_in[24];

    const int E  = in_sizes[0];
    const int Lc = in_sizes[2];
    const int C  = CC;
    const int CH = 16384;    // GRU chunk rows (gates 2*CH*384*4 = 50.3MB fit pool1)

    // ---- workspace carve (~192 MB) ----
    char* p = (char*)d_ws;
    auto carve = [&](size_t bytes) { void* r = (void*)p; p += align_up_(bytes); return r; };
    u16*   l_emb_hi = (u16*)carve((size_t)Lc * DD * 2);
    u16*   l_emb_lo = (u16*)carve((size_t)Lc * DD * 2);
    u16*   c_emb_hi = (u16*)carve((size_t)C * DD * 2);
    u16*   c_emb_lo = (u16*)carve((size_t)C * DD * 2);
    float* pool1    = (float*)carve((size_t)C * DD * 4);      // hidden fp32 | gates
    u16*   hagg_hi  = (u16*)carve((size_t)C * DD * 2);
    u16*   hagg_lo  = (u16*)carve((size_t)C * DD * 2);
    int*   ideg_l   = (int*)carve((size_t)Lc * 4);
    int*   ideg_c   = (int*)carve((size_t)C * 4);
    int*   l_off    = (int*)carve((size_t)(Lc + 1) * 4);
    int*   c_off    = (int*)carve((size_t)(C + 1) * 4);
    int*   l_edges  = (int*)carve((size_t)E * 4);
    int*   c_edges  = (int*)carve((size_t)E * 4);
    int*   fillc    = (int*)carve((size_t)(C > Lc ? C : Lc) * 4);
    float* Wf_c     = (float*)carve((size_t)384 * 128 * 4);
    float* Wcat     = (float*)carve((size_t)384 * 256 * 4);
    float* bmsg_c   = (float*)carve(384 * 4);
    float* bmsg_l   = (float*)carve(384 * 4);
    u16* w_l2c1_h = (u16*)carve(128 * 128 * 2); u16* w_l2c1_l = (u16*)carve(128 * 128 * 2);
    u16* w_c2l1_h = (u16*)carve(128 * 128 * 2); u16* w_c2l1_l = (u16*)carve(128 * 128 * 2);
    u16* w_ro1_h  = (u16*)carve(128 * 128 * 2); u16* w_ro1_l  = (u16*)carve(128 * 128 * 2);
    u16* w_gic_h  = (u16*)carve(384 * 128 * 2); u16* w_gic_l  = (u16*)carve(384 * 128 * 2);
    u16* w_ghc_h  = (u16*)carve(384 * 128 * 2); u16* w_ghc_l  = (u16*)carve(384 * 128 * 2);
    u16* w_ghl_h  = (u16*)carve(384 * 128 * 2); u16* w_ghl_l  = (u16*)carve(384 * 128 * 2);
    u16* w_gil_h  = (u16*)carve(384 * 256 * 2); u16* w_gil_l  = (u16*)carve(384 * 256 * 2);
    float* g_sum  = (float*)carve(BB * 4);
    float* g_cnt  = (float*)carve(BB * 4);
    (void)ws_size; (void)n_in; (void)out_size;

    // ---- degrees + CSR build ----
    hipMemsetAsync(ideg_l, 0, (size_t)Lc * 4, stream);
    hipMemsetAsync(ideg_c, 0, (size_t)C * 4, stream);
    ideg_kernel<<<(E + 255) / 256, 256, 0, stream>>>(l_ei, c_ei, ideg_l, ideg_c, E);
    scan_kernel<<<1, 1024, 0, stream>>>(ideg_c, c_off, C);
    scan_kernel<<<1, 1024, 0, stream>>>(ideg_l, l_off, Lc);
    hipMemsetAsync(fillc, 0, (size_t)C * 4, stream);
    fill_kernel<<<(E + 255) / 256, 256, 0, stream>>>(c_ei, l_ei, c_off, fillc, c_edges, E);
    hipMemsetAsync(fillc, 0, (size_t)Lc * 4, stream);
    fill_kernel<<<(E + 255) / 256, 256, 0, stream>>>(l_ei, c_ei, l_off, fillc, l_edges, E);

    // ---- weight folds:  Wf_c = cgru_wih @ l2c_w2 ; Wcat = [lgru_wihA @ c2l_w2 | lgru_wihB] ----
    foldw_kernel<<<(384 * 128 + 255) / 256, 256, 0, stream>>>(cgru_wih, 128, l2c_w2, Wf_c, 128, 384);
    foldb_kernel<<<2, 256, 0, stream>>>(cgru_wih, 128, l2c_b2, bmsg_c, 384);
    hipMemcpyAsync(Wcat, lgru_wih, (size_t)384 * 256 * 4, hipMemcpyDeviceToDevice, stream);
    foldw_kernel<<<(384 * 128 + 255) / 256, 256, 0, stream>>>(lgru_wih, 256, c2l_w2, Wcat, 256, 384);
    foldb_kernel<<<2, 256, 0, stream>>>(lgru_wih, 256, c2l_b2, bmsg_l, 384);

    // ---- weight splits ----
    splitw_kernel<<<(128 * 128 + 255) / 256, 256, 0, stream>>>(l2c_w1, w_l2c1_h, w_l2c1_l, 128 * 128);
    splitw_kernel<<<(128 * 128 + 255) / 256, 256, 0, stream>>>(c2l_w1, w_c2l1_h, w_c2l1_l, 128 * 128);
    splitw_kernel<<<(128 * 128 + 255) / 256, 256, 0, stream>>>(ro_w1, w_ro1_h, w_ro1_l, 128 * 128);
    splitw_kernel<<<(384 * 128 + 255) / 256, 256, 0, stream>>>(Wf_c, w_gic_h, w_gic_l, 384 * 128);
    splitw_kernel<<<(384 * 128 + 255) / 256, 256, 0, stream>>>(cgru_whh, w_ghc_h, w_ghc_l, 384 * 128);
    splitw_kernel<<<(384 * 128 + 255) / 256, 256, 0, stream>>>(lgru_whh, w_ghl_h, w_ghl_l, 384 * 128);
    splitw_kernel<<<(384 * 256 + 255) / 256, 256, 0, stream>>>(Wcat, w_gil_h, w_gil_l, 384 * 256);

    // ---- init embeddings ----
    init_emb_kernel<<<((size_t)Lc * DD + 255) / 256, 256, 0, stream>>>(l_init, l_emb_hi, l_emb_lo, Lc * DD);
    init_emb_kernel<<<((size_t)C * DD + 255) / 256, 256, 0, stream>>>(c_init, c_emb_hi, c_emb_lo, C * DD);

    for (int it = 0; it < N_ITER; ++it) {
        // ---- literal -> clause ----
        mfma_gemm<true, false, false><<<dim3((Lc + 127) / 128, 1), 256, 0, stream>>>(
            l_emb_hi, l_emb_lo, nullptr, nullptr, w_l2c1_h, w_l2c1_l,
            l2c_b1, nullptr, nullptr, pool1, Lc, 128, 128);
        gather_kernel<<<(C + 3) / 4, 256, 0, stream>>>(pool1, c_off, c_edges, hagg_hi, hagg_lo, C);
        {
            float* gi = pool1;
            float* gh = pool1 + (size_t)CH * 384;
            for (int r0 = 0; r0 < C; r0 += CH) {
                int n = imin_(CH, C - r0);
                mfma_gemm<false, false, true><<<dim3((n + 127) / 128, 3), 256, 0, stream>>>(
                    hagg_hi + (size_t)r0 * DD, hagg_lo + (size_t)r0 * DD, nullptr, nullptr,
                    w_gic_h, w_gic_l, cgru_bih, bmsg_c, ideg_c + r0, gi, n, 128, 384);
                mfma_gemm<false, false, false><<<dim3((n + 127) / 128, 3), 256, 0, stream>>>(
                    c_emb_hi + (size_t)r0 * DD, c_emb_lo + (size_t)r0 * DD, nullptr, nullptr,
                    w_ghc_h, w_ghc_l, cgru_bhh, nullptr, nullptr, gh, n, 128, 384);
                gru4_kernel<<<((size_t)n * 32 + 255) / 256, 256, 0, stream>>>(
                    gi, gh, c_emb_hi + (size_t)r0 * DD, c_emb_lo + (size_t)r0 * DD, n * 32);
            }
        }

        // ---- clause -> literal ----
        mfma_gemm<true, false, false><<<dim3((C + 127) / 128, 1), 256, 0, stream>>>(
            c_emb_hi, c_emb_lo, nullptr, nullptr, w_c2l1_h, w_c2l1_l,
            c2l_b1, nullptr, nullptr, pool1, C, 128, 128);
        gather_kernel<<<(Lc + 3) / 4, 256, 0, stream>>>(pool1, l_off, l_edges, hagg_hi, hagg_lo, Lc);
        {
            float* gi = pool1;
            float* gh = pool1 + (size_t)CH * 384;
            for (int r0 = 0; r0 < Lc; r0 += CH) {
                int n = imin_(CH, Lc - r0);
                mfma_gemm<false, true, true><<<dim3((n + 127) / 128, 3), 256, 0, stream>>>(
                    hagg_hi + (size_t)r0 * DD, hagg_lo + (size_t)r0 * DD,
                    l_emb_hi + (size_t)r0 * DD, l_emb_lo + (size_t)r0 * DD,
                    w_gil_h, w_gil_l, lgru_bih, bmsg_l, ideg_l + r0, gi, n, 256, 384);
                mfma_gemm<false, false, false><<<dim3((n + 127) / 128, 3), 256, 0, stream>>>(
                    l_emb_hi + (size_t)r0 * DD, l_emb_lo + (size_t)r0 * DD, nullptr, nullptr,
                    w_ghl_h, w_ghl_l, lgru_bhh, nullptr, nullptr, gh, n, 128, 384);
                gru4_kernel<<<((size_t)n * 32 + 255) / 256, 256, 0, stream>>>(
                    gi, gh, l_emb_hi + (size_t)r0 * DD, l_emb_lo + (size_t)r0 * DD, n * 32);
            }
        }
    }

    // ---- readout ----
    mfma_gemm<true, false, false><<<dim3((Lc + 127) / 128, 1), 256, 0, stream>>>(
        l_emb_hi, l_emb_lo, nullptr, nullptr, w_ro1_h, w_ro1_l,
        ro_b1, nullptr, nullptr, pool1, Lc, 128, 128);
    hipMemsetAsync(g_sum, 0, BB * 4, stream);
    hipMemsetAsync(g_cnt, 0, BB * 4, stream);
    logit2_kernel<<<256, 256, 0, stream>>>(pool1, ro_w2, l_batch, g_sum, g_cnt, Lc);
    final_kernel<<<1, 64, 0, stream>>>(g_sum, g_cnt, ro_b2, (float*)d_out);
}

// Round 5
// 1902.885 us; speedup vs baseline: 3.5066x; 1.5839x over previous
//
#include <hip/hip_runtime.h>
#include <hip/hip_bf16.h>

#define DD 128
#define CC 100000
#define BB 32
#define N_ITER 4
#define INV_INIT_NORM 0.125f   // 1/(sqrt(128)/sqrt(2)) = 1/8

typedef unsigned short u16;
typedef __attribute__((ext_vector_type(8))) short  frag_ab;   // 8 bf16 (4 VGPRs)
typedef __attribute__((ext_vector_type(4))) float  f32x4;
typedef __attribute__((ext_vector_type(8))) unsigned short us8;
typedef __attribute__((ext_vector_type(4))) unsigned short us4;

__device__ __forceinline__ u16 f2bf(float f) {
    union { float f; unsigned u; } v; v.f = f;
    unsigned r = v.u + 0x7fff + ((v.u >> 16) & 1);   // RNE
    return (u16)(r >> 16);
}
__device__ __forceinline__ float bf2f(u16 h) {
    union { unsigned u; float f; } v; v.u = ((unsigned)h) << 16;
    return v.f;
}

// ---------------- precompute: degrees / hierarchical scan / CSR fill ----------------

__global__ void ideg_kernel(const int* __restrict__ li, const int* __restrict__ ci,
                            int* __restrict__ idl, int* __restrict__ idc, int E) {
    int e = blockIdx.x * 256 + threadIdx.x;
    if (e < E) {
        atomicAdd(&idl[li[e]], 1);
        atomicAdd(&idc[ci[e]], 1);
    }
}

// per-block sums: block handles 4096 elems (1024 thr x 4)
__global__ __launch_bounds__(1024)
void bsum_kernel(const int* __restrict__ deg, int* __restrict__ bsum, int n) {
    __shared__ int wred[16];
    const int tid = threadIdx.x, lane = tid & 63, wid = tid >> 6;
    int idx = blockIdx.x * 4096 + tid * 4;
    int s = 0;
#pragma unroll
    for (int j = 0; j < 4; ++j) if (idx + j < n) s += deg[idx + j];
#pragma unroll
    for (int o = 32; o > 0; o >>= 1) s += __shfl_down(s, o);
    if (lane == 0) wred[wid] = s;
    __syncthreads();
    if (tid == 0) {
        int t = 0;
#pragma unroll
        for (int k = 0; k < 16; ++k) t += wred[k];
        bsum[blockIdx.x] = t;
    }
}

// per-block exclusive scan with carry from bsum prefix
__global__ __launch_bounds__(1024)
void scan2_kernel(const int* __restrict__ deg, const int* __restrict__ bsum,
                  int* __restrict__ off, int n, int nb) {
    __shared__ int wsum[16];
    __shared__ int carry_s;
    const int tid = threadIdx.x, lane = tid & 63, wid = tid >> 6;
    if (tid == 0) {
        int c = 0;
        for (int b = 0; b < blockIdx.x; ++b) c += bsum[b];
        carry_s = c;
    }
    int idx = blockIdx.x * 4096 + tid * 4;
    int v0 = idx     < n ? deg[idx]     : 0;
    int v1 = idx + 1 < n ? deg[idx + 1] : 0;
    int v2 = idx + 2 < n ? deg[idx + 2] : 0;
    int v3 = idx + 3 < n ? deg[idx + 3] : 0;
    int t = v0 + v1 + v2 + v3;
    int s = t;
#pragma unroll
    for (int o = 1; o < 64; o <<= 1) { int u = __shfl_up(s, o); if (lane >= o) s += u; }
    if (lane == 63) wsum[wid] = s;
    __syncthreads();
    if (wid == 0 && lane < 16) {
        int x = wsum[lane];
#pragma unroll
        for (int o = 1; o < 16; o <<= 1) { int u = __shfl_up(x, o); if (lane >= o) x += u; }
        wsum[lane] = x;
    }
    __syncthreads();
    int woff = (wid > 0) ? wsum[wid - 1] : 0;
    int excl = carry_s + woff + s - t;
    if (idx     < n) off[idx]     = excl;
    if (idx + 1 < n) off[idx + 1] = excl + v0;
    if (idx + 2 < n) off[idx + 2] = excl + v0 + v1;
    if (idx + 3 < n) off[idx + 3] = excl + v0 + v1 + v2;
    if (blockIdx.x == nb - 1 && tid == 0) off[n] = carry_s + wsum[15];
}

__global__ void fill_kernel(const int* __restrict__ dst, const int* __restrict__ src,
                            const int* __restrict__ off, int* __restrict__ fill,
                            int* __restrict__ edges, int E) {
    int e = blockIdx.x * 256 + threadIdx.x;
    if (e < E) {
        int d = dst[e];
        int p = atomicAdd(&fill[d], 1);
        edges[off[d] + p] = src[e];
    }
}

// ---------------- precompute: weight folds / bf16 conversion ----------------

__global__ void foldw_kernel(const float* __restrict__ wih, int ldw,
                             const float* __restrict__ w2,
                             float* __restrict__ out, int out_ld, int M) {
    int idx = blockIdx.x * 256 + threadIdx.x;
    if (idx >= M * 128) return;
    int o = idx >> 7, k = idx & 127;
    float s = 0.f;
    for (int m = 0; m < 128; ++m) s += wih[(size_t)o * ldw + m] * w2[m * 128 + k];
    out[(size_t)o * out_ld + k] = s;
}

__global__ void foldb_kernel(const float* __restrict__ wih, int ldw,
                             const float* __restrict__ b2,
                             float* __restrict__ out, int M) {
    int o = blockIdx.x * 256 + threadIdx.x;
    if (o >= M) return;
    float s = 0.f;
    for (int m = 0; m < 128; ++m) s += wih[(size_t)o * ldw + m] * b2[m];
    out[o] = s;
}

__global__ void cvtw_kernel(const float* __restrict__ w, u16* __restrict__ hi, int n) {
    int i = blockIdx.x * 256 + threadIdx.x;
    if (i < n) hi[i] = f2bf(w[i]);
}

__global__ void init_emb_kernel(const float* __restrict__ init, u16* __restrict__ hi, int n) {
    int i = blockIdx.x * 256 + threadIdx.x;
    if (i < n) hi[i] = f2bf(init[i & (DD - 1)] * INV_INIT_NORM);
}

// ---------------- bf16 MFMA GEMM ----------------
// Y[N,M] = act(A[N,K] @ W[M,K]^T + bias (+ bias2 if ideg>0)); A,W bf16 planes.
// XCAT: k>=128 reads A2 at row gr^1 (negation swap; chunk base must be even).
// 128x128 tile, 4 waves (2x2 of 64x64), BK=32, 16x16x32 bf16 MFMA.
// LDS [g][128][8] u16, row^=g<<1 swizzle.

template<bool RELU, bool XCAT, bool BIAS2, bool OUTBF16>
__global__ __launch_bounds__(256)
void mfma_gemm(const u16* __restrict__ Ahi, const u16* __restrict__ A2hi,
               const u16* __restrict__ Whi,
               const float* __restrict__ bias, const float* __restrict__ bias2,
               const int* __restrict__ ideg,
               void* __restrict__ Yv, int N, int K, int M) {
    __shared__ u16 Ah[4][128][8], Wh[4][128][8];

    const int tid = threadIdx.x;
    const int bn = blockIdx.x * 128, bm = blockIdx.y * 128;
    const int l = tid & 63, w = tid >> 6;
    const int wr = w >> 1, wc = w & 1;
    const int lr = l & 15, lg = l >> 4;

    f32x4 acc[4][4];
#pragma unroll
    for (int i = 0; i < 4; ++i)
#pragma unroll
        for (int j = 0; j < 4; ++j) acc[i][j] = (f32x4){0.f, 0.f, 0.f, 0.f};

    for (int k0 = 0; k0 < K; k0 += 32) {
#pragma unroll
        for (int t = 0; t < 2; ++t) {
            const int slot = t * 256 + tid;          // 0..511
            const int row = slot >> 2, g = slot & 3, rs = row ^ (g << 1);
            const int gr = bn + row;
            us8 vh = (us8)0;
            if (gr < N) {
                if (XCAT && k0 >= 128) {
                    vh = *(const us8*)(A2hi + (size_t)(gr ^ 1) * 128 + (k0 - 128) + g * 8);
                } else {
                    vh = *(const us8*)(Ahi + (size_t)gr * 128 + k0 + g * 8);
                }
            }
            *(us8*)&Ah[g][rs][0] = vh;
            *(us8*)&Wh[g][rs][0] = *(const us8*)(Whi + (size_t)(bm + row) * K + k0 + g * 8);
        }
        __syncthreads();

        frag_ab a_h[4], b_h[4];
#pragma unroll
        for (int i = 0; i < 4; ++i) {
            const int ra = wr * 64 + i * 16 + lr;
            a_h[i] = *(const frag_ab*)&Ah[lg][ra ^ (lg << 1)][0];
            const int rb = wc * 64 + i * 16 + lr;
            b_h[i] = *(const frag_ab*)&Wh[lg][rb ^ (lg << 1)][0];
        }
#pragma unroll
        for (int i = 0; i < 4; ++i)
#pragma unroll
            for (int j = 0; j < 4; ++j)
                acc[i][j] = __builtin_amdgcn_mfma_f32_16x16x32_bf16(a_h[i], b_h[j], acc[i][j], 0, 0, 0);
        __syncthreads();
    }

    // epilogue: C/D layout col = lane&15, row = (lane>>4)*4 + reg
#pragma unroll
    for (int j = 0; j < 4; ++j) {
        const int gc = bm + wc * 64 + j * 16 + lr;
        const float bj = bias[gc];
        const float b2j = BIAS2 ? bias2[gc] : 0.f;
#pragma unroll
        for (int i = 0; i < 4; ++i) {
            const int grb = bn + wr * 64 + i * 16 + lg * 4;
#pragma unroll
            for (int r = 0; r < 4; ++r) {
                const int gr = grb + r;
                if (gr < N) {
                    float o = acc[i][j][r] + bj;
                    if (BIAS2) { if (ideg[gr] > 0) o += b2j; }
                    if (RELU) o = fmaxf(o, 0.f);
                    if (OUTBF16) ((u16*)Yv)[(size_t)gr * M + gc] = f2bf(o);
                    else         ((float*)Yv)[(size_t)gr * M + gc] = o;
                }
            }
        }
    }
}

// ---------------- CSR gather: out[row] = (1/max(deg,1)) * sum msg[src], bf16 in/out ----------------

__global__ void gather_kernel(const u16* __restrict__ msg, const int* __restrict__ off,
                              const int* __restrict__ edges, u16* __restrict__ ohi, int n) {
    int row = blockIdx.x * 4 + (threadIdx.x >> 6);
    if (row >= n) return;
    int lane = threadIdx.x & 63;
    int s = off[row], e = off[row + 1];
    float ax = 0.f, ay = 0.f;
    for (int i = s; i < e; ++i) {
        const ushort2 v = ((const ushort2*)(msg + (size_t)edges[i] * DD))[lane];
        ax += bf2f(v.x); ay += bf2f(v.y);
    }
    float sc = 1.0f / (float)((e - s) > 0 ? (e - s) : 1);
    *(ushort2*)(ohi + (size_t)row * DD + 2 * lane) = make_ushort2(f2bf(ax * sc), f2bf(ay * sc));
}

// ---------------- GRU elementwise, all bf16 (4 elems/thread) ----------------

__device__ __forceinline__ float sigmoidf_(float x) { return 1.0f / (1.0f + expf(-x)); }

__global__ void gru4_kernel(const u16* __restrict__ gi, const u16* __restrict__ gh,
                            u16* __restrict__ h, int n4) {
    int i = blockIdx.x * 256 + threadIdx.x;
    if (i >= n4) return;
    int r = i >> 5, c = i & 31;
    size_t b = (size_t)r * 384 + c * 4;
    us4 ir = *(const us4*)(gi + b), iz = *(const us4*)(gi + b + 128), in_ = *(const us4*)(gi + b + 256);
    us4 hr = *(const us4*)(gh + b), hz = *(const us4*)(gh + b + 128), hn = *(const us4*)(gh + b + 256);
    us4 hv = *(const us4*)(h + (size_t)i * 4);
    us4 o;
#pragma unroll
    for (int k = 0; k < 4; ++k) {
        float rg = sigmoidf_(bf2f(ir[k]) + bf2f(hr[k]));
        float zg = sigmoidf_(bf2f(iz[k]) + bf2f(hz[k]));
        float ng = tanhf(bf2f(in_[k]) + rg * bf2f(hn[k]));
        o[k] = f2bf((1.f - zg) * ng + zg * bf2f(hv[k]));
    }
    *(us4*)(h + (size_t)i * 4) = o;
}

// ---------------- readout ----------------

__global__ __launch_bounds__(256)
void logit2_kernel(const float* __restrict__ hidden, const float* __restrict__ w2,
                   const int* __restrict__ l_batch,
                   float* __restrict__ gsum, float* __restrict__ gcnt, int Lc) {
    __shared__ float s_sum[BB];
    __shared__ float s_cnt[BB];
    const int tid = threadIdx.x;
    if (tid < BB) { s_sum[tid] = 0.f; s_cnt[tid] = 0.f; }
    __syncthreads();
    const int lane = tid & 63;
    const int gw = blockIdx.x * 4 + (tid >> 6);
    const int nw = gridDim.x * 4;
    const float2 wv = ((const float2*)w2)[lane];
    for (int row = gw; row < Lc; row += nw) {
        float2 h = ((const float2*)(hidden + (size_t)row * DD))[lane];
        float dp = h.x * wv.x + h.y * wv.y;
#pragma unroll
        for (int off = 32; off > 0; off >>= 1) dp += __shfl_down(dp, off);
        if (lane == 0) {
            int b = l_batch[row];
            atomicAdd(&s_sum[b], dp);
            atomicAdd(&s_cnt[b], 1.0f);
        }
    }
    __syncthreads();
    if (tid < BB) {
        atomicAdd(&gsum[tid], s_sum[tid]);
        atomicAdd(&gcnt[tid], s_cnt[tid]);
    }
}

__global__ void final_kernel(const float* __restrict__ gsum, const float* __restrict__ gcnt,
                             const float* __restrict__ b2, float* __restrict__ out) {
    int b = threadIdx.x;
    if (b < BB) {
        float m = gsum[b] / fmaxf(gcnt[b], 1.0f) + b2[0];
        out[b] = 1.0f / (1.0f + expf(-m));
    }
}

// ---------------- host side ----------------

static inline size_t align_up_(size_t x) { return (x + 255) & ~(size_t)255; }
static inline int imin_(int a, int b) { return a < b ? a : b; }

extern "C" void kernel_launch(void* const* d_in, const int* in_sizes, int n_in,
                              void* d_out, int out_size, void* d_ws, size_t ws_size,
                              hipStream_t stream) {
    const int*   l_ei     = (const int*)d_in[0];
    const int*   c_ei     = (const int*)d_in[1];
    const int*   l_batch  = (const int*)d_in[2];
    const float* l_init   = (const float*)d_in[3];
    const float* c_init   = (const float*)d_in[4];
    const float* l2c_w1   = (const float*)d_in[5];
    const float* l2c_b1   = (const float*)d_in[6];
    const float* l2c_w2   = (const float*)d_in[7];
    const float* l2c_b2   = (const float*)d_in[8];
    const float* c2l_w1   = (const float*)d_in[9];
    const float* c2l_b1   = (const float*)d_in[10];
    const float* c2l_w2   = (const float*)d_in[11];
    const float* c2l_b2   = (const float*)d_in[12];
    const float* cgru_wih = (const float*)d_in[13];
    const float* cgru_whh = (const float*)d_in[14];
    const float* cgru_bih = (const float*)d_in[15];
    const float* cgru_bhh = (const float*)d_in[16];
    const float* lgru_wih = (const float*)d_in[17];
    const float* lgru_whh = (const float*)d_in[18];
    const float* lgru_bih = (const float*)d_in[19];
    const float* lgru_bhh = (const float*)d_in[20];
    const float* ro_w1    = (const float*)d_in[21];
    const float* ro_b1    = (const float*)d_in[22];
    const float* ro_w2    = (const float*)d_in[23];
    const float* ro_b2    = (const float*)d_in[24];

    const int E  = in_sizes[0];
    const int Lc = in_sizes[2];
    const int C  = CC;
    const int CH = 50000;      // GRU chunk rows: gates 2*CH*384*2B = 76.8MB pool
    const int NMAX = (C > Lc ? C : Lc);

    // ---- workspace carve (~175 MB, <= proven-safe budget) ----
    char* p = (char*)d_ws;
    auto carve = [&](size_t bytes) { void* r = (void*)p; p += align_up_(bytes); return r; };
    u16*   l_emb   = (u16*)carve((size_t)Lc * DD * 2);         // 15.36 MB
    u16*   c_emb   = (u16*)carve((size_t)C * DD * 2);          // 25.6 MB
    u16*   hagg    = (u16*)carve((size_t)NMAX * DD * 2);       // 25.6 MB
    u16*   msg     = (u16*)carve((size_t)NMAX * DD * 2);       // 25.6 MB
    float* gates   = (float*)carve((size_t)2 * CH * 384 * 2);  // 76.8 MB (u16 gi+gh | f32 readout hidden)
    int*   ideg_l  = (int*)carve((size_t)Lc * 4);
    int*   ideg_c  = (int*)carve((size_t)C * 4);
    int*   l_off   = (int*)carve((size_t)(Lc + 1) * 4);
    int*   c_off   = (int*)carve((size_t)(C + 1) * 4);
    int*   l_edges = (int*)carve((size_t)E * 4);
    int*   c_edges = (int*)carve((size_t)E * 4);
    int*   fillc   = (int*)carve((size_t)NMAX * 4);
    int*   bsums   = (int*)carve(64 * 4);
    float* Wf_c    = (float*)carve((size_t)384 * 128 * 4);
    float* Wcat    = (float*)carve((size_t)384 * 256 * 4);
    float* bmsg_c  = (float*)carve(384 * 4);
    float* bmsg_l  = (float*)carve(384 * 4);
    u16* w_l2c1 = (u16*)carve(128 * 128 * 2);
    u16* w_c2l1 = (u16*)carve(128 * 128 * 2);
    u16* w_ro1  = (u16*)carve(128 * 128 * 2);
    u16* w_gic  = (u16*)carve(384 * 128 * 2);
    u16* w_ghc  = (u16*)carve(384 * 128 * 2);
    u16* w_ghl  = (u16*)carve(384 * 128 * 2);
    u16* w_gil  = (u16*)carve(384 * 256 * 2);
    float* g_sum = (float*)carve(BB * 4);
    float* g_cnt = (float*)carve(BB * 4);
    (void)ws_size; (void)n_in; (void)out_size;

    // ---- degrees + CSR build ----
    hipMemsetAsync(ideg_l, 0, (size_t)Lc * 4, stream);
    hipMemsetAsync(ideg_c, 0, (size_t)C * 4, stream);
    ideg_kernel<<<(E + 255) / 256, 256, 0, stream>>>(l_ei, c_ei, ideg_l, ideg_c, E);
    {
        int nbc = (C + 4095) / 4096, nbl = (Lc + 4095) / 4096;
        bsum_kernel<<<nbc, 1024, 0, stream>>>(ideg_c, bsums, C);
        scan2_kernel<<<nbc, 1024, 0, stream>>>(ideg_c, bsums, c_off, C, nbc);
        bsum_kernel<<<nbl, 1024, 0, stream>>>(ideg_l, bsums, Lc);
        scan2_kernel<<<nbl, 1024, 0, stream>>>(ideg_l, bsums, l_off, Lc, nbl);
    }
    hipMemsetAsync(fillc, 0, (size_t)C * 4, stream);
    fill_kernel<<<(E + 255) / 256, 256, 0, stream>>>(c_ei, l_ei, c_off, fillc, c_edges, E);
    hipMemsetAsync(fillc, 0, (size_t)Lc * 4, stream);
    fill_kernel<<<(E + 255) / 256, 256, 0, stream>>>(l_ei, c_ei, l_off, fillc, l_edges, E);

    // ---- weight folds: Wf_c = cgru_wih @ l2c_w2 ; Wcat = [lgru_wihA @ c2l_w2 | lgru_wihB] ----
    foldw_kernel<<<(384 * 128 + 255) / 256, 256, 0, stream>>>(cgru_wih, 128, l2c_w2, Wf_c, 128, 384);
    foldb_kernel<<<2, 256, 0, stream>>>(cgru_wih, 128, l2c_b2, bmsg_c, 384);
    hipMemcpyAsync(Wcat, lgru_wih, (size_t)384 * 256 * 4, hipMemcpyDeviceToDevice, stream);
    foldw_kernel<<<(384 * 128 + 255) / 256, 256, 0, stream>>>(lgru_wih, 256, c2l_w2, Wcat, 256, 384);
    foldb_kernel<<<2, 256, 0, stream>>>(lgru_wih, 256, c2l_b2, bmsg_l, 384);

    // ---- bf16 weight conversion ----
    cvtw_kernel<<<(128 * 128 + 255) / 256, 256, 0, stream>>>(l2c_w1, w_l2c1, 128 * 128);
    cvtw_kernel<<<(128 * 128 + 255) / 256, 256, 0, stream>>>(c2l_w1, w_c2l1, 128 * 128);
    cvtw_kernel<<<(128 * 128 + 255) / 256, 256, 0, stream>>>(ro_w1, w_ro1, 128 * 128);
    cvtw_kernel<<<(384 * 128 + 255) / 256, 256, 0, stream>>>(Wf_c, w_gic, 384 * 128);
    cvtw_kernel<<<(384 * 128 + 255) / 256, 256, 0, stream>>>(cgru_whh, w_ghc, 384 * 128);
    cvtw_kernel<<<(384 * 128 + 255) / 256, 256, 0, stream>>>(lgru_whh, w_ghl, 384 * 128);
    cvtw_kernel<<<(384 * 256 + 255) / 256, 256, 0, stream>>>(Wcat, w_gil, 384 * 256);

    // ---- init embeddings ----
    init_emb_kernel<<<((size_t)Lc * DD + 255) / 256, 256, 0, stream>>>(l_init, l_emb, Lc * DD);
    init_emb_kernel<<<((size_t)C * DD + 255) / 256, 256, 0, stream>>>(c_init, c_emb, C * DD);

    u16* gi = (u16*)gates;
    u16* gh = (u16*)gates + (size_t)CH * 384;

    for (int it = 0; it < N_ITER; ++it) {
        // ---- literal -> clause ----
        mfma_gemm<true, false, false, true><<<dim3((Lc + 127) / 128, 1), 256, 0, stream>>>(
            l_emb, nullptr, w_l2c1, l2c_b1, nullptr, nullptr, msg, Lc, 128, 128);
        gather_kernel<<<(C + 3) / 4, 256, 0, stream>>>(msg, c_off, c_edges, hagg, C);
        for (int r0 = 0; r0 < C; r0 += CH) {
            int n = imin_(CH, C - r0);
            mfma_gemm<false, false, true, true><<<dim3((n + 127) / 128, 3), 256, 0, stream>>>(
                hagg + (size_t)r0 * DD, nullptr, w_gic, cgru_bih, bmsg_c, ideg_c + r0, gi, n, 128, 384);
            mfma_gemm<false, false, false, true><<<dim3((n + 127) / 128, 3), 256, 0, stream>>>(
                c_emb + (size_t)r0 * DD, nullptr, w_ghc, cgru_bhh, nullptr, nullptr, gh, n, 128, 384);
            gru4_kernel<<<((size_t)n * 32 + 255) / 256, 256, 0, stream>>>(
                gi, gh, c_emb + (size_t)r0 * DD, n * 32);
        }

        // ---- clause -> literal ----
        mfma_gemm<true, false, false, true><<<dim3((C + 127) / 128, 1), 256, 0, stream>>>(
            c_emb, nullptr, w_c2l1, c2l_b1, nullptr, nullptr, msg, C, 128, 128);
        gather_kernel<<<(Lc + 3) / 4, 256, 0, stream>>>(msg, l_off, l_edges, hagg, Lc);
        for (int r0 = 0; r0 < Lc; r0 += CH) {
            int n = imin_(CH, Lc - r0);
            mfma_gemm<false, true, true, true><<<dim3((n + 127) / 128, 3), 256, 0, stream>>>(
                hagg + (size_t)r0 * DD, l_emb + (size_t)r0 * DD, w_gil,
                lgru_bih, bmsg_l, ideg_l + r0, gi, n, 256, 384);
            mfma_gemm<false, false, false, true><<<dim3((n + 127) / 128, 3), 256, 0, stream>>>(
                l_emb + (size_t)r0 * DD, nullptr, w_ghl, lgru_bhh, nullptr, nullptr, gh, n, 128, 384);
            gru4_kernel<<<((size_t)n * 32 + 255) / 256, 256, 0, stream>>>(
                gi, gh, l_emb + (size_t)r0 * DD, n * 32);
        }
    }

    // ---- readout (hidden f32 in gates pool) ----
    float* hidden = gates;
    mfma_gemm<true, false, false, false><<<dim3((Lc + 127) / 128, 1), 256, 0, stream>>>(
        l_emb, nullptr, w_ro1, ro_b1, nullptr, nullptr, hidden, Lc, 128, 128);
    hipMemsetAsync(g_sum, 0, BB * 4, stream);
    hipMemsetAsync(g_cnt, 0, BB * 4, stream);
    logit2_kernel<<<256, 256, 0, stream>>>(hidden, ro_w2, l_batch, g_sum, g_cnt, Lc);
    final_kernel<<<1, 64, 0, stream>>>(g_sum, g_cnt, ro_b2, (float*)d_out);
}

// Round 6
// 1837.185 us; speedup vs baseline: 3.6320x; 1.0358x over previous
//
#include <hip/hip_runtime.h>
#include <hip/hip_bf16.h>

#define DD 128
#define CC 100000
#define BB 32
#define N_ITER 4
#define INV_INIT_NORM 0.125f   // 1/(sqrt(128)/sqrt(2)) = 1/8

typedef unsigned short u16;
typedef __attribute__((ext_vector_type(8))) short  frag_ab;   // 8 bf16 (4 VGPRs)
typedef __attribute__((ext_vector_type(4))) float  f32x4;
typedef __attribute__((ext_vector_type(8))) unsigned short us8;

__device__ __forceinline__ u16 f2bf(float f) {
    union { float f; unsigned u; } v; v.f = f;
    unsigned r = v.u + 0x7fff + ((v.u >> 16) & 1);   // RNE
    return (u16)(r >> 16);
}
__device__ __forceinline__ float bf2f(u16 h) {
    union { unsigned u; float f; } v; v.u = ((unsigned)h) << 16;
    return v.f;
}
__device__ __forceinline__ float sigmoidf_(float x) { return 1.0f / (1.0f + expf(-x)); }

// ---------------- precompute: degrees / hierarchical scan / CSR fill ----------------

__global__ void ideg_kernel(const int* __restrict__ li, const int* __restrict__ ci,
                            int* __restrict__ idl, int* __restrict__ idc, int E) {
    int e = blockIdx.x * 256 + threadIdx.x;
    if (e < E) {
        atomicAdd(&idl[li[e]], 1);
        atomicAdd(&idc[ci[e]], 1);
    }
}

__global__ __launch_bounds__(1024)
void bsum_kernel(const int* __restrict__ deg, int* __restrict__ bsum, int n) {
    __shared__ int wred[16];
    const int tid = threadIdx.x, lane = tid & 63, wid = tid >> 6;
    int idx = blockIdx.x * 4096 + tid * 4;
    int s = 0;
#pragma unroll
    for (int j = 0; j < 4; ++j) if (idx + j < n) s += deg[idx + j];
#pragma unroll
    for (int o = 32; o > 0; o >>= 1) s += __shfl_down(s, o);
    if (lane == 0) wred[wid] = s;
    __syncthreads();
    if (tid == 0) {
        int t = 0;
#pragma unroll
        for (int k = 0; k < 16; ++k) t += wred[k];
        bsum[blockIdx.x] = t;
    }
}

__global__ __launch_bounds__(1024)
void scan2_kernel(const int* __restrict__ deg, const int* __restrict__ bsum,
                  int* __restrict__ off, int n, int nb) {
    __shared__ int wsum[16];
    __shared__ int carry_s;
    const int tid = threadIdx.x, lane = tid & 63, wid = tid >> 6;
    if (tid == 0) {
        int c = 0;
        for (int b = 0; b < blockIdx.x; ++b) c += bsum[b];
        carry_s = c;
    }
    int idx = blockIdx.x * 4096 + tid * 4;
    int v0 = idx     < n ? deg[idx]     : 0;
    int v1 = idx + 1 < n ? deg[idx + 1] : 0;
    int v2 = idx + 2 < n ? deg[idx + 2] : 0;
    int v3 = idx + 3 < n ? deg[idx + 3] : 0;
    int t = v0 + v1 + v2 + v3;
    int s = t;
#pragma unroll
    for (int o = 1; o < 64; o <<= 1) { int u = __shfl_up(s, o); if (lane >= o) s += u; }
    if (lane == 63) wsum[wid] = s;
    __syncthreads();
    if (wid == 0 && lane < 16) {
        int x = wsum[lane];
#pragma unroll
        for (int o = 1; o < 16; o <<= 1) { int u = __shfl_up(x, o); if (lane >= o) x += u; }
        wsum[lane] = x;
    }
    __syncthreads();
    int woff = (wid > 0) ? wsum[wid - 1] : 0;
    int excl = carry_s + woff + s - t;
    if (idx     < n) off[idx]     = excl;
    if (idx + 1 < n) off[idx + 1] = excl + v0;
    if (idx + 2 < n) off[idx + 2] = excl + v0 + v1;
    if (idx + 3 < n) off[idx + 3] = excl + v0 + v1 + v2;
    if (blockIdx.x == nb - 1 && tid == 0) off[n] = carry_s + wsum[15];
}

__global__ void fill_kernel(const int* __restrict__ dst, const int* __restrict__ src,
                            const int* __restrict__ off, int* __restrict__ fill,
                            int* __restrict__ edges, int E) {
    int e = blockIdx.x * 256 + threadIdx.x;
    if (e < E) {
        int d = dst[e];
        int p = atomicAdd(&fill[d], 1);
        edges[off[d] + p] = src[e];
    }
}

// ---------------- precompute: weight folds / bf16 conversion ----------------

__global__ void foldw_kernel(const float* __restrict__ wih, int ldw,
                             const float* __restrict__ w2,
                             float* __restrict__ out, int out_ld, int M) {
    int idx = blockIdx.x * 256 + threadIdx.x;
    if (idx >= M * 128) return;
    int o = idx >> 7, k = idx & 127;
    float s = 0.f;
    for (int m = 0; m < 128; ++m) s += wih[(size_t)o * ldw + m] * w2[m * 128 + k];
    out[(size_t)o * out_ld + k] = s;
}

__global__ void foldb_kernel(const float* __restrict__ wih, int ldw,
                             const float* __restrict__ b2,
                             float* __restrict__ out, int M) {
    int o = blockIdx.x * 256 + threadIdx.x;
    if (o >= M) return;
    float s = 0.f;
    for (int m = 0; m < 128; ++m) s += wih[(size_t)o * ldw + m] * b2[m];
    out[o] = s;
}

__global__ void cvtw_kernel(const float* __restrict__ w, u16* __restrict__ hi, int n) {
    int i = blockIdx.x * 256 + threadIdx.x;
    if (i < n) hi[i] = f2bf(w[i]);
}

__global__ void init_emb_kernel(const float* __restrict__ init, u16* __restrict__ hi, int n) {
    int i = blockIdx.x * 256 + threadIdx.x;
    if (i < n) hi[i] = f2bf(init[i & (DD - 1)] * INV_INIT_NORM);
}

// ---------------- bf16 MFMA GEMM (msg MLP + readout) ----------------
// Y[N,M] = act(A[N,128] @ W[M,128]^T + bias); 128x128 tile, 4 waves.

template<bool RELU, bool OUTBF16>
__global__ __launch_bounds__(256)
void mfma_gemm(const u16* __restrict__ Ahi, const u16* __restrict__ Whi,
               const float* __restrict__ bias, void* __restrict__ Yv, int N, int M) {
    __shared__ u16 Ah[4][128][8], Wh[4][128][8];

    const int tid = threadIdx.x;
    const int bn = blockIdx.x * 128, bm = blockIdx.y * 128;
    const int l = tid & 63, w = tid >> 6;
    const int wr = w >> 1, wc = w & 1;
    const int lr = l & 15, lg = l >> 4;

    f32x4 acc[4][4];
#pragma unroll
    for (int i = 0; i < 4; ++i)
#pragma unroll
        for (int j = 0; j < 4; ++j) acc[i][j] = (f32x4){0.f, 0.f, 0.f, 0.f};

    for (int k0 = 0; k0 < 128; k0 += 32) {
#pragma unroll
        for (int t = 0; t < 2; ++t) {
            const int slot = t * 256 + tid;
            const int row = slot >> 2, g = slot & 3, rs = row ^ (g << 1);
            const int gr = bn + row;
            us8 vh = (us8)0;
            if (gr < N) vh = *(const us8*)(Ahi + (size_t)gr * 128 + k0 + g * 8);
            *(us8*)&Ah[g][rs][0] = vh;
            *(us8*)&Wh[g][rs][0] = *(const us8*)(Whi + (size_t)(bm + row) * 128 + k0 + g * 8);
        }
        __syncthreads();

        frag_ab a_h[4], b_h[4];
#pragma unroll
        for (int i = 0; i < 4; ++i) {
            const int ra = wr * 64 + i * 16 + lr;
            a_h[i] = *(const frag_ab*)&Ah[lg][ra ^ (lg << 1)][0];
            const int rb = wc * 64 + i * 16 + lr;
            b_h[i] = *(const frag_ab*)&Wh[lg][rb ^ (lg << 1)][0];
        }
#pragma unroll
        for (int i = 0; i < 4; ++i)
#pragma unroll
            for (int j = 0; j < 4; ++j)
                acc[i][j] = __builtin_amdgcn_mfma_f32_16x16x32_bf16(a_h[i], b_h[j], acc[i][j], 0, 0, 0);
        __syncthreads();
    }

#pragma unroll
    for (int j = 0; j < 4; ++j) {
        const int gc = bm + wc * 64 + j * 16 + lr;
        const float bj = bias[gc];
#pragma unroll
        for (int i = 0; i < 4; ++i) {
            const int grb = bn + wr * 64 + i * 16 + lg * 4;
#pragma unroll
            for (int r = 0; r < 4; ++r) {
                const int gr = grb + r;
                if (gr < N) {
                    float o = acc[i][j][r] + bj;
                    if (RELU) o = fmaxf(o, 0.f);
                    if (OUTBF16) ((u16*)Yv)[(size_t)gr * M + gc] = f2bf(o);
                    else         ((float*)Yv)[(size_t)gr * M + gc] = o;
                }
            }
        }
    }
}

// ---------------- fused gate-GEMMs + GRU ----------------
// Per 64-row block: stage X[N,128] (+X2 swap rows if XCAT) and H[N,128] in LDS;
// 3 passes (r,z,n): ai = X@Wih_gate^T, ah = H@Whh_gate^T (weights streamed from
// L2); combine gates in registers; H <- GRU(H, gates), written bf16 in place.

template<bool XCAT>
__global__ __launch_bounds__(256)
void gru_fused(const u16* __restrict__ X, const u16* __restrict__ X2,
               u16* H,
               const u16* __restrict__ Wih, const u16* __restrict__ Whh,
               const float* __restrict__ bih, const float* __restrict__ bmsg,
               const float* __restrict__ bhh, const int* __restrict__ ideg,
               int N) {
    constexpr int KX = XCAT ? 256 : 128;
    constexpr int GX = KX / 8;
    __shared__ u16 Xs[GX][64][8];
    __shared__ u16 Hs[16][64][8];

    const int tid = threadIdx.x;
    const int bn = blockIdx.x * 64;
    const int l = tid & 63, w = tid >> 6;
    const int wr = w >> 1, wc = w & 1;      // wave tile: rows wr*32+(0..31), cols wc*64+(0..63)
    const int lr = l & 15, lg = l >> 4;

    // ---- stage X (and swapped X2 for the xcat upper half) ----
#pragma unroll
    for (int t = 0; t < (64 * GX) / 256; ++t) {
        int slot = t * 256 + tid;
        int row = slot / GX, g = slot % GX;
        int gr = bn + row;
        us8 v = (us8)0;
        if (gr < N) {
            if (XCAT && g >= 16) v = *(const us8*)(X2 + (size_t)(gr ^ 1) * 128 + (g - 16) * 8);
            else                 v = *(const us8*)(X + (size_t)gr * 128 + g * 8);
        }
        *(us8*)&Xs[g][row ^ ((g & 3) << 1)][0] = v;
    }
    // ---- stage H ----
#pragma unroll
    for (int t = 0; t < 4; ++t) {
        int slot = t * 256 + tid;
        int row = slot >> 4, g = slot & 15;
        int gr = bn + row;
        us8 v = (us8)0;
        if (gr < N) v = *(const us8*)(H + (size_t)gr * 128 + g * 8);
        *(us8*)&Hs[g][row ^ ((g & 3) << 1)][0] = v;
    }
    __syncthreads();

    // per-thread row degree flags (rows bn + wr*32 + i*16 + lg*4 + r)
    int dg[2][4];
#pragma unroll
    for (int i = 0; i < 2; ++i) {
        int rbase = bn + wr * 32 + i * 16 + lg * 4;
#pragma unroll
        for (int r = 0; r < 4; ++r)
            dg[i][r] = (rbase + r < N) ? ideg[rbase + r] : 0;
    }

    auto run_pass = [&](int gate, f32x4 (&ai)[2][4], f32x4 (&ah)[2][4]) {
#pragma unroll
        for (int i = 0; i < 2; ++i)
#pragma unroll
            for (int j = 0; j < 4; ++j) {
                ai[i][j] = (f32x4){0.f, 0.f, 0.f, 0.f};
                ah[i][j] = (f32x4){0.f, 0.f, 0.f, 0.f};
            }
#pragma unroll
        for (int ks = 0; ks < KX / 32; ++ks) {
            frag_ab a0 = *(const frag_ab*)&Xs[ks * 4 + lg][(wr * 32 + lr) ^ (lg << 1)][0];
            frag_ab a1 = *(const frag_ab*)&Xs[ks * 4 + lg][(wr * 32 + 16 + lr) ^ (lg << 1)][0];
#pragma unroll
            for (int j = 0; j < 4; ++j) {
                const int col = gate * 128 + wc * 64 + j * 16 + lr;
                frag_ab b = *(const frag_ab*)(Wih + (size_t)col * KX + ks * 32 + lg * 8);
                ai[0][j] = __builtin_amdgcn_mfma_f32_16x16x32_bf16(a0, b, ai[0][j], 0, 0, 0);
                ai[1][j] = __builtin_amdgcn_mfma_f32_16x16x32_bf16(a1, b, ai[1][j], 0, 0, 0);
            }
        }
#pragma unroll
        for (int ks = 0; ks < 4; ++ks) {
            frag_ab a0 = *(const frag_ab*)&Hs[ks * 4 + lg][(wr * 32 + lr) ^ (lg << 1)][0];
            frag_ab a1 = *(const frag_ab*)&Hs[ks * 4 + lg][(wr * 32 + 16 + lr) ^ (lg << 1)][0];
#pragma unroll
            for (int j = 0; j < 4; ++j) {
                const int col = gate * 128 + wc * 64 + j * 16 + lr;
                frag_ab b = *(const frag_ab*)(Whh + (size_t)col * 128 + ks * 32 + lg * 8);
                ah[0][j] = __builtin_amdgcn_mfma_f32_16x16x32_bf16(a0, b, ah[0][j], 0, 0, 0);
                ah[1][j] = __builtin_amdgcn_mfma_f32_16x16x32_bf16(a1, b, ah[1][j], 0, 0, 0);
            }
        }
    };

    f32x4 ai[2][4], ah[2][4], rg[2][4], zg[2][4];

    // ---- pass 0: r gate ----
    run_pass(0, ai, ah);
#pragma unroll
    for (int i = 0; i < 2; ++i)
#pragma unroll
        for (int j = 0; j < 4; ++j) {
            const int gc = wc * 64 + j * 16 + lr;
            const float bi = bih[gc], bm = bmsg[gc], bh = bhh[gc];
#pragma unroll
            for (int r = 0; r < 4; ++r) {
                float pre = ai[i][j][r] + bi + (dg[i][r] > 0 ? bm : 0.f) + ah[i][j][r] + bh;
                rg[i][j][r] = sigmoidf_(pre);
            }
        }

    // ---- pass 1: z gate ----
    run_pass(1, ai, ah);
#pragma unroll
    for (int i = 0; i < 2; ++i)
#pragma unroll
        for (int j = 0; j < 4; ++j) {
            const int gc = 128 + wc * 64 + j * 16 + lr;
            const float bi = bih[gc], bm = bmsg[gc], bh = bhh[gc];
#pragma unroll
            for (int r = 0; r < 4; ++r) {
                float pre = ai[i][j][r] + bi + (dg[i][r] > 0 ? bm : 0.f) + ah[i][j][r] + bh;
                zg[i][j][r] = sigmoidf_(pre);
            }
        }

    // ---- pass 2: n gate + GRU combine + store ----
    run_pass(2, ai, ah);
#pragma unroll
    for (int i = 0; i < 2; ++i)
#pragma unroll
        for (int j = 0; j < 4; ++j) {
            const int gc = wc * 64 + j * 16 + lr;          // output col in D
            const int gg = 256 + gc;
            const float bi = bih[gg], bm = bmsg[gg], bh = bhh[gg];
#pragma unroll
            for (int r = 0; r < 4; ++r) {
                const int gr = bn + wr * 32 + i * 16 + lg * 4 + r;
                if (gr < N) {
                    float i_n = ai[i][j][r] + bi + (dg[i][r] > 0 ? bm : 0.f);
                    float h_n = ah[i][j][r] + bh;
                    float n = tanhf(i_n + rg[i][j][r] * h_n);
                    float hv = bf2f(H[(size_t)gr * 128 + gc]);
                    float o = (1.f - zg[i][j][r]) * n + zg[i][j][r] * hv;
                    H[(size_t)gr * 128 + gc] = f2bf(o);
                }
            }
        }
}

// ---------------- CSR gather: out[row] = (1/max(deg,1)) * sum msg[src], bf16 ----------------

__global__ void gather_kernel(const u16* __restrict__ msg, const int* __restrict__ off,
                              const int* __restrict__ edges, u16* __restrict__ ohi, int n) {
    int row = blockIdx.x * 4 + (threadIdx.x >> 6);
    if (row >= n) return;
    int lane = threadIdx.x & 63;
    int s = off[row], e = off[row + 1];
    float ax = 0.f, ay = 0.f;
    for (int i = s; i < e; ++i) {
        const ushort2 v = ((const ushort2*)(msg + (size_t)edges[i] * DD))[lane];
        ax += bf2f(v.x); ay += bf2f(v.y);
    }
    float sc = 1.0f / (float)((e - s) > 0 ? (e - s) : 1);
    *(ushort2*)(ohi + (size_t)row * DD + 2 * lane) = make_ushort2(f2bf(ax * sc), f2bf(ay * sc));
}

// ---------------- readout ----------------

__global__ __launch_bounds__(256)
void logit2_kernel(const float* __restrict__ hidden, const float* __restrict__ w2,
                   const int* __restrict__ l_batch,
                   float* __restrict__ gsum, float* __restrict__ gcnt, int Lc) {
    __shared__ float s_sum[BB];
    __shared__ float s_cnt[BB];
    const int tid = threadIdx.x;
    if (tid < BB) { s_sum[tid] = 0.f; s_cnt[tid] = 0.f; }
    __syncthreads();
    const int lane = tid & 63;
    const int gw = blockIdx.x * 4 + (tid >> 6);
    const int nw = gridDim.x * 4;
    const float2 wv = ((const float2*)w2)[lane];
    for (int row = gw; row < Lc; row += nw) {
        float2 h = ((const float2*)(hidden + (size_t)row * DD))[lane];
        float dp = h.x * wv.x + h.y * wv.y;
#pragma unroll
        for (int off = 32; off > 0; off >>= 1) dp += __shfl_down(dp, off);
        if (lane == 0) {
            int b = l_batch[row];
            atomicAdd(&s_sum[b], dp);
            atomicAdd(&s_cnt[b], 1.0f);
        }
    }
    __syncthreads();
    if (tid < BB) {
        atomicAdd(&gsum[tid], s_sum[tid]);
        atomicAdd(&gcnt[tid], s_cnt[tid]);
    }
}

__global__ void final_kernel(const float* __restrict__ gsum, const float* __restrict__ gcnt,
                             const float* __restrict__ b2, float* __restrict__ out) {
    int b = threadIdx.x;
    if (b < BB) {
        float m = gsum[b] / fmaxf(gcnt[b], 1.0f) + b2[0];
        out[b] = 1.0f / (1.0f + expf(-m));
    }
}

// ---------------- host side ----------------

static inline size_t align_up_(size_t x) { return (x + 255) & ~(size_t)255; }

extern "C" void kernel_launch(void* const* d_in, const int* in_sizes, int n_in,
                              void* d_out, int out_size, void* d_ws, size_t ws_size,
                              hipStream_t stream) {
    const int*   l_ei     = (const int*)d_in[0];
    const int*   c_ei     = (const int*)d_in[1];
    const int*   l_batch  = (const int*)d_in[2];
    const float* l_init   = (const float*)d_in[3];
    const float* c_init   = (const float*)d_in[4];
    const float* l2c_w1   = (const float*)d_in[5];
    const float* l2c_b1   = (const float*)d_in[6];
    const float* l2c_w2   = (const float*)d_in[7];
    const float* l2c_b2   = (const float*)d_in[8];
    const float* c2l_w1   = (const float*)d_in[9];
    const float* c2l_b1   = (const float*)d_in[10];
    const float* c2l_w2   = (const float*)d_in[11];
    const float* c2l_b2   = (const float*)d_in[12];
    const float* cgru_wih = (const float*)d_in[13];
    const float* cgru_whh = (const float*)d_in[14];
    const float* cgru_bih = (const float*)d_in[15];
    const float* cgru_bhh = (const float*)d_in[16];
    const float* lgru_wih = (const float*)d_in[17];
    const float* lgru_whh = (const float*)d_in[18];
    const float* lgru_bih = (const float*)d_in[19];
    const float* lgru_bhh = (const float*)d_in[20];
    const float* ro_w1    = (const float*)d_in[21];
    const float* ro_b1    = (const float*)d_in[22];
    const float* ro_w2    = (const float*)d_in[23];
    const float* ro_b2    = (const float*)d_in[24];

    const int E  = in_sizes[0];
    const int Lc = in_sizes[2];
    const int C  = CC;
    const int NMAX = (C > Lc ? C : Lc);

    // ---- workspace carve (~128 MB) ----
    char* p = (char*)d_ws;
    auto carve = [&](size_t bytes) { void* r = (void*)p; p += align_up_(bytes); return r; };
    u16*   l_emb   = (u16*)carve((size_t)Lc * DD * 2);
    u16*   c_emb   = (u16*)carve((size_t)C * DD * 2);
    u16*   hagg    = (u16*)carve((size_t)NMAX * DD * 2);
    u16*   msg     = (u16*)carve((size_t)NMAX * DD * 2);
    float* hiddenf = (float*)carve((size_t)Lc * DD * 4);
    int*   ideg_l  = (int*)carve((size_t)Lc * 4);
    int*   ideg_c  = (int*)carve((size_t)C * 4);
    int*   l_off   = (int*)carve((size_t)(Lc + 1) * 4);
    int*   c_off   = (int*)carve((size_t)(C + 1) * 4);
    int*   l_edges = (int*)carve((size_t)E * 4);
    int*   c_edges = (int*)carve((size_t)E * 4);
    int*   fillc   = (int*)carve((size_t)NMAX * 4);
    int*   bsums   = (int*)carve(64 * 4);
    float* Wf_c    = (float*)carve((size_t)384 * 128 * 4);
    float* Wcat    = (float*)carve((size_t)384 * 256 * 4);
    float* bmsg_c  = (float*)carve(384 * 4);
    float* bmsg_l  = (float*)carve(384 * 4);
    u16* w_l2c1 = (u16*)carve(128 * 128 * 2);
    u16* w_c2l1 = (u16*)carve(128 * 128 * 2);
    u16* w_ro1  = (u16*)carve(128 * 128 * 2);
    u16* w_gic  = (u16*)carve(384 * 128 * 2);
    u16* w_ghc  = (u16*)carve(384 * 128 * 2);
    u16* w_ghl  = (u16*)carve(384 * 128 * 2);
    u16* w_gil  = (u16*)carve(384 * 256 * 2);
    float* g_sum = (float*)carve(BB * 4);
    float* g_cnt = (float*)carve(BB * 4);
    (void)ws_size; (void)n_in; (void)out_size;

    // ---- degrees + CSR build ----
    hipMemsetAsync(ideg_l, 0, (size_t)Lc * 4, stream);
    hipMemsetAsync(ideg_c, 0, (size_t)C * 4, stream);
    ideg_kernel<<<(E + 255) / 256, 256, 0, stream>>>(l_ei, c_ei, ideg_l, ideg_c, E);
    {
        int nbc = (C + 4095) / 4096, nbl = (Lc + 4095) / 4096;
        bsum_kernel<<<nbc, 1024, 0, stream>>>(ideg_c, bsums, C);
        scan2_kernel<<<nbc, 1024, 0, stream>>>(ideg_c, bsums, c_off, C, nbc);
        bsum_kernel<<<nbl, 1024, 0, stream>>>(ideg_l, bsums, Lc);
        scan2_kernel<<<nbl, 1024, 0, stream>>>(ideg_l, bsums, l_off, Lc, nbl);
    }
    hipMemsetAsync(fillc, 0, (size_t)C * 4, stream);
    fill_kernel<<<(E + 255) / 256, 256, 0, stream>>>(c_ei, l_ei, c_off, fillc, c_edges, E);
    hipMemsetAsync(fillc, 0, (size_t)Lc * 4, stream);
    fill_kernel<<<(E + 255) / 256, 256, 0, stream>>>(l_ei, c_ei, l_off, fillc, l_edges, E);

    // ---- weight folds: Wf_c = cgru_wih @ l2c_w2 ; Wcat = [lgru_wihA @ c2l_w2 | lgru_wihB] ----
    foldw_kernel<<<(384 * 128 + 255) / 256, 256, 0, stream>>>(cgru_wih, 128, l2c_w2, Wf_c, 128, 384);
    foldb_kernel<<<2, 256, 0, stream>>>(cgru_wih, 128, l2c_b2, bmsg_c, 384);
    hipMemcpyAsync(Wcat, lgru_wih, (size_t)384 * 256 * 4, hipMemcpyDeviceToDevice, stream);
    foldw_kernel<<<(384 * 128 + 255) / 256, 256, 0, stream>>>(lgru_wih, 256, c2l_w2, Wcat, 256, 384);
    foldb_kernel<<<2, 256, 0, stream>>>(lgru_wih, 256, c2l_b2, bmsg_l, 384);

    // ---- bf16 weight conversion ----
    cvtw_kernel<<<(128 * 128 + 255) / 256, 256, 0, stream>>>(l2c_w1, w_l2c1, 128 * 128);
    cvtw_kernel<<<(128 * 128 + 255) / 256, 256, 0, stream>>>(c2l_w1, w_c2l1, 128 * 128);
    cvtw_kernel<<<(128 * 128 + 255) / 256, 256, 0, stream>>>(ro_w1, w_ro1, 128 * 128);
    cvtw_kernel<<<(384 * 128 + 255) / 256, 256, 0, stream>>>(Wf_c, w_gic, 384 * 128);
    cvtw_kernel<<<(384 * 128 + 255) / 256, 256, 0, stream>>>(cgru_whh, w_ghc, 384 * 128);
    cvtw_kernel<<<(384 * 128 + 255) / 256, 256, 0, stream>>>(lgru_whh, w_ghl, 384 * 128);
    cvtw_kernel<<<(384 * 256 + 255) / 256, 256, 0, stream>>>(Wcat, w_gil, 384 * 256);

    // ---- init embeddings ----
    init_emb_kernel<<<((size_t)Lc * DD + 255) / 256, 256, 0, stream>>>(l_init, l_emb, Lc * DD);
    init_emb_kernel<<<((size_t)C * DD + 255) / 256, 256, 0, stream>>>(c_init, c_emb, C * DD);

    for (int it = 0; it < N_ITER; ++it) {
        // ---- literal -> clause ----
        mfma_gemm<true, true><<<dim3((Lc + 127) / 128, 1), 256, 0, stream>>>(
            l_emb, w_l2c1, l2c_b1, msg, Lc, 128);
        gather_kernel<<<(C + 3) / 4, 256, 0, stream>>>(msg, c_off, c_edges, hagg, C);
        gru_fused<false><<<(C + 63) / 64, 256, 0, stream>>>(
            hagg, nullptr, c_emb, w_gic, w_ghc, cgru_bih, bmsg_c, cgru_bhh, ideg_c, C);

        // ---- clause -> literal ----
        mfma_gemm<true, true><<<dim3((C + 127) / 128, 1), 256, 0, stream>>>(
            c_emb, w_c2l1, c2l_b1, msg, C, 128);
        gather_kernel<<<(Lc + 3) / 4, 256, 0, stream>>>(msg, l_off, l_edges, hagg, Lc);
        gru_fused<true><<<(Lc + 63) / 64, 256, 0, stream>>>(
            hagg, l_emb, l_emb, w_gil, w_ghl, lgru_bih, bmsg_l, lgru_bhh, ideg_l, Lc);
    }

    // ---- readout ----
    mfma_gemm<true, false><<<dim3((Lc + 127) / 128, 1), 256, 0, stream>>>(
        l_emb, w_ro1, ro_b1, hiddenf, Lc, 128);
    hipMemsetAsync(g_sum, 0, BB * 4, stream);
    hipMemsetAsync(g_cnt, 0, BB * 4, stream);
    logit2_kernel<<<1024, 256, 0, stream>>>(hiddenf, ro_w2, l_batch, g_sum, g_cnt, Lc);
    final_kernel<<<1, 64, 0, stream>>>(g_sum, g_cnt, ro_b2, (float*)d_out);
}

// Round 7
// 1385.353 us; speedup vs baseline: 4.8166x; 1.3261x over previous
//
#include <hip/hip_runtime.h>
#include <hip/hip_bf16.h>

#define DD 128
#define CC 100000
#define BB 32
#define N_ITER 4
#define INV_INIT_NORM 0.125f   // 1/(sqrt(128)/sqrt(2)) = 1/8

typedef unsigned short u16;
typedef __attribute__((ext_vector_type(8))) short  frag_ab;   // 8 bf16 (4 VGPRs)
typedef __attribute__((ext_vector_type(4))) float  f32x4;
typedef __attribute__((ext_vector_type(8))) unsigned short us8;

__device__ __forceinline__ u16 f2bf(float f) {
    union { float f; unsigned u; } v; v.f = f;
    unsigned r = v.u + 0x7fff + ((v.u >> 16) & 1);   // RNE
    return (u16)(r >> 16);
}
__device__ __forceinline__ float bf2f(u16 h) {
    union { unsigned u; float f; } v; v.u = ((unsigned)h) << 16;
    return v.f;
}
__device__ __forceinline__ float sigmoidf_(float x) { return 1.0f / (1.0f + expf(-x)); }

// ---------------- precompute: degrees / hierarchical scan / CSR fill ----------------

__global__ void ideg_kernel(const int* __restrict__ li, const int* __restrict__ ci,
                            int* __restrict__ idl, int* __restrict__ idc, int E) {
    int e = blockIdx.x * 256 + threadIdx.x;
    if (e < E) {
        atomicAdd(&idl[li[e]], 1);
        atomicAdd(&idc[ci[e]], 1);
    }
}

__global__ __launch_bounds__(1024)
void bsum_kernel(const int* __restrict__ deg, int* __restrict__ bsum, int n) {
    __shared__ int wred[16];
    const int tid = threadIdx.x, lane = tid & 63, wid = tid >> 6;
    int idx = blockIdx.x * 4096 + tid * 4;
    int s = 0;
#pragma unroll
    for (int j = 0; j < 4; ++j) if (idx + j < n) s += deg[idx + j];
#pragma unroll
    for (int o = 32; o > 0; o >>= 1) s += __shfl_down(s, o);
    if (lane == 0) wred[wid] = s;
    __syncthreads();
    if (tid == 0) {
        int t = 0;
#pragma unroll
        for (int k = 0; k < 16; ++k) t += wred[k];
        bsum[blockIdx.x] = t;
    }
}

__global__ __launch_bounds__(1024)
void scan2_kernel(const int* __restrict__ deg, const int* __restrict__ bsum,
                  int* __restrict__ off, int n, int nb) {
    __shared__ int wsum[16];
    __shared__ int carry_s;
    const int tid = threadIdx.x, lane = tid & 63, wid = tid >> 6;
    if (tid == 0) {
        int c = 0;
        for (int b = 0; b < blockIdx.x; ++b) c += bsum[b];
        carry_s = c;
    }
    int idx = blockIdx.x * 4096 + tid * 4;
    int v0 = idx     < n ? deg[idx]     : 0;
    int v1 = idx + 1 < n ? deg[idx + 1] : 0;
    int v2 = idx + 2 < n ? deg[idx + 2] : 0;
    int v3 = idx + 3 < n ? deg[idx + 3] : 0;
    int t = v0 + v1 + v2 + v3;
    int s = t;
#pragma unroll
    for (int o = 1; o < 64; o <<= 1) { int u = __shfl_up(s, o); if (lane >= o) s += u; }
    if (lane == 63) wsum[wid] = s;
    __syncthreads();
    if (wid == 0 && lane < 16) {
        int x = wsum[lane];
#pragma unroll
        for (int o = 1; o < 16; o <<= 1) { int u = __shfl_up(x, o); if (lane >= o) x += u; }
        wsum[lane] = x;
    }
    __syncthreads();
    int woff = (wid > 0) ? wsum[wid - 1] : 0;
    int excl = carry_s + woff + s - t;
    if (idx     < n) off[idx]     = excl;
    if (idx + 1 < n) off[idx + 1] = excl + v0;
    if (idx + 2 < n) off[idx + 2] = excl + v0 + v1;
    if (idx + 3 < n) off[idx + 3] = excl + v0 + v1 + v2;
    if (blockIdx.x == nb - 1 && tid == 0) off[n] = carry_s + wsum[15];
}

__global__ void fill_kernel(const int* __restrict__ dst, const int* __restrict__ src,
                            const int* __restrict__ off, int* __restrict__ fill,
                            int* __restrict__ edges, int E) {
    int e = blockIdx.x * 256 + threadIdx.x;
    if (e < E) {
        int d = dst[e];
        int p = atomicAdd(&fill[d], 1);
        edges[off[d] + p] = src[e];
    }
}

// ---------------- precompute: weight folds / bf16 conversion ----------------

__global__ void foldw_kernel(const float* __restrict__ wih, int ldw,
                             const float* __restrict__ w2,
                             float* __restrict__ out, int out_ld, int M) {
    int idx = blockIdx.x * 256 + threadIdx.x;
    if (idx >= M * 128) return;
    int o = idx >> 7, k = idx & 127;
    float s = 0.f;
    for (int m = 0; m < 128; ++m) s += wih[(size_t)o * ldw + m] * w2[m * 128 + k];
    out[(size_t)o * out_ld + k] = s;
}

__global__ void foldb_kernel(const float* __restrict__ wih, int ldw,
                             const float* __restrict__ b2,
                             float* __restrict__ out, int M) {
    int o = blockIdx.x * 256 + threadIdx.x;
    if (o >= M) return;
    float s = 0.f;
    for (int m = 0; m < 128; ++m) s += wih[(size_t)o * ldw + m] * b2[m];
    out[o] = s;
}

__global__ void cvtw_kernel(const float* __restrict__ w, u16* __restrict__ hi, int n) {
    int i = blockIdx.x * 256 + threadIdx.x;
    if (i < n) hi[i] = f2bf(w[i]);
}

__global__ void init_emb_kernel(const float* __restrict__ init, u16* __restrict__ hi, int n) {
    int i = blockIdx.x * 256 + threadIdx.x;
    if (i < n) hi[i] = f2bf(init[i & (DD - 1)] * INV_INIT_NORM);
}

// ---------------- bf16 MFMA GEMM (msg MLP + readout) ----------------

template<bool RELU, bool OUTBF16>
__global__ __launch_bounds__(256)
void mfma_gemm(const u16* __restrict__ Ahi, const u16* __restrict__ Whi,
               const float* __restrict__ bias, void* __restrict__ Yv, int N, int M) {
    __shared__ u16 Ah[4][128][8], Wh[4][128][8];

    const int tid = threadIdx.x;
    const int bn = blockIdx.x * 128, bm = blockIdx.y * 128;
    const int l = tid & 63, w = tid >> 6;
    const int wr = w >> 1, wc = w & 1;
    const int lr = l & 15, lg = l >> 4;

    f32x4 acc[4][4];
#pragma unroll
    for (int i = 0; i < 4; ++i)
#pragma unroll
        for (int j = 0; j < 4; ++j) acc[i][j] = (f32x4){0.f, 0.f, 0.f, 0.f};

    for (int k0 = 0; k0 < 128; k0 += 32) {
#pragma unroll
        for (int t = 0; t < 2; ++t) {
            const int slot = t * 256 + tid;
            const int row = slot >> 2, g = slot & 3, rs = row ^ (g << 1);
            const int gr = bn + row;
            us8 vh = (us8)0;
            if (gr < N) vh = *(const us8*)(Ahi + (size_t)gr * 128 + k0 + g * 8);
            *(us8*)&Ah[g][rs][0] = vh;
            *(us8*)&Wh[g][rs][0] = *(const us8*)(Whi + (size_t)(bm + row) * 128 + k0 + g * 8);
        }
        __syncthreads();

        frag_ab a_h[4], b_h[4];
#pragma unroll
        for (int i = 0; i < 4; ++i) {
            const int ra = wr * 64 + i * 16 + lr;
            a_h[i] = *(const frag_ab*)&Ah[lg][ra ^ (lg << 1)][0];
            const int rb = wc * 64 + i * 16 + lr;
            b_h[i] = *(const frag_ab*)&Wh[lg][rb ^ (lg << 1)][0];
        }
#pragma unroll
        for (int i = 0; i < 4; ++i)
#pragma unroll
            for (int j = 0; j < 4; ++j)
                acc[i][j] = __builtin_amdgcn_mfma_f32_16x16x32_bf16(a_h[i], b_h[j], acc[i][j], 0, 0, 0);
        __syncthreads();
    }

#pragma unroll
    for (int j = 0; j < 4; ++j) {
        const int gc = bm + wc * 64 + j * 16 + lr;
        const float bj = bias[gc];
#pragma unroll
        for (int i = 0; i < 4; ++i) {
            const int grb = bn + wr * 64 + i * 16 + lg * 4;
#pragma unroll
            for (int r = 0; r < 4; ++r) {
                const int gr = grb + r;
                if (gr < N) {
                    float o = acc[i][j][r] + bj;
                    if (RELU) o = fmaxf(o, 0.f);
                    if (OUTBF16) ((u16*)Yv)[(size_t)gr * M + gc] = f2bf(o);
                    else         ((float*)Yv)[(size_t)gr * M + gc] = o;
                }
            }
        }
    }
}

// ---------------- weight-stationary fused GRU ----------------
// Block = 256 thr / 4 waves; blockIdx: cg = bid&3 (owns output dims d in
// [cg*32,cg*32+32)), rowblk = bid>>2 (128 rows; wave w owns 32 rows).
// Weight slice (96 gate rows: {r,z,n} x 32 dims) staged ONCE in LDS with
// k8^row XOR swizzle (2-way-free ds_read_b128 B-frags). A-frags (X,H rows)
// load straight global->VGPR (rows wave-exclusive). gates in registers,
// H_out written bf16 (ping-pong, never in-place: col-split would race).

template<bool XCAT>
__global__ __launch_bounds__(256)
void gru_wsta(const u16* __restrict__ X, const u16* __restrict__ X2,
              const u16* __restrict__ Hin, u16* __restrict__ Hout,
              const u16* __restrict__ Wih, const u16* __restrict__ Whh,
              const float* __restrict__ bih, const float* __restrict__ bmsg,
              const float* __restrict__ bhh, const int* __restrict__ ideg,
              int N) {
    constexpr int KX = XCAT ? 256 : 128;
    constexpr int KX8 = KX / 8;
    __shared__ u16 Wih_s[96 * KX];    // XCAT 48KB else 24KB
    __shared__ u16 Whh_s[96 * 128];   // 24KB

    const int tid = threadIdx.x;
    const int cg = blockIdx.x & 3;
    const int rw = (blockIdx.x >> 2) * 128 + (tid >> 6) * 32;  // wave's 32 rows
    const int l = tid & 63;
    const int lr = l & 15, lg = l >> 4;

    // ---- stage weight slice into LDS (once) ----
    for (int s = tid; s < 96 * KX8; s += 256) {
        int rloc = s / KX8, k8 = s % KX8;
        int grow = (rloc >> 5) * 128 + cg * 32 + (rloc & 31);
        *(us8*)&Wih_s[rloc * KX + ((k8 ^ (rloc & 7)) << 3)] =
            *(const us8*)(Wih + (size_t)grow * KX + k8 * 8);
    }
    for (int s = tid; s < 96 * 16; s += 256) {
        int rloc = s >> 4, k8 = s & 15;
        int grow = (rloc >> 5) * 128 + cg * 32 + (rloc & 31);
        *(us8*)&Whh_s[rloc * 128 + ((k8 ^ (rloc & 7)) << 3)] =
            *(const us8*)(Whh + (size_t)grow * 128 + k8 * 8);
    }
    __syncthreads();
    if (rw >= N) return;   // no further barriers below

    const int ra0 = rw + lr, ra1 = rw + 16 + lr;

    f32x4 ai[6][2], ah[6][2];
#pragma unroll
    for (int j = 0; j < 6; ++j)
#pragma unroll
        for (int i = 0; i < 2; ++i) {
            ai[j][i] = (f32x4){0.f, 0.f, 0.f, 0.f};
            ah[j][i] = (f32x4){0.f, 0.f, 0.f, 0.f};
        }

    // ---- X @ Wih^T ----
#pragma unroll
    for (int ks = 0; ks < KX / 32; ++ks) {
        us8 v0 = (us8)0, v1 = (us8)0;
        if (XCAT && ks >= 4) {
            const int k = (ks - 4) * 32 + lg * 8;
            if (ra0 < N) v0 = *(const us8*)(X2 + (size_t)(ra0 ^ 1) * 128 + k);
            if (ra1 < N) v1 = *(const us8*)(X2 + (size_t)(ra1 ^ 1) * 128 + k);
        } else {
            const int k = ks * 32 + lg * 8;
            if (ra0 < N) v0 = *(const us8*)(X + (size_t)ra0 * 128 + k);
            if (ra1 < N) v1 = *(const us8*)(X + (size_t)ra1 * 128 + k);
        }
        frag_ab a0 = *(const frag_ab*)&v0, a1 = *(const frag_ab*)&v1;
        const int k8 = ks * 4 + lg;
#pragma unroll
        for (int j = 0; j < 6; ++j) {
            const int rloc = j * 16 + lr;
            frag_ab b = *(const frag_ab*)&Wih_s[rloc * KX + ((k8 ^ (rloc & 7)) << 3)];
            ai[j][0] = __builtin_amdgcn_mfma_f32_16x16x32_bf16(a0, b, ai[j][0], 0, 0, 0);
            ai[j][1] = __builtin_amdgcn_mfma_f32_16x16x32_bf16(a1, b, ai[j][1], 0, 0, 0);
        }
    }
    // ---- H @ Whh^T ----
#pragma unroll
    for (int ks = 0; ks < 4; ++ks) {
        const int k = ks * 32 + lg * 8;
        us8 v0 = (us8)0, v1 = (us8)0;
        if (ra0 < N) v0 = *(const us8*)(Hin + (size_t)ra0 * 128 + k);
        if (ra1 < N) v1 = *(const us8*)(Hin + (size_t)ra1 * 128 + k);
        frag_ab a0 = *(const frag_ab*)&v0, a1 = *(const frag_ab*)&v1;
        const int k8 = ks * 4 + lg;
#pragma unroll
        for (int j = 0; j < 6; ++j) {
            const int rloc = j * 16 + lr;
            frag_ab b = *(const frag_ab*)&Whh_s[rloc * 128 + ((k8 ^ (rloc & 7)) << 3)];
            ah[j][0] = __builtin_amdgcn_mfma_f32_16x16x32_bf16(a0, b, ah[j][0], 0, 0, 0);
            ah[j][1] = __builtin_amdgcn_mfma_f32_16x16x32_bf16(a1, b, ah[j][1], 0, 0, 0);
        }
    }

    // ---- gate combine + writeback (C/D layout: col=lane&15, row=(lane>>4)*4+r) ----
#pragma unroll
    for (int i = 0; i < 2; ++i) {
#pragma unroll
        for (int dh = 0; dh < 2; ++dh) {
            const int d = cg * 32 + dh * 16 + lr;
            const float bi_r = bih[d],       bh_r = bhh[d],       bm_r = bmsg[d];
            const float bi_z = bih[128 + d], bh_z = bhh[128 + d], bm_z = bmsg[128 + d];
            const float bi_n = bih[256 + d], bh_n = bhh[256 + d], bm_n = bmsg[256 + d];
#pragma unroll
            for (int r = 0; r < 4; ++r) {
                const int grow = rw + i * 16 + lg * 4 + r;
                if (grow < N) {
                    const bool hd = ideg[grow] > 0;
                    float rp = ai[0 + dh][i][r] + bi_r + (hd ? bm_r : 0.f) + ah[0 + dh][i][r] + bh_r;
                    float zp = ai[2 + dh][i][r] + bi_z + (hd ? bm_z : 0.f) + ah[2 + dh][i][r] + bh_z;
                    float np_i = ai[4 + dh][i][r] + bi_n + (hd ? bm_n : 0.f);
                    float np_h = ah[4 + dh][i][r] + bh_n;
                    float rg = sigmoidf_(rp);
                    float zg = sigmoidf_(zp);
                    float ng = tanhf(np_i + rg * np_h);
                    float hv = bf2f(Hin[(size_t)grow * 128 + d]);
                    Hout[(size_t)grow * 128 + d] = f2bf((1.f - zg) * ng + zg * hv);
                }
            }
        }
    }
}

// ---------------- CSR gather: out[row] = (1/max(deg,1)) * sum msg[src], bf16 ----------------

__global__ void gather_kernel(const u16* __restrict__ msg, const int* __restrict__ off,
                              const int* __restrict__ edges, u16* __restrict__ ohi, int n) {
    int row = blockIdx.x * 4 + (threadIdx.x >> 6);
    if (row >= n) return;
    int lane = threadIdx.x & 63;
    int s = off[row], e = off[row + 1];
    float ax = 0.f, ay = 0.f;
    for (int i = s; i < e; ++i) {
        const ushort2 v = ((const ushort2*)(msg + (size_t)edges[i] * DD))[lane];
        ax += bf2f(v.x); ay += bf2f(v.y);
    }
    float sc = 1.0f / (float)((e - s) > 0 ? (e - s) : 1);
    *(ushort2*)(ohi + (size_t)row * DD + 2 * lane) = make_ushort2(f2bf(ax * sc), f2bf(ay * sc));
}

// ---------------- readout ----------------

__global__ __launch_bounds__(256)
void logit2_kernel(const float* __restrict__ hidden, const float* __restrict__ w2,
                   const int* __restrict__ l_batch,
                   float* __restrict__ gsum, float* __restrict__ gcnt, int Lc) {
    __shared__ float s_sum[BB];
    __shared__ float s_cnt[BB];
    const int tid = threadIdx.x;
    if (tid < BB) { s_sum[tid] = 0.f; s_cnt[tid] = 0.f; }
    __syncthreads();
    const int lane = tid & 63;
    const int gw = blockIdx.x * 4 + (tid >> 6);
    const int nw = gridDim.x * 4;
    const float2 wv = ((const float2*)w2)[lane];
    for (int row = gw; row < Lc; row += nw) {
        float2 h = ((const float2*)(hidden + (size_t)row * DD))[lane];
        float dp = h.x * wv.x + h.y * wv.y;
#pragma unroll
        for (int off = 32; off > 0; off >>= 1) dp += __shfl_down(dp, off);
        if (lane == 0) {
            int b = l_batch[row];
            atomicAdd(&s_sum[b], dp);
            atomicAdd(&s_cnt[b], 1.0f);
        }
    }
    __syncthreads();
    if (tid < BB) {
        atomicAdd(&gsum[tid], s_sum[tid]);
        atomicAdd(&gcnt[tid], s_cnt[tid]);
    }
}

__global__ void final_kernel(const float* __restrict__ gsum, const float* __restrict__ gcnt,
                             const float* __restrict__ b2, float* __restrict__ out) {
    int b = threadIdx.x;
    if (b < BB) {
        float m = gsum[b] / fmaxf(gcnt[b], 1.0f) + b2[0];
        out[b] = 1.0f / (1.0f + expf(-m));
    }
}

// ---------------- host side ----------------

static inline size_t align_up_(size_t x) { return (x + 255) & ~(size_t)255; }

extern "C" void kernel_launch(void* const* d_in, const int* in_sizes, int n_in,
                              void* d_out, int out_size, void* d_ws, size_t ws_size,
                              hipStream_t stream) {
    const int*   l_ei     = (const int*)d_in[0];
    const int*   c_ei     = (const int*)d_in[1];
    const int*   l_batch  = (const int*)d_in[2];
    const float* l_init   = (const float*)d_in[3];
    const float* c_init   = (const float*)d_in[4];
    const float* l2c_w1   = (const float*)d_in[5];
    const float* l2c_b1   = (const float*)d_in[6];
    const float* l2c_w2   = (const float*)d_in[7];
    const float* l2c_b2   = (const float*)d_in[8];
    const float* c2l_w1   = (const float*)d_in[9];
    const float* c2l_b1   = (const float*)d_in[10];
    const float* c2l_w2   = (const float*)d_in[11];
    const float* c2l_b2   = (const float*)d_in[12];
    const float* cgru_wih = (const float*)d_in[13];
    const float* cgru_whh = (const float*)d_in[14];
    const float* cgru_bih = (const float*)d_in[15];
    const float* cgru_bhh = (const float*)d_in[16];
    const float* lgru_wih = (const float*)d_in[17];
    const float* lgru_whh = (const float*)d_in[18];
    const float* lgru_bih = (const float*)d_in[19];
    const float* lgru_bhh = (const float*)d_in[20];
    const float* ro_w1    = (const float*)d_in[21];
    const float* ro_b1    = (const float*)d_in[22];
    const float* ro_w2    = (const float*)d_in[23];
    const float* ro_b2    = (const float*)d_in[24];

    const int E  = in_sizes[0];
    const int Lc = in_sizes[2];
    const int C  = CC;
    const int NMAX = (C > Lc ? C : Lc);

    // ---- workspace carve (~170 MB) ----
    char* p = (char*)d_ws;
    auto carve = [&](size_t bytes) { void* r = (void*)p; p += align_up_(bytes); return r; };
    u16*   l_embA  = (u16*)carve((size_t)Lc * DD * 2);
    u16*   l_embB  = (u16*)carve((size_t)Lc * DD * 2);
    u16*   c_embA  = (u16*)carve((size_t)C * DD * 2);
    u16*   c_embB  = (u16*)carve((size_t)C * DD * 2);
    u16*   hagg    = (u16*)carve((size_t)NMAX * DD * 2);
    u16*   msg     = (u16*)carve((size_t)NMAX * DD * 2);
    float* hiddenf = (float*)carve((size_t)Lc * DD * 4);
    int*   ideg_l  = (int*)carve((size_t)Lc * 4);
    int*   ideg_c  = (int*)carve((size_t)C * 4);
    int*   l_off   = (int*)carve((size_t)(Lc + 1) * 4);
    int*   c_off   = (int*)carve((size_t)(C + 1) * 4);
    int*   l_edges = (int*)carve((size_t)E * 4);
    int*   c_edges = (int*)carve((size_t)E * 4);
    int*   fillc   = (int*)carve((size_t)NMAX * 4);
    int*   bsums   = (int*)carve(64 * 4);
    float* Wf_c    = (float*)carve((size_t)384 * 128 * 4);
    float* Wcat    = (float*)carve((size_t)384 * 256 * 4);
    float* bmsg_c  = (float*)carve(384 * 4);
    float* bmsg_l  = (float*)carve(384 * 4);
    u16* w_l2c1 = (u16*)carve(128 * 128 * 2);
    u16* w_c2l1 = (u16*)carve(128 * 128 * 2);
    u16* w_ro1  = (u16*)carve(128 * 128 * 2);
    u16* w_gic  = (u16*)carve(384 * 128 * 2);
    u16* w_ghc  = (u16*)carve(384 * 128 * 2);
    u16* w_ghl  = (u16*)carve(384 * 128 * 2);
    u16* w_gil  = (u16*)carve(384 * 256 * 2);
    float* g_sum = (float*)carve(BB * 4);
    float* g_cnt = (float*)carve(BB * 4);
    (void)ws_size; (void)n_in; (void)out_size;

    // ---- degrees + CSR build ----
    hipMemsetAsync(ideg_l, 0, (size_t)Lc * 4, stream);
    hipMemsetAsync(ideg_c, 0, (size_t)C * 4, stream);
    ideg_kernel<<<(E + 255) / 256, 256, 0, stream>>>(l_ei, c_ei, ideg_l, ideg_c, E);
    {
        int nbc = (C + 4095) / 4096, nbl = (Lc + 4095) / 4096;
        bsum_kernel<<<nbc, 1024, 0, stream>>>(ideg_c, bsums, C);
        scan2_kernel<<<nbc, 1024, 0, stream>>>(ideg_c, bsums, c_off, C, nbc);
        bsum_kernel<<<nbl, 1024, 0, stream>>>(ideg_l, bsums, Lc);
        scan2_kernel<<<nbl, 1024, 0, stream>>>(ideg_l, bsums, l_off, Lc, nbl);
    }
    hipMemsetAsync(fillc, 0, (size_t)C * 4, stream);
    fill_kernel<<<(E + 255) / 256, 256, 0, stream>>>(c_ei, l_ei, c_off, fillc, c_edges, E);
    hipMemsetAsync(fillc, 0, (size_t)Lc * 4, stream);
    fill_kernel<<<(E + 255) / 256, 256, 0, stream>>>(l_ei, c_ei, l_off, fillc, l_edges, E);

    // ---- weight folds: Wf_c = cgru_wih @ l2c_w2 ; Wcat = [lgru_wihA @ c2l_w2 | lgru_wihB] ----
    foldw_kernel<<<(384 * 128 + 255) / 256, 256, 0, stream>>>(cgru_wih, 128, l2c_w2, Wf_c, 128, 384);
    foldb_kernel<<<2, 256, 0, stream>>>(cgru_wih, 128, l2c_b2, bmsg_c, 384);
    hipMemcpyAsync(Wcat, lgru_wih, (size_t)384 * 256 * 4, hipMemcpyDeviceToDevice, stream);
    foldw_kernel<<<(384 * 128 + 255) / 256, 256, 0, stream>>>(lgru_wih, 256, c2l_w2, Wcat, 256, 384);
    foldb_kernel<<<2, 256, 0, stream>>>(lgru_wih, 256, c2l_b2, bmsg_l, 384);

    // ---- bf16 weight conversion ----
    cvtw_kernel<<<(128 * 128 + 255) / 256, 256, 0, stream>>>(l2c_w1, w_l2c1, 128 * 128);
    cvtw_kernel<<<(128 * 128 + 255) / 256, 256, 0, stream>>>(c2l_w1, w_c2l1, 128 * 128);
    cvtw_kernel<<<(128 * 128 + 255) / 256, 256, 0, stream>>>(ro_w1, w_ro1, 128 * 128);
    cvtw_kernel<<<(384 * 128 + 255) / 256, 256, 0, stream>>>(Wf_c, w_gic, 384 * 128);
    cvtw_kernel<<<(384 * 128 + 255) / 256, 256, 0, stream>>>(cgru_whh, w_ghc, 384 * 128);
    cvtw_kernel<<<(384 * 128 + 255) / 256, 256, 0, stream>>>(lgru_whh, w_ghl, 384 * 128);
    cvtw_kernel<<<(384 * 256 + 255) / 256, 256, 0, stream>>>(Wcat, w_gil, 384 * 256);

    // ---- init embeddings ----
    init_emb_kernel<<<((size_t)Lc * DD + 255) / 256, 256, 0, stream>>>(l_init, l_embA, Lc * DD);
    init_emb_kernel<<<((size_t)C * DD + 255) / 256, 256, 0, stream>>>(c_init, c_embA, C * DD);

    u16* l_cur = l_embA; u16* l_nxt = l_embB;
    u16* c_cur = c_embA; u16* c_nxt = c_embB;

    for (int it = 0; it < N_ITER; ++it) {
        // ---- literal -> clause ----
        mfma_gemm<true, true><<<dim3((Lc + 127) / 128, 1), 256, 0, stream>>>(
            l_cur, w_l2c1, l2c_b1, msg, Lc, 128);
        gather_kernel<<<(C + 3) / 4, 256, 0, stream>>>(msg, c_off, c_edges, hagg, C);
        gru_wsta<false><<<4 * ((C + 127) / 128), 256, 0, stream>>>(
            hagg, nullptr, c_cur, c_nxt, w_gic, w_ghc, cgru_bih, bmsg_c, cgru_bhh, ideg_c, C);
        { u16* t = c_cur; c_cur = c_nxt; c_nxt = t; }

        // ---- clause -> literal ----
        mfma_gemm<true, true><<<dim3((C + 127) / 128, 1), 256, 0, stream>>>(
            c_cur, w_c2l1, c2l_b1, msg, C, 128);
        gather_kernel<<<(Lc + 3) / 4, 256, 0, stream>>>(msg, l_off, l_edges, hagg, Lc);
        gru_wsta<true><<<4 * ((Lc + 127) / 128), 256, 0, stream>>>(
            hagg, l_cur, l_cur, l_nxt, w_gil, w_ghl, lgru_bih, bmsg_l, lgru_bhh, ideg_l, Lc);
        { u16* t = l_cur; l_cur = l_nxt; l_nxt = t; }
    }

    // ---- readout ----
    mfma_gemm<true, false><<<dim3((Lc + 127) / 128, 1), 256, 0, stream>>>(
        l_cur, w_ro1, ro_b1, hiddenf, Lc, 128);
    hipMemsetAsync(g_sum, 0, BB * 4, stream);
    hipMemsetAsync(g_cnt, 0, BB * 4, stream);
    logit2_kernel<<<1024, 256, 0, stream>>>(hiddenf, ro_w2, l_batch, g_sum, g_cnt, Lc);
    final_kernel<<<1, 64, 0, stream>>>(g_sum, g_cnt, ro_b2, (float*)d_out);
}

// Round 8
// 1281.049 us; speedup vs baseline: 5.2087x; 1.0814x over previous
//
#include <hip/hip_runtime.h>
#include <hip/hip_bf16.h>

#define DD 128
#define CC 100000
#define BB 32
#define N_ITER 4
#define INV_INIT_NORM 0.125f   // 1/(sqrt(128)/sqrt(2)) = 1/8

typedef unsigned short u16;
typedef __attribute__((ext_vector_type(8))) short  frag_ab;   // 8 bf16 (4 VGPRs)
typedef __attribute__((ext_vector_type(4))) float  f32x4;
typedef __attribute__((ext_vector_type(8))) unsigned short us8;

__device__ __forceinline__ u16 f2bf(float f) {
    union { float f; unsigned u; } v; v.f = f;
    unsigned r = v.u + 0x7fff + ((v.u >> 16) & 1);   // RNE
    return (u16)(r >> 16);
}
__device__ __forceinline__ float bf2f(u16 h) {
    union { unsigned u; float f; } v; v.u = ((unsigned)h) << 16;
    return v.f;
}
__device__ __forceinline__ float sigmoidf_(float x) { return 1.0f / (1.0f + expf(-x)); }

// ---------------- precompute: degrees / hierarchical scan / CSR fill ----------------

__global__ void ideg_kernel(const int* __restrict__ li, const int* __restrict__ ci,
                            int* __restrict__ idl, int* __restrict__ idc, int E) {
    int e = blockIdx.x * 256 + threadIdx.x;
    if (e < E) {
        atomicAdd(&idl[li[e]], 1);
        atomicAdd(&idc[ci[e]], 1);
    }
}

__global__ __launch_bounds__(1024)
void bsum_kernel(const int* __restrict__ deg, int* __restrict__ bsum, int n) {
    __shared__ int wred[16];
    const int tid = threadIdx.x, lane = tid & 63, wid = tid >> 6;
    int idx = blockIdx.x * 4096 + tid * 4;
    int s = 0;
#pragma unroll
    for (int j = 0; j < 4; ++j) if (idx + j < n) s += deg[idx + j];
#pragma unroll
    for (int o = 32; o > 0; o >>= 1) s += __shfl_down(s, o);
    if (lane == 0) wred[wid] = s;
    __syncthreads();
    if (tid == 0) {
        int t = 0;
#pragma unroll
        for (int k = 0; k < 16; ++k) t += wred[k];
        bsum[blockIdx.x] = t;
    }
}

__global__ __launch_bounds__(1024)
void scan2_kernel(const int* __restrict__ deg, const int* __restrict__ bsum,
                  int* __restrict__ off, int n, int nb) {
    __shared__ int wsum[16];
    __shared__ int carry_s;
    const int tid = threadIdx.x, lane = tid & 63, wid = tid >> 6;
    if (tid == 0) {
        int c = 0;
        for (int b = 0; b < blockIdx.x; ++b) c += bsum[b];
        carry_s = c;
    }
    int idx = blockIdx.x * 4096 + tid * 4;
    int v0 = idx     < n ? deg[idx]     : 0;
    int v1 = idx + 1 < n ? deg[idx + 1] : 0;
    int v2 = idx + 2 < n ? deg[idx + 2] : 0;
    int v3 = idx + 3 < n ? deg[idx + 3] : 0;
    int t = v0 + v1 + v2 + v3;
    int s = t;
#pragma unroll
    for (int o = 1; o < 64; o <<= 1) { int u = __shfl_up(s, o); if (lane >= o) s += u; }
    if (lane == 63) wsum[wid] = s;
    __syncthreads();
    if (wid == 0 && lane < 16) {
        int x = wsum[lane];
#pragma unroll
        for (int o = 1; o < 16; o <<= 1) { int u = __shfl_up(x, o); if (lane >= o) x += u; }
        wsum[lane] = x;
    }
    __syncthreads();
    int woff = (wid > 0) ? wsum[wid - 1] : 0;
    int excl = carry_s + woff + s - t;
    if (idx     < n) off[idx]     = excl;
    if (idx + 1 < n) off[idx + 1] = excl + v0;
    if (idx + 2 < n) off[idx + 2] = excl + v0 + v1;
    if (idx + 3 < n) off[idx + 3] = excl + v0 + v1 + v2;
    if (blockIdx.x == nb - 1 && tid == 0) off[n] = carry_s + wsum[15];
}

__global__ void fill_kernel(const int* __restrict__ dst, const int* __restrict__ src,
                            const int* __restrict__ off, int* __restrict__ fill,
                            int* __restrict__ edges, int E) {
    int e = blockIdx.x * 256 + threadIdx.x;
    if (e < E) {
        int d = dst[e];
        int p = atomicAdd(&fill[d], 1);
        edges[off[d] + p] = src[e];
    }
}

// ---------------- precompute: weight folds / bf16 conversion ----------------

__global__ void foldw_kernel(const float* __restrict__ wih, int ldw,
                             const float* __restrict__ w2,
                             float* __restrict__ out, int out_ld, int M) {
    int idx = blockIdx.x * 256 + threadIdx.x;
    if (idx >= M * 128) return;
    int o = idx >> 7, k = idx & 127;
    float s = 0.f;
    for (int m = 0; m < 128; ++m) s += wih[(size_t)o * ldw + m] * w2[m * 128 + k];
    out[(size_t)o * out_ld + k] = s;
}

__global__ void foldb_kernel(const float* __restrict__ wih, int ldw,
                             const float* __restrict__ b2,
                             float* __restrict__ out, int M) {
    int o = blockIdx.x * 256 + threadIdx.x;
    if (o >= M) return;
    float s = 0.f;
    for (int m = 0; m < 128; ++m) s += wih[(size_t)o * ldw + m] * b2[m];
    out[o] = s;
}

__global__ void cvtw_kernel(const float* __restrict__ w, u16* __restrict__ hi, int n) {
    int i = blockIdx.x * 256 + threadIdx.x;
    if (i < n) hi[i] = f2bf(w[i]);
}

__global__ void init_emb_kernel(const float* __restrict__ init, u16* __restrict__ hi, int n) {
    int i = blockIdx.x * 256 + threadIdx.x;
    if (i < n) hi[i] = f2bf(init[i & (DD - 1)] * INV_INIT_NORM);
}

// ---------------- bf16 MFMA GEMM (msg MLP + readout) ----------------

template<bool RELU, bool OUTBF16>
__global__ __launch_bounds__(256)
void mfma_gemm(const u16* __restrict__ Ahi, const u16* __restrict__ Whi,
               const float* __restrict__ bias, void* __restrict__ Yv, int N, int M) {
    __shared__ u16 Ah[4][128][8], Wh[4][128][8];

    const int tid = threadIdx.x;
    const int bn = blockIdx.x * 128, bm = blockIdx.y * 128;
    const int l = tid & 63, w = tid >> 6;
    const int wr = w >> 1, wc = w & 1;
    const int lr = l & 15, lg = l >> 4;

    f32x4 acc[4][4];
#pragma unroll
    for (int i = 0; i < 4; ++i)
#pragma unroll
        for (int j = 0; j < 4; ++j) acc[i][j] = (f32x4){0.f, 0.f, 0.f, 0.f};

    for (int k0 = 0; k0 < 128; k0 += 32) {
#pragma unroll
        for (int t = 0; t < 2; ++t) {
            const int slot = t * 256 + tid;
            const int row = slot >> 2, g = slot & 3, rs = row ^ (g << 1);
            const int gr = bn + row;
            us8 vh = (us8)0;
            if (gr < N) vh = *(const us8*)(Ahi + (size_t)gr * 128 + k0 + g * 8);
            *(us8*)&Ah[g][rs][0] = vh;
            *(us8*)&Wh[g][rs][0] = *(const us8*)(Whi + (size_t)(bm + row) * 128 + k0 + g * 8);
        }
        __syncthreads();

        frag_ab a_h[4], b_h[4];
#pragma unroll
        for (int i = 0; i < 4; ++i) {
            const int ra = wr * 64 + i * 16 + lr;
            a_h[i] = *(const frag_ab*)&Ah[lg][ra ^ (lg << 1)][0];
            const int rb = wc * 64 + i * 16 + lr;
            b_h[i] = *(const frag_ab*)&Wh[lg][rb ^ (lg << 1)][0];
        }
#pragma unroll
        for (int i = 0; i < 4; ++i)
#pragma unroll
            for (int j = 0; j < 4; ++j)
                acc[i][j] = __builtin_amdgcn_mfma_f32_16x16x32_bf16(a_h[i], b_h[j], acc[i][j], 0, 0, 0);
        __syncthreads();
    }

#pragma unroll
    for (int j = 0; j < 4; ++j) {
        const int gc = bm + wc * 64 + j * 16 + lr;
        const float bj = bias[gc];
#pragma unroll
        for (int i = 0; i < 4; ++i) {
            const int grb = bn + wr * 64 + i * 16 + lg * 4;
#pragma unroll
            for (int r = 0; r < 4; ++r) {
                const int gr = grb + r;
                if (gr < N) {
                    float o = acc[i][j][r] + bj;
                    if (RELU) o = fmaxf(o, 0.f);
                    if (OUTBF16) ((u16*)Yv)[(size_t)gr * M + gc] = f2bf(o);
                    else         ((float*)Yv)[(size_t)gr * M + gc] = o;
                }
            }
        }
    }
}

// ---------------- weight-stationary fused GRU ----------------
// XCD-aware block swizzle: x=b&7 (XCD), t=b>>3, cg=t&3, q=t>>2, rowblk=x+8q.
// The 4 col-group blocks of a rowblk land on the SAME XCD temporally adjacent,
// so X/Hin rows are fetched from HBM once per XCD and re-read from L2.
// Weight slice (96 gate rows x {r,z,n}) staged once in LDS (XOR swizzle);
// A-frags global->VGPR; gates in registers; ping-pong H (col-split can't be
// in-place).

template<bool XCAT>
__global__ __launch_bounds__(256)
void gru_wsta(const u16* __restrict__ X, const u16* __restrict__ X2,
              const u16* __restrict__ Hin, u16* __restrict__ Hout,
              const u16* __restrict__ Wih, const u16* __restrict__ Whh,
              const float* __restrict__ bih, const float* __restrict__ bmsg,
              const float* __restrict__ bhh, const int* __restrict__ ideg,
              int N, int nrb) {
    constexpr int KX = XCAT ? 256 : 128;
    constexpr int KX8 = KX / 8;
    __shared__ u16 Wih_s[96 * KX];    // XCAT 48KB else 24KB
    __shared__ u16 Whh_s[96 * 128];   // 24KB

    const int b = blockIdx.x;
    const int xcd = b & 7;
    const int t  = b >> 3;
    const int cg = t & 3;
    const int rowblk = xcd + 8 * (t >> 2);
    if (rowblk >= nrb) return;        // uniform early-out (before any barrier)

    const int tid = threadIdx.x;
    const int rw = rowblk * 128 + (tid >> 6) * 32;  // wave's 32 rows
    const int l = tid & 63;
    const int lr = l & 15, lg = l >> 4;

    // ---- stage weight slice into LDS (once) ----
    for (int s = tid; s < 96 * KX8; s += 256) {
        int rloc = s / KX8, k8 = s % KX8;
        int grow = (rloc >> 5) * 128 + cg * 32 + (rloc & 31);
        *(us8*)&Wih_s[rloc * KX + ((k8 ^ (rloc & 7)) << 3)] =
            *(const us8*)(Wih + (size_t)grow * KX + k8 * 8);
    }
    for (int s = tid; s < 96 * 16; s += 256) {
        int rloc = s >> 4, k8 = s & 15;
        int grow = (rloc >> 5) * 128 + cg * 32 + (rloc & 31);
        *(us8*)&Whh_s[rloc * 128 + ((k8 ^ (rloc & 7)) << 3)] =
            *(const us8*)(Whh + (size_t)grow * 128 + k8 * 8);
    }
    __syncthreads();
    if (rw >= N) return;   // no further barriers below

    const int ra0 = rw + lr, ra1 = rw + 16 + lr;

    f32x4 ai[6][2], ah[6][2];
#pragma unroll
    for (int j = 0; j < 6; ++j)
#pragma unroll
        for (int i = 0; i < 2; ++i) {
            ai[j][i] = (f32x4){0.f, 0.f, 0.f, 0.f};
            ah[j][i] = (f32x4){0.f, 0.f, 0.f, 0.f};
        }

    // ---- X @ Wih^T ----
#pragma unroll
    for (int ks = 0; ks < KX / 32; ++ks) {
        us8 v0 = (us8)0, v1 = (us8)0;
        if (XCAT && ks >= 4) {
            const int k = (ks - 4) * 32 + lg * 8;
            if (ra0 < N) v0 = *(const us8*)(X2 + (size_t)(ra0 ^ 1) * 128 + k);
            if (ra1 < N) v1 = *(const us8*)(X2 + (size_t)(ra1 ^ 1) * 128 + k);
        } else {
            const int k = ks * 32 + lg * 8;
            if (ra0 < N) v0 = *(const us8*)(X + (size_t)ra0 * 128 + k);
            if (ra1 < N) v1 = *(const us8*)(X + (size_t)ra1 * 128 + k);
        }
        frag_ab a0 = *(const frag_ab*)&v0, a1 = *(const frag_ab*)&v1;
        const int k8 = ks * 4 + lg;
#pragma unroll
        for (int j = 0; j < 6; ++j) {
            const int rloc = j * 16 + lr;
            frag_ab bfr = *(const frag_ab*)&Wih_s[rloc * KX + ((k8 ^ (rloc & 7)) << 3)];
            ai[j][0] = __builtin_amdgcn_mfma_f32_16x16x32_bf16(a0, bfr, ai[j][0], 0, 0, 0);
            ai[j][1] = __builtin_amdgcn_mfma_f32_16x16x32_bf16(a1, bfr, ai[j][1], 0, 0, 0);
        }
    }
    // ---- H @ Whh^T ----
#pragma unroll
    for (int ks = 0; ks < 4; ++ks) {
        const int k = ks * 32 + lg * 8;
        us8 v0 = (us8)0, v1 = (us8)0;
        if (ra0 < N) v0 = *(const us8*)(Hin + (size_t)ra0 * 128 + k);
        if (ra1 < N) v1 = *(const us8*)(Hin + (size_t)ra1 * 128 + k);
        frag_ab a0 = *(const frag_ab*)&v0, a1 = *(const frag_ab*)&v1;
        const int k8 = ks * 4 + lg;
#pragma unroll
        for (int j = 0; j < 6; ++j) {
            const int rloc = j * 16 + lr;
            frag_ab bfr = *(const frag_ab*)&Whh_s[rloc * 128 + ((k8 ^ (rloc & 7)) << 3)];
            ah[j][0] = __builtin_amdgcn_mfma_f32_16x16x32_bf16(a0, bfr, ah[j][0], 0, 0, 0);
            ah[j][1] = __builtin_amdgcn_mfma_f32_16x16x32_bf16(a1, bfr, ah[j][1], 0, 0, 0);
        }
    }

    // ---- gate combine + writeback (C/D layout: col=lane&15, row=(lane>>4)*4+r) ----
#pragma unroll
    for (int i = 0; i < 2; ++i) {
#pragma unroll
        for (int dh = 0; dh < 2; ++dh) {
            const int d = cg * 32 + dh * 16 + lr;
            const float bi_r = bih[d],       bh_r = bhh[d],       bm_r = bmsg[d];
            const float bi_z = bih[128 + d], bh_z = bhh[128 + d], bm_z = bmsg[128 + d];
            const float bi_n = bih[256 + d], bh_n = bhh[256 + d], bm_n = bmsg[256 + d];
#pragma unroll
            for (int r = 0; r < 4; ++r) {
                const int grow = rw + i * 16 + lg * 4 + r;
                if (grow < N) {
                    const bool hd = ideg[grow] > 0;
                    float rp = ai[0 + dh][i][r] + bi_r + (hd ? bm_r : 0.f) + ah[0 + dh][i][r] + bh_r;
                    float zp = ai[2 + dh][i][r] + bi_z + (hd ? bm_z : 0.f) + ah[2 + dh][i][r] + bh_z;
                    float np_i = ai[4 + dh][i][r] + bi_n + (hd ? bm_n : 0.f);
                    float np_h = ah[4 + dh][i][r] + bh_n;
                    float rg = sigmoidf_(rp);
                    float zg = sigmoidf_(zp);
                    float ng = tanhf(np_i + rg * np_h);
                    float hv = bf2f(Hin[(size_t)grow * 128 + d]);
                    Hout[(size_t)grow * 128 + d] = f2bf((1.f - zg) * ng + zg * hv);
                }
            }
        }
    }
}

// ---------------- CSR gather: out[row] = (1/max(deg,1)) * sum msg[src], bf16 ----------------

__global__ void gather_kernel(const u16* __restrict__ msg, const int* __restrict__ off,
                              const int* __restrict__ edges, u16* __restrict__ ohi, int n) {
    int row = blockIdx.x * 4 + (threadIdx.x >> 6);
    if (row >= n) return;
    int lane = threadIdx.x & 63;
    int s = off[row], e = off[row + 1];
    float ax = 0.f, ay = 0.f;
    for (int i = s; i < e; ++i) {
        const ushort2 v = ((const ushort2*)(msg + (size_t)edges[i] * DD))[lane];
        ax += bf2f(v.x); ay += bf2f(v.y);
    }
    float sc = 1.0f / (float)((e - s) > 0 ? (e - s) : 1);
    *(ushort2*)(ohi + (size_t)row * DD + 2 * lane) = make_ushort2(f2bf(ax * sc), f2bf(ay * sc));
}

// ---------------- readout ----------------

__global__ __launch_bounds__(256)
void logit2_kernel(const float* __restrict__ hidden, const float* __restrict__ w2,
                   const int* __restrict__ l_batch,
                   float* __restrict__ gsum, float* __restrict__ gcnt, int Lc) {
    __shared__ float s_sum[BB];
    __shared__ float s_cnt[BB];
    const int tid = threadIdx.x;
    if (tid < BB) { s_sum[tid] = 0.f; s_cnt[tid] = 0.f; }
    __syncthreads();
    const int lane = tid & 63;
    const int gw = blockIdx.x * 4 + (tid >> 6);
    const int nw = gridDim.x * 4;
    const float2 wv = ((const float2*)w2)[lane];
    for (int row = gw; row < Lc; row += nw) {
        float2 h = ((const float2*)(hidden + (size_t)row * DD))[lane];
        float dp = h.x * wv.x + h.y * wv.y;
#pragma unroll
        for (int off = 32; off > 0; off >>= 1) dp += __shfl_down(dp, off);
        if (lane == 0) {
            int b = l_batch[row];
            atomicAdd(&s_sum[b], dp);
            atomicAdd(&s_cnt[b], 1.0f);
        }
    }
    __syncthreads();
    if (tid < BB) {
        atomicAdd(&gsum[tid], s_sum[tid]);
        atomicAdd(&gcnt[tid], s_cnt[tid]);
    }
}

__global__ void final_kernel(const float* __restrict__ gsum, const float* __restrict__ gcnt,
                             const float* __restrict__ b2, float* __restrict__ out) {
    int b = threadIdx.x;
    if (b < BB) {
        float m = gsum[b] / fmaxf(gcnt[b], 1.0f) + b2[0];
        out[b] = 1.0f / (1.0f + expf(-m));
    }
}

// ---------------- host side ----------------

static inline size_t align_up_(size_t x) { return (x + 255) & ~(size_t)255; }

extern "C" void kernel_launch(void* const* d_in, const int* in_sizes, int n_in,
                              void* d_out, int out_size, void* d_ws, size_t ws_size,
                              hipStream_t stream) {
    const int*   l_ei     = (const int*)d_in[0];
    const int*   c_ei     = (const int*)d_in[1];
    const int*   l_batch  = (const int*)d_in[2];
    const float* l_init   = (const float*)d_in[3];
    const float* c_init   = (const float*)d_in[4];
    const float* l2c_w1   = (const float*)d_in[5];
    const float* l2c_b1   = (const float*)d_in[6];
    const float* l2c_w2   = (const float*)d_in[7];
    const float* l2c_b2   = (const float*)d_in[8];
    const float* c2l_w1   = (const float*)d_in[9];
    const float* c2l_b1   = (const float*)d_in[10];
    const float* c2l_w2   = (const float*)d_in[11];
    const float* c2l_b2   = (const float*)d_in[12];
    const float* cgru_wih = (const float*)d_in[13];
    const float* cgru_whh = (const float*)d_in[14];
    const float* cgru_bih = (const float*)d_in[15];
    const float* cgru_bhh = (const float*)d_in[16];
    const float* lgru_wih = (const float*)d_in[17];
    const float* lgru_whh = (const float*)d_in[18];
    const float* lgru_bih = (const float*)d_in[19];
    const float* lgru_bhh = (const float*)d_in[20];
    const float* ro_w1    = (const float*)d_in[21];
    const float* ro_b1    = (const float*)d_in[22];
    const float* ro_w2    = (const float*)d_in[23];
    const float* ro_b2    = (const float*)d_in[24];

    const int E  = in_sizes[0];
    const int Lc = in_sizes[2];
    const int C  = CC;
    const int NMAX = (C > Lc ? C : Lc);

    // ---- workspace carve (~170 MB) ----
    char* p = (char*)d_ws;
    auto carve = [&](size_t bytes) { void* r = (void*)p; p += align_up_(bytes); return r; };
    u16*   l_embA  = (u16*)carve((size_t)Lc * DD * 2);
    u16*   l_embB  = (u16*)carve((size_t)Lc * DD * 2);
    u16*   c_embA  = (u16*)carve((size_t)C * DD * 2);
    u16*   c_embB  = (u16*)carve((size_t)C * DD * 2);
    u16*   hagg    = (u16*)carve((size_t)NMAX * DD * 2);
    u16*   msg     = (u16*)carve((size_t)NMAX * DD * 2);
    float* hiddenf = (float*)carve((size_t)Lc * DD * 4);
    int*   ideg_l  = (int*)carve((size_t)Lc * 4);
    int*   ideg_c  = (int*)carve((size_t)C * 4);
    int*   l_off   = (int*)carve((size_t)(Lc + 1) * 4);
    int*   c_off   = (int*)carve((size_t)(C + 1) * 4);
    int*   l_edges = (int*)carve((size_t)E * 4);
    int*   c_edges = (int*)carve((size_t)E * 4);
    int*   fillc   = (int*)carve((size_t)NMAX * 4);
    int*   bsums   = (int*)carve(64 * 4);
    float* Wf_c    = (float*)carve((size_t)384 * 128 * 4);
    float* Wcat    = (float*)carve((size_t)384 * 256 * 4);
    float* bmsg_c  = (float*)carve(384 * 4);
    float* bmsg_l  = (float*)carve(384 * 4);
    u16* w_l2c1 = (u16*)carve(128 * 128 * 2);
    u16* w_c2l1 = (u16*)carve(128 * 128 * 2);
    u16* w_ro1  = (u16*)carve(128 * 128 * 2);
    u16* w_gic  = (u16*)carve(384 * 128 * 2);
    u16* w_ghc  = (u16*)carve(384 * 128 * 2);
    u16* w_ghl  = (u16*)carve(384 * 128 * 2);
    u16* w_gil  = (u16*)carve(384 * 256 * 2);
    float* g_sum = (float*)carve(BB * 4);
    float* g_cnt = (float*)carve(BB * 4);
    (void)ws_size; (void)n_in; (void)out_size;

    // ---- degrees + CSR build ----
    hipMemsetAsync(ideg_l, 0, (size_t)Lc * 4, stream);
    hipMemsetAsync(ideg_c, 0, (size_t)C * 4, stream);
    ideg_kernel<<<(E + 255) / 256, 256, 0, stream>>>(l_ei, c_ei, ideg_l, ideg_c, E);
    {
        int nbc = (C + 4095) / 4096, nbl = (Lc + 4095) / 4096;
        bsum_kernel<<<nbc, 1024, 0, stream>>>(ideg_c, bsums, C);
        scan2_kernel<<<nbc, 1024, 0, stream>>>(ideg_c, bsums, c_off, C, nbc);
        bsum_kernel<<<nbl, 1024, 0, stream>>>(ideg_l, bsums, Lc);
        scan2_kernel<<<nbl, 1024, 0, stream>>>(ideg_l, bsums, l_off, Lc, nbl);
    }
    hipMemsetAsync(fillc, 0, (size_t)C * 4, stream);
    fill_kernel<<<(E + 255) / 256, 256, 0, stream>>>(c_ei, l_ei, c_off, fillc, c_edges, E);
    hipMemsetAsync(fillc, 0, (size_t)Lc * 4, stream);
    fill_kernel<<<(E + 255) / 256, 256, 0, stream>>>(l_ei, c_ei, l_off, fillc, l_edges, E);

    // ---- weight folds: Wf_c = cgru_wih @ l2c_w2 ; Wcat = [lgru_wihA @ c2l_w2 | lgru_wihB] ----
    foldw_kernel<<<(384 * 128 + 255) / 256, 256, 0, stream>>>(cgru_wih, 128, l2c_w2, Wf_c, 128, 384);
    foldb_kernel<<<2, 256, 0, stream>>>(cgru_wih, 128, l2c_b2, bmsg_c, 384);
    hipMemcpyAsync(Wcat, lgru_wih, (size_t)384 * 256 * 4, hipMemcpyDeviceToDevice, stream);
    foldw_kernel<<<(384 * 128 + 255) / 256, 256, 0, stream>>>(lgru_wih, 256, c2l_w2, Wcat, 256, 384);
    foldb_kernel<<<2, 256, 0, stream>>>(lgru_wih, 256, c2l_b2, bmsg_l, 384);

    // ---- bf16 weight conversion ----
    cvtw_kernel<<<(128 * 128 + 255) / 256, 256, 0, stream>>>(l2c_w1, w_l2c1, 128 * 128);
    cvtw_kernel<<<(128 * 128 + 255) / 256, 256, 0, stream>>>(c2l_w1, w_c2l1, 128 * 128);
    cvtw_kernel<<<(128 * 128 + 255) / 256, 256, 0, stream>>>(ro_w1, w_ro1, 128 * 128);
    cvtw_kernel<<<(384 * 128 + 255) / 256, 256, 0, stream>>>(Wf_c, w_gic, 384 * 128);
    cvtw_kernel<<<(384 * 128 + 255) / 256, 256, 0, stream>>>(cgru_whh, w_ghc, 384 * 128);
    cvtw_kernel<<<(384 * 128 + 255) / 256, 256, 0, stream>>>(lgru_whh, w_ghl, 384 * 128);
    cvtw_kernel<<<(384 * 256 + 255) / 256, 256, 0, stream>>>(Wcat, w_gil, 384 * 256);

    // ---- init embeddings ----
    init_emb_kernel<<<((size_t)Lc * DD + 255) / 256, 256, 0, stream>>>(l_init, l_embA, Lc * DD);
    init_emb_kernel<<<((size_t)C * DD + 255) / 256, 256, 0, stream>>>(c_init, c_embA, C * DD);

    u16* l_cur = l_embA; u16* l_nxt = l_embB;
    u16* c_cur = c_embA; u16* c_nxt = c_embB;

    const int nrb_c = (C + 127) / 128,  nrbp_c = ((nrb_c + 7) / 8) * 8;
    const int nrb_l = (Lc + 127) / 128, nrbp_l = ((nrb_l + 7) / 8) * 8;

    for (int it = 0; it < N_ITER; ++it) {
        // ---- literal -> clause ----
        mfma_gemm<true, true><<<dim3((Lc + 127) / 128, 1), 256, 0, stream>>>(
            l_cur, w_l2c1, l2c_b1, msg, Lc, 128);
        gather_kernel<<<(C + 3) / 4, 256, 0, stream>>>(msg, c_off, c_edges, hagg, C);
        gru_wsta<false><<<nrbp_c * 4, 256, 0, stream>>>(
            hagg, nullptr, c_cur, c_nxt, w_gic, w_ghc, cgru_bih, bmsg_c, cgru_bhh,
            ideg_c, C, nrb_c);
        { u16* t = c_cur; c_cur = c_nxt; c_nxt = t; }

        // ---- clause -> literal ----
        mfma_gemm<true, true><<<dim3((C + 127) / 128, 1), 256, 0, stream>>>(
            c_cur, w_c2l1, c2l_b1, msg, C, 128);
        gather_kernel<<<(Lc + 3) / 4, 256, 0, stream>>>(msg, l_off, l_edges, hagg, Lc);
        gru_wsta<true><<<nrbp_l * 4, 256, 0, stream>>>(
            hagg, l_cur, l_cur, l_nxt, w_gil, w_ghl, lgru_bih, bmsg_l, lgru_bhh,
            ideg_l, Lc, nrb_l);
        { u16* t = l_cur; l_cur = l_nxt; l_nxt = t; }
    }

    // ---- readout ----
    mfma_gemm<true, false><<<dim3((Lc + 127) / 128, 1), 256, 0, stream>>>(
        l_cur, w_ro1, ro_b1, hiddenf, Lc, 128);
    hipMemsetAsync(g_sum, 0, BB * 4, stream);
    hipMemsetAsync(g_cnt, 0, BB * 4, stream);
    logit2_kernel<<<1024, 256, 0, stream>>>(hiddenf, ro_w2, l_batch, g_sum, g_cnt, Lc);
    final_kernel<<<1, 64, 0, stream>>>(g_sum, g_cnt, ro_b2, (float*)d_out);
}

// Round 9
// 1101.710 us; speedup vs baseline: 6.0566x; 1.1628x over previous
//
#include <hip/hip_runtime.h>
#include <hip/hip_bf16.h>

#define DD 128
#define CC 100000
#define BB 32
#define N_ITER 4
#define INV_INIT_NORM 0.125f   // 1/(sqrt(128)/sqrt(2)) = 1/8

typedef unsigned short u16;
typedef __attribute__((ext_vector_type(8))) short  frag_ab;   // 8 bf16 (4 VGPRs)
typedef __attribute__((ext_vector_type(4))) float  f32x4;
typedef __attribute__((ext_vector_type(8))) unsigned short us8;

__device__ __forceinline__ u16 f2bf(float f) {
    union { float f; unsigned u; } v; v.f = f;
    unsigned r = v.u + 0x7fff + ((v.u >> 16) & 1);   // RNE
    return (u16)(r >> 16);
}
__device__ __forceinline__ float bf2f(u16 h) {
    union { unsigned u; float f; } v; v.u = ((unsigned)h) << 16;
    return v.f;
}
// fast HW transcendentals: v_exp_f32 + v_rcp_f32 (exact at +-inf, ~ulp-level err)
__device__ __forceinline__ float fsigmoid_(float x) {
    return __builtin_amdgcn_rcpf(1.0f + __expf(-x));
}
__device__ __forceinline__ float ftanh_(float x) {
    return 1.0f - 2.0f * __builtin_amdgcn_rcpf(1.0f + __expf(2.0f * x));
}

// ---------------- precompute: degrees / hierarchical scan / CSR fill ----------------

__global__ void ideg_kernel(const int* __restrict__ li, const int* __restrict__ ci,
                            int* __restrict__ idl, int* __restrict__ idc, int E) {
    int e = blockIdx.x * 256 + threadIdx.x;
    if (e < E) {
        atomicAdd(&idl[li[e]], 1);
        atomicAdd(&idc[ci[e]], 1);
    }
}

__global__ __launch_bounds__(1024)
void bsum_kernel(const int* __restrict__ deg, int* __restrict__ bsum, int n) {
    __shared__ int wred[16];
    const int tid = threadIdx.x, lane = tid & 63, wid = tid >> 6;
    int idx = blockIdx.x * 4096 + tid * 4;
    int s = 0;
#pragma unroll
    for (int j = 0; j < 4; ++j) if (idx + j < n) s += deg[idx + j];
#pragma unroll
    for (int o = 32; o > 0; o >>= 1) s += __shfl_down(s, o);
    if (lane == 0) wred[wid] = s;
    __syncthreads();
    if (tid == 0) {
        int t = 0;
#pragma unroll
        for (int k = 0; k < 16; ++k) t += wred[k];
        bsum[blockIdx.x] = t;
    }
}

__global__ __launch_bounds__(1024)
void scan2_kernel(const int* __restrict__ deg, const int* __restrict__ bsum,
                  int* __restrict__ off, int n, int nb) {
    __shared__ int wsum[16];
    __shared__ int carry_s;
    const int tid = threadIdx.x, lane = tid & 63, wid = tid >> 6;
    if (tid == 0) {
        int c = 0;
        for (int b = 0; b < blockIdx.x; ++b) c += bsum[b];
        carry_s = c;
    }
    int idx = blockIdx.x * 4096 + tid * 4;
    int v0 = idx     < n ? deg[idx]     : 0;
    int v1 = idx + 1 < n ? deg[idx + 1] : 0;
    int v2 = idx + 2 < n ? deg[idx + 2] : 0;
    int v3 = idx + 3 < n ? deg[idx + 3] : 0;
    int t = v0 + v1 + v2 + v3;
    int s = t;
#pragma unroll
    for (int o = 1; o < 64; o <<= 1) { int u = __shfl_up(s, o); if (lane >= o) s += u; }
    if (lane == 63) wsum[wid] = s;
    __syncthreads();
    if (wid == 0 && lane < 16) {
        int x = wsum[lane];
#pragma unroll
        for (int o = 1; o < 16; o <<= 1) { int u = __shfl_up(x, o); if (lane >= o) x += u; }
        wsum[lane] = x;
    }
    __syncthreads();
    int woff = (wid > 0) ? wsum[wid - 1] : 0;
    int excl = carry_s + woff + s - t;
    if (idx     < n) off[idx]     = excl;
    if (idx + 1 < n) off[idx + 1] = excl + v0;
    if (idx + 2 < n) off[idx + 2] = excl + v0 + v1;
    if (idx + 3 < n) off[idx + 3] = excl + v0 + v1 + v2;
    if (blockIdx.x == nb - 1 && tid == 0) off[n] = carry_s + wsum[15];
}

__global__ void fill_kernel(const int* __restrict__ dst, const int* __restrict__ src,
                            const int* __restrict__ off, int* __restrict__ fill,
                            int* __restrict__ edges, int E) {
    int e = blockIdx.x * 256 + threadIdx.x;
    if (e < E) {
        int d = dst[e];
        int p = atomicAdd(&fill[d], 1);
        edges[off[d] + p] = src[e];
    }
}

// ---------------- precompute: weight folds / bf16 conversion ----------------

__global__ void foldw_kernel(const float* __restrict__ wih, int ldw,
                             const float* __restrict__ w2,
                             float* __restrict__ out, int out_ld, int M) {
    int idx = blockIdx.x * 256 + threadIdx.x;
    if (idx >= M * 128) return;
    int o = idx >> 7, k = idx & 127;
    float s = 0.f;
    for (int m = 0; m < 128; ++m) s += wih[(size_t)o * ldw + m] * w2[m * 128 + k];
    out[(size_t)o * out_ld + k] = s;
}

__global__ void foldb_kernel(const float* __restrict__ wih, int ldw,
                             const float* __restrict__ b2,
                             float* __restrict__ out, int M) {
    int o = blockIdx.x * 256 + threadIdx.x;
    if (o >= M) return;
    float s = 0.f;
    for (int m = 0; m < 128; ++m) s += wih[(size_t)o * ldw + m] * b2[m];
    out[o] = s;
}

__global__ void cvtw_kernel(const float* __restrict__ w, u16* __restrict__ hi, int n) {
    int i = blockIdx.x * 256 + threadIdx.x;
    if (i < n) hi[i] = f2bf(w[i]);
}

__global__ void init_emb_kernel(const float* __restrict__ init, u16* __restrict__ hi, int n) {
    int i = blockIdx.x * 256 + threadIdx.x;
    if (i < n) hi[i] = f2bf(init[i & (DD - 1)] * INV_INIT_NORM);
}

// ---------------- bf16 MFMA GEMM (msg MLP + readout) ----------------

template<bool RELU, bool OUTBF16>
__global__ __launch_bounds__(256)
void mfma_gemm(const u16* __restrict__ Ahi, const u16* __restrict__ Whi,
               const float* __restrict__ bias, void* __restrict__ Yv, int N, int M) {
    __shared__ u16 Ah[4][128][8], Wh[4][128][8];

    const int tid = threadIdx.x;
    const int bn = blockIdx.x * 128, bm = blockIdx.y * 128;
    const int l = tid & 63, w = tid >> 6;
    const int wr = w >> 1, wc = w & 1;
    const int lr = l & 15, lg = l >> 4;

    f32x4 acc[4][4];
#pragma unroll
    for (int i = 0; i < 4; ++i)
#pragma unroll
        for (int j = 0; j < 4; ++j) acc[i][j] = (f32x4){0.f, 0.f, 0.f, 0.f};

    for (int k0 = 0; k0 < 128; k0 += 32) {
#pragma unroll
        for (int t = 0; t < 2; ++t) {
            const int slot = t * 256 + tid;
            const int row = slot >> 2, g = slot & 3, rs = row ^ (g << 1);
            const int gr = bn + row;
            us8 vh = (us8)0;
            if (gr < N) vh = *(const us8*)(Ahi + (size_t)gr * 128 + k0 + g * 8);
            *(us8*)&Ah[g][rs][0] = vh;
            *(us8*)&Wh[g][rs][0] = *(const us8*)(Whi + (size_t)(bm + row) * 128 + k0 + g * 8);
        }
        __syncthreads();

        frag_ab a_h[4], b_h[4];
#pragma unroll
        for (int i = 0; i < 4; ++i) {
            const int ra = wr * 64 + i * 16 + lr;
            a_h[i] = *(const frag_ab*)&Ah[lg][ra ^ (lg << 1)][0];
            const int rb = wc * 64 + i * 16 + lr;
            b_h[i] = *(const frag_ab*)&Wh[lg][rb ^ (lg << 1)][0];
        }
#pragma unroll
        for (int i = 0; i < 4; ++i)
#pragma unroll
            for (int j = 0; j < 4; ++j)
                acc[i][j] = __builtin_amdgcn_mfma_f32_16x16x32_bf16(a_h[i], b_h[j], acc[i][j], 0, 0, 0);
        __syncthreads();
    }

#pragma unroll
    for (int j = 0; j < 4; ++j) {
        const int gc = bm + wc * 64 + j * 16 + lr;
        const float bj = bias[gc];
#pragma unroll
        for (int i = 0; i < 4; ++i) {
            const int grb = bn + wr * 64 + i * 16 + lg * 4;
#pragma unroll
            for (int r = 0; r < 4; ++r) {
                const int gr = grb + r;
                if (gr < N) {
                    float o = acc[i][j][r] + bj;
                    if (RELU) o = fmaxf(o, 0.f);
                    if (OUTBF16) ((u16*)Yv)[(size_t)gr * M + gc] = f2bf(o);
                    else         ((float*)Yv)[(size_t)gr * M + gc] = o;
                }
            }
        }
    }
}

// ---------------- weight-stationary fused GRU ----------------
// 512 threads / 8 waves; each wave owns 32 rows -> 256 rows per block.
// XCD-aware swizzle: x=b&7, t=b>>3, cg=t&3, rowblk=x+8*(t>>2) -- the 4
// col-group blocks of a rowblk land on the same XCD temporally adjacent
// (X/Hin rows HBM-fetched once, L2 re-read; verified R8: FETCH 102->26MB).
// Weight slice (96 gate rows {r,z,n} x 32 dims) staged once in LDS (XOR
// swizzle); A-frags global->VGPR; gates in registers with HW exp/rcp;
// ping-pong H (col-split can't be in-place).

template<bool XCAT>
__global__ __launch_bounds__(512)
void gru_wsta(const u16* __restrict__ X, const u16* __restrict__ X2,
              const u16* __restrict__ Hin, u16* __restrict__ Hout,
              const u16* __restrict__ Wih, const u16* __restrict__ Whh,
              const float* __restrict__ bih, const float* __restrict__ bmsg,
              const float* __restrict__ bhh, const int* __restrict__ ideg,
              int N, int nrb) {
    constexpr int KX = XCAT ? 256 : 128;
    constexpr int KX8 = KX / 8;
    __shared__ u16 Wih_s[96 * KX];    // XCAT 48KB else 24KB
    __shared__ u16 Whh_s[96 * 128];   // 24KB

    const int b = blockIdx.x;
    const int xcd = b & 7;
    const int t  = b >> 3;
    const int cg = t & 3;
    const int rowblk = xcd + 8 * (t >> 2);
    if (rowblk >= nrb) return;        // uniform early-out (before any barrier)

    const int tid = threadIdx.x;
    const int rw = rowblk * 256 + (tid >> 6) * 32;  // wave's 32 rows
    const int l = tid & 63;
    const int lr = l & 15, lg = l >> 4;

    // ---- stage weight slice into LDS (once per 256 rows) ----
    for (int s = tid; s < 96 * KX8; s += 512) {
        int rloc = s / KX8, k8 = s % KX8;
        int grow = (rloc >> 5) * 128 + cg * 32 + (rloc & 31);
        *(us8*)&Wih_s[rloc * KX + ((k8 ^ (rloc & 7)) << 3)] =
            *(const us8*)(Wih + (size_t)grow * KX + k8 * 8);
    }
    for (int s = tid; s < 96 * 16; s += 512) {
        int rloc = s >> 4, k8 = s & 15;
        int grow = (rloc >> 5) * 128 + cg * 32 + (rloc & 31);
        *(us8*)&Whh_s[rloc * 128 + ((k8 ^ (rloc & 7)) << 3)] =
            *(const us8*)(Whh + (size_t)grow * 128 + k8 * 8);
    }
    __syncthreads();
    if (rw >= N) return;   // no further barriers below

    const int ra0 = rw + lr, ra1 = rw + 16 + lr;

    f32x4 ai[6][2], ah[6][2];
#pragma unroll
    for (int j = 0; j < 6; ++j)
#pragma unroll
        for (int i = 0; i < 2; ++i) {
            ai[j][i] = (f32x4){0.f, 0.f, 0.f, 0.f};
            ah[j][i] = (f32x4){0.f, 0.f, 0.f, 0.f};
        }

    // ---- X @ Wih^T ----
#pragma unroll
    for (int ks = 0; ks < KX / 32; ++ks) {
        us8 v0 = (us8)0, v1 = (us8)0;
        if (XCAT && ks >= 4) {
            const int k = (ks - 4) * 32 + lg * 8;
            if (ra0 < N) v0 = *(const us8*)(X2 + (size_t)(ra0 ^ 1) * 128 + k);
            if (ra1 < N) v1 = *(const us8*)(X2 + (size_t)(ra1 ^ 1) * 128 + k);
        } else {
            const int k = ks * 32 + lg * 8;
            if (ra0 < N) v0 = *(const us8*)(X + (size_t)ra0 * 128 + k);
            if (ra1 < N) v1 = *(const us8*)(X + (size_t)ra1 * 128 + k);
        }
        frag_ab a0 = *(const frag_ab*)&v0, a1 = *(const frag_ab*)&v1;
        const int k8 = ks * 4 + lg;
#pragma unroll
        for (int j = 0; j < 6; ++j) {
            const int rloc = j * 16 + lr;
            frag_ab bfr = *(const frag_ab*)&Wih_s[rloc * KX + ((k8 ^ (rloc & 7)) << 3)];
            ai[j][0] = __builtin_amdgcn_mfma_f32_16x16x32_bf16(a0, bfr, ai[j][0], 0, 0, 0);
            ai[j][1] = __builtin_amdgcn_mfma_f32_16x16x32_bf16(a1, bfr, ai[j][1], 0, 0, 0);
        }
    }
    // ---- H @ Whh^T ----
#pragma unroll
    for (int ks = 0; ks < 4; ++ks) {
        const int k = ks * 32 + lg * 8;
        us8 v0 = (us8)0, v1 = (us8)0;
        if (ra0 < N) v0 = *(const us8*)(Hin + (size_t)ra0 * 128 + k);
        if (ra1 < N) v1 = *(const us8*)(Hin + (size_t)ra1 * 128 + k);
        frag_ab a0 = *(const frag_ab*)&v0, a1 = *(const frag_ab*)&v1;
        const int k8 = ks * 4 + lg;
#pragma unroll
        for (int j = 0; j < 6; ++j) {
            const int rloc = j * 16 + lr;
            frag_ab bfr = *(const frag_ab*)&Whh_s[rloc * 128 + ((k8 ^ (rloc & 7)) << 3)];
            ah[j][0] = __builtin_amdgcn_mfma_f32_16x16x32_bf16(a0, bfr, ah[j][0], 0, 0, 0);
            ah[j][1] = __builtin_amdgcn_mfma_f32_16x16x32_bf16(a1, bfr, ah[j][1], 0, 0, 0);
        }
    }

    // ---- gate combine + writeback (C/D layout: col=lane&15, row=(lane>>4)*4+r) ----
#pragma unroll
    for (int i = 0; i < 2; ++i) {
#pragma unroll
        for (int dh = 0; dh < 2; ++dh) {
            const int d = cg * 32 + dh * 16 + lr;
            const float bi_r = bih[d],       bh_r = bhh[d],       bm_r = bmsg[d];
            const float bi_z = bih[128 + d], bh_z = bhh[128 + d], bm_z = bmsg[128 + d];
            const float bi_n = bih[256 + d], bh_n = bhh[256 + d], bm_n = bmsg[256 + d];
#pragma unroll
            for (int r = 0; r < 4; ++r) {
                const int grow = rw + i * 16 + lg * 4 + r;
                if (grow < N) {
                    const bool hd = ideg[grow] > 0;
                    float rp = ai[0 + dh][i][r] + bi_r + (hd ? bm_r : 0.f) + ah[0 + dh][i][r] + bh_r;
                    float zp = ai[2 + dh][i][r] + bi_z + (hd ? bm_z : 0.f) + ah[2 + dh][i][r] + bh_z;
                    float np_i = ai[4 + dh][i][r] + bi_n + (hd ? bm_n : 0.f);
                    float np_h = ah[4 + dh][i][r] + bh_n;
                    float rg = fsigmoid_(rp);
                    float zg = fsigmoid_(zp);
                    float ng = ftanh_(np_i + rg * np_h);
                    float hv = bf2f(Hin[(size_t)grow * 128 + d]);
                    Hout[(size_t)grow * 128 + d] = f2bf((1.f - zg) * ng + zg * hv);
                }
            }
        }
    }
}

// ---------------- CSR gather: out[row] = (1/max(deg,1)) * sum msg[src], bf16 ----------------

__global__ void gather_kernel(const u16* __restrict__ msg, const int* __restrict__ off,
                              const int* __restrict__ edges, u16* __restrict__ ohi, int n) {
    int row = blockIdx.x * 4 + (threadIdx.x >> 6);
    if (row >= n) return;
    int lane = threadIdx.x & 63;
    int s = off[row], e = off[row + 1];
    float ax = 0.f, ay = 0.f;
    for (int i = s; i < e; ++i) {
        const ushort2 v = ((const ushort2*)(msg + (size_t)edges[i] * DD))[lane];
        ax += bf2f(v.x); ay += bf2f(v.y);
    }
    float sc = __builtin_amdgcn_rcpf((float)((e - s) > 0 ? (e - s) : 1));
    *(ushort2*)(ohi + (size_t)row * DD + 2 * lane) = make_ushort2(f2bf(ax * sc), f2bf(ay * sc));
}

// ---------------- readout ----------------

__global__ __launch_bounds__(256)
void logit2_kernel(const float* __restrict__ hidden, const float* __restrict__ w2,
                   const int* __restrict__ l_batch,
                   float* __restrict__ gsum, float* __restrict__ gcnt, int Lc) {
    __shared__ float s_sum[BB];
    __shared__ float s_cnt[BB];
    const int tid = threadIdx.x;
    if (tid < BB) { s_sum[tid] = 0.f; s_cnt[tid] = 0.f; }
    __syncthreads();
    const int lane = tid & 63;
    const int gw = blockIdx.x * 4 + (tid >> 6);
    const int nw = gridDim.x * 4;
    const float2 wv = ((const float2*)w2)[lane];
    for (int row = gw; row < Lc; row += nw) {
        float2 h = ((const float2*)(hidden + (size_t)row * DD))[lane];
        float dp = h.x * wv.x + h.y * wv.y;
#pragma unroll
        for (int off = 32; off > 0; off >>= 1) dp += __shfl_down(dp, off);
        if (lane == 0) {
            int b = l_batch[row];
            atomicAdd(&s_sum[b], dp);
            atomicAdd(&s_cnt[b], 1.0f);
        }
    }
    __syncthreads();
    if (tid < BB) {
        atomicAdd(&gsum[tid], s_sum[tid]);
        atomicAdd(&gcnt[tid], s_cnt[tid]);
    }
}

__global__ void final_kernel(const float* __restrict__ gsum, const float* __restrict__ gcnt,
                             const float* __restrict__ b2, float* __restrict__ out) {
    int b = threadIdx.x;
    if (b < BB) {
        float m = gsum[b] / fmaxf(gcnt[b], 1.0f) + b2[0];
        out[b] = 1.0f / (1.0f + expf(-m));
    }
}

// ---------------- host side ----------------

static inline size_t align_up_(size_t x) { return (x + 255) & ~(size_t)255; }

extern "C" void kernel_launch(void* const* d_in, const int* in_sizes, int n_in,
                              void* d_out, int out_size, void* d_ws, size_t ws_size,
                              hipStream_t stream) {
    const int*   l_ei     = (const int*)d_in[0];
    const int*   c_ei     = (const int*)d_in[1];
    const int*   l_batch  = (const int*)d_in[2];
    const float* l_init   = (const float*)d_in[3];
    const float* c_init   = (const float*)d_in[4];
    const float* l2c_w1   = (const float*)d_in[5];
    const float* l2c_b1   = (const float*)d_in[6];
    const float* l2c_w2   = (const float*)d_in[7];
    const float* l2c_b2   = (const float*)d_in[8];
    const float* c2l_w1   = (const float*)d_in[9];
    const float* c2l_b1   = (const float*)d_in[10];
    const float* c2l_w2   = (const float*)d_in[11];
    const float* c2l_b2   = (const float*)d_in[12];
    const float* cgru_wih = (const float*)d_in[13];
    const float* cgru_whh = (const float*)d_in[14];
    const float* cgru_bih = (const float*)d_in[15];
    const float* cgru_bhh = (const float*)d_in[16];
    const float* lgru_wih = (const float*)d_in[17];
    const float* lgru_whh = (const float*)d_in[18];
    const float* lgru_bih = (const float*)d_in[19];
    const float* lgru_bhh = (const float*)d_in[20];
    const float* ro_w1    = (const float*)d_in[21];
    const float* ro_b1    = (const float*)d_in[22];
    const float* ro_w2    = (const float*)d_in[23];
    const float* ro_b2    = (const float*)d_in[24];

    const int E  = in_sizes[0];
    const int Lc = in_sizes[2];
    const int C  = CC;
    const int NMAX = (C > Lc ? C : Lc);

    // ---- workspace carve (~170 MB) ----
    char* p = (char*)d_ws;
    auto carve = [&](size_t bytes) { void* r = (void*)p; p += align_up_(bytes); return r; };
    u16*   l_embA  = (u16*)carve((size_t)Lc * DD * 2);
    u16*   l_embB  = (u16*)carve((size_t)Lc * DD * 2);
    u16*   c_embA  = (u16*)carve((size_t)C * DD * 2);
    u16*   c_embB  = (u16*)carve((size_t)C * DD * 2);
    u16*   hagg    = (u16*)carve((size_t)NMAX * DD * 2);
    u16*   msg     = (u16*)carve((size_t)NMAX * DD * 2);
    float* hiddenf = (float*)carve((size_t)Lc * DD * 4);
    int*   ideg_l  = (int*)carve((size_t)Lc * 4);
    int*   ideg_c  = (int*)carve((size_t)C * 4);
    int*   l_off   = (int*)carve((size_t)(Lc + 1) * 4);
    int*   c_off   = (int*)carve((size_t)(C + 1) * 4);
    int*   l_edges = (int*)carve((size_t)E * 4);
    int*   c_edges = (int*)carve((size_t)E * 4);
    int*   fillc   = (int*)carve((size_t)NMAX * 4);
    int*   bsums   = (int*)carve(64 * 4);
    float* Wf_c    = (float*)carve((size_t)384 * 128 * 4);
    float* Wcat    = (float*)carve((size_t)384 * 256 * 4);
    float* bmsg_c  = (float*)carve(384 * 4);
    float* bmsg_l  = (float*)carve(384 * 4);
    u16* w_l2c1 = (u16*)carve(128 * 128 * 2);
    u16* w_c2l1 = (u16*)carve(128 * 128 * 2);
    u16* w_ro1  = (u16*)carve(128 * 128 * 2);
    u16* w_gic  = (u16*)carve(384 * 128 * 2);
    u16* w_ghc  = (u16*)carve(384 * 128 * 2);
    u16* w_ghl  = (u16*)carve(384 * 128 * 2);
    u16* w_gil  = (u16*)carve(384 * 256 * 2);
    float* g_sum = (float*)carve(BB * 4);
    float* g_cnt = (float*)carve(BB * 4);
    (void)ws_size; (void)n_in; (void)out_size;

    // ---- degrees + CSR build ----
    hipMemsetAsync(ideg_l, 0, (size_t)Lc * 4, stream);
    hipMemsetAsync(ideg_c, 0, (size_t)C * 4, stream);
    ideg_kernel<<<(E + 255) / 256, 256, 0, stream>>>(l_ei, c_ei, ideg_l, ideg_c, E);
    {
        int nbc = (C + 4095) / 4096, nbl = (Lc + 4095) / 4096;
        bsum_kernel<<<nbc, 1024, 0, stream>>>(ideg_c, bsums, C);
        scan2_kernel<<<nbc, 1024, 0, stream>>>(ideg_c, bsums, c_off, C, nbc);
        bsum_kernel<<<nbl, 1024, 0, stream>>>(ideg_l, bsums, Lc);
        scan2_kernel<<<nbl, 1024, 0, stream>>>(ideg_l, bsums, l_off, Lc, nbl);
    }
    hipMemsetAsync(fillc, 0, (size_t)C * 4, stream);
    fill_kernel<<<(E + 255) / 256, 256, 0, stream>>>(c_ei, l_ei, c_off, fillc, c_edges, E);
    hipMemsetAsync(fillc, 0, (size_t)Lc * 4, stream);
    fill_kernel<<<(E + 255) / 256, 256, 0, stream>>>(l_ei, c_ei, l_off, fillc, l_edges, E);

    // ---- weight folds: Wf_c = cgru_wih @ l2c_w2 ; Wcat = [lgru_wihA @ c2l_w2 | lgru_wihB] ----
    foldw_kernel<<<(384 * 128 + 255) / 256, 256, 0, stream>>>(cgru_wih, 128, l2c_w2, Wf_c, 128, 384);
    foldb_kernel<<<2, 256, 0, stream>>>(cgru_wih, 128, l2c_b2, bmsg_c, 384);
    hipMemcpyAsync(Wcat, lgru_wih, (size_t)384 * 256 * 4, hipMemcpyDeviceToDevice, stream);
    foldw_kernel<<<(384 * 128 + 255) / 256, 256, 0, stream>>>(lgru_wih, 256, c2l_w2, Wcat, 256, 384);
    foldb_kernel<<<2, 256, 0, stream>>>(lgru_wih, 256, c2l_b2, bmsg_l, 384);

    // ---- bf16 weight conversion ----
    cvtw_kernel<<<(128 * 128 + 255) / 256, 256, 0, stream>>>(l2c_w1, w_l2c1, 128 * 128);
    cvtw_kernel<<<(128 * 128 + 255) / 256, 256, 0, stream>>>(c2l_w1, w_c2l1, 128 * 128);
    cvtw_kernel<<<(128 * 128 + 255) / 256, 256, 0, stream>>>(ro_w1, w_ro1, 128 * 128);
    cvtw_kernel<<<(384 * 128 + 255) / 256, 256, 0, stream>>>(Wf_c, w_gic, 384 * 128);
    cvtw_kernel<<<(384 * 128 + 255) / 256, 256, 0, stream>>>(cgru_whh, w_ghc, 384 * 128);
    cvtw_kernel<<<(384 * 128 + 255) / 256, 256, 0, stream>>>(lgru_whh, w_ghl, 384 * 128);
    cvtw_kernel<<<(384 * 256 + 255) / 256, 256, 0, stream>>>(Wcat, w_gil, 384 * 256);

    // ---- init embeddings ----
    init_emb_kernel<<<((size_t)Lc * DD + 255) / 256, 256, 0, stream>>>(l_init, l_embA, Lc * DD);
    init_emb_kernel<<<((size_t)C * DD + 255) / 256, 256, 0, stream>>>(c_init, c_embA, C * DD);

    u16* l_cur = l_embA; u16* l_nxt = l_embB;
    u16* c_cur = c_embA; u16* c_nxt = c_embB;

    const int nrb_c = (C + 255) / 256,  nrbp_c = ((nrb_c + 7) / 8) * 8;
    const int nrb_l = (Lc + 255) / 256, nrbp_l = ((nrb_l + 7) / 8) * 8;

    for (int it = 0; it < N_ITER; ++it) {
        // ---- literal -> clause ----
        mfma_gemm<true, true><<<dim3((Lc + 127) / 128, 1), 256, 0, stream>>>(
            l_cur, w_l2c1, l2c_b1, msg, Lc, 128);
        gather_kernel<<<(C + 3) / 4, 256, 0, stream>>>(msg, c_off, c_edges, hagg, C);
        gru_wsta<false><<<nrbp_c * 4, 512, 0, stream>>>(
            hagg, nullptr, c_cur, c_nxt, w_gic, w_ghc, cgru_bih, bmsg_c, cgru_bhh,
            ideg_c, C, nrb_c);
        { u16* t = c_cur; c_cur = c_nxt; c_nxt = t; }

        // ---- clause -> literal ----
        mfma_gemm<true, true><<<dim3((C + 127) / 128, 1), 256, 0, stream>>>(
            c_cur, w_c2l1, c2l_b1, msg, C, 128);
        gather_kernel<<<(Lc + 3) / 4, 256, 0, stream>>>(msg, l_off, l_edges, hagg, Lc);
        gru_wsta<true><<<nrbp_l * 4, 512, 0, stream>>>(
            hagg, l_cur, l_cur, l_nxt, w_gil, w_ghl, lgru_bih, bmsg_l, lgru_bhh,
            ideg_l, Lc, nrb_l);
        { u16* t = l_cur; l_cur = l_nxt; l_nxt = t; }
    }

    // ---- readout ----
    mfma_gemm<true, false><<<dim3((Lc + 127) / 128, 1), 256, 0, stream>>>(
        l_cur, w_ro1, ro_b1, hiddenf, Lc, 128);
    hipMemsetAsync(g_sum, 0, BB * 4, stream);
    hipMemsetAsync(g_cnt, 0, BB * 4, stream);
    logit2_kernel<<<1024, 256, 0, stream>>>(hiddenf, ro_w2, l_batch, g_sum, g_cnt, Lc);
    final_kernel<<<1, 64, 0, stream>>>(g_sum, g_cnt, ro_b2, (float*)d_out);
}